// Round 1
// baseline (562.085 us; speedup 1.0000x reference)
//
#include <hip/hip_runtime.h>

#define LRELU_ALPHA 0.2f
#define NN 4096
#define MAXNB 1024

__device__ __forceinline__ float waveSum(float v) {
  #pragma unroll
  for (int o = 32; o > 0; o >>= 1) v += __shfl_down(v, o, 64);
  return v;
}
__device__ __forceinline__ float waveMax(float v) {
  #pragma unroll
  for (int o = 32; o > 0; o >>= 1) v = fmaxf(v, __shfl_down(v, o, 64));
  return v;
}

__device__ __forceinline__ bool adj_test(const void* adj, size_t idx, int mode) {
  if (mode == 1) return ((const unsigned char*)adj)[idx] != 0;
  if (mode == 0) return ((const int*)adj)[idx] != 0;
  return ((const float*)adj)[idx] != 0.0f;
}

// ---- adj dtype probe: bit0 = saw 0x3F800000 (f32 1.0), bit1 = saw word>1 (byte-bool)
__global__ void zero_flag(int* flag) {
  if (threadIdx.x == 0 && blockIdx.x == 0) flag[0] = 0;
}
__global__ __launch_bounds__(256) void detect_adj(const unsigned int* __restrict__ w,
                                                  int nwords, int* flag) {
  int f = 0;
  for (int idx = blockIdx.x * 256 + threadIdx.x; idx < nwords; idx += gridDim.x * 256) {
    unsigned int v = w[idx];
    if (v == 0x3F800000u) f |= 1;
    else if (v > 1u) f |= 2;
  }
  if (f) atomicOr(flag, f);
}

// ---- generic f32 GEMM: C[M,N] = A[M,K] @ B[K,N]; ACT 0=none 1=relu 2=sigmoid
// requires M%64==0, N%64==0, K%16==0, lda/ldb %4==0 (all satisfied here)
template<int ACT>
__global__ __launch_bounds__(256) void gemm_f32(
    const float* __restrict__ A, int lda,
    const float* __restrict__ B, int ldb,
    float* __restrict__ C, int ldc,
    int M, int N, int K, const float* __restrict__ bias)
{
  __shared__ float As[16][68];  // [k][m], padded stride 68 (16B-aligned rows, no pow2 conflicts)
  __shared__ float Bs[16][64];  // [k][n]
  const int tid = threadIdx.x;
  const int m0 = blockIdx.y * 64, n0 = blockIdx.x * 64;
  const int tx = tid & 15, ty = tid >> 4;
  const int arow = tid >> 2, acol = (tid & 3) * 4;
  const int brow = tid >> 4, bcol = (tid & 15) * 4;
  float acc[4][4] = {};
  for (int k0 = 0; k0 < K; k0 += 16) {
    float4 av = *(const float4*)(A + (size_t)(m0 + arow) * lda + k0 + acol);
    float4 bv = *(const float4*)(B + (size_t)(k0 + brow) * ldb + n0 + bcol);
    As[acol + 0][arow] = av.x;
    As[acol + 1][arow] = av.y;
    As[acol + 2][arow] = av.z;
    As[acol + 3][arow] = av.w;
    *(float4*)(&Bs[brow][bcol]) = bv;
    __syncthreads();
    #pragma unroll
    for (int kk = 0; kk < 16; ++kk) {
      float a4[4], b4[4];
      #pragma unroll
      for (int i = 0; i < 4; ++i) a4[i] = As[kk][ty * 4 + i];
      #pragma unroll
      for (int j = 0; j < 4; ++j) b4[j] = Bs[kk][tx * 4 + j];
      #pragma unroll
      for (int i = 0; i < 4; ++i)
        #pragma unroll
        for (int j = 0; j < 4; ++j)
          acc[i][j] = fmaf(a4[i], b4[j], acc[i][j]);
    }
    __syncthreads();
  }
  #pragma unroll
  for (int i = 0; i < 4; ++i) {
    const int row = m0 + ty * 4 + i;
    #pragma unroll
    for (int j = 0; j < 4; ++j) {
      const int col = n0 + tx * 4 + j;
      float v = acc[i][j];
      if (bias) v += bias[col];
      if (ACT == 1) v = fmaxf(v, 0.f);
      if (ACT == 2) v = 1.f / (1.f + expf(-v));
      C[(size_t)row * ldc + col] = v;
    }
  }
}

// ---- per-row attention scores: fs = h@a[:F], fd = h@a[F:] (1 wave per row, 4 rows/block)
__global__ __launch_bounds__(256) void fsrc_fdst(
    const float* __restrict__ h, const float* __restrict__ a,
    int F, float* __restrict__ fs, float* __restrict__ fd)
{
  const int wid = threadIdx.x >> 6, lane = threadIdx.x & 63;
  const int row = blockIdx.x * 4 + wid;
  const float* hr = h + (size_t)row * F;
  float s0 = 0.f, s1 = 0.f;
  for (int f = lane; f < F; f += 64) {
    float hv = hr[f];
    s0 = fmaf(hv, a[f], s0);
    s1 = fmaf(hv, a[F + f], s1);
  }
  s0 = waveSum(s0);
  s1 = waveSum(s1);
  if (lane == 0) { fs[row] = s0; fd[row] = s1; }
}

// ---- masked-softmax sparse aggregate + ELU, 1 block per row
// out[i,:] = ELU( sum_j softmax_j(mask(lrelu(fs_i+fd_j))) * h[j,:] )
__global__ __launch_bounds__(256) void gat_aggregate(
    const float* __restrict__ h, int F,
    const float* __restrict__ fs, const float* __restrict__ fd,
    const void* __restrict__ adj, const int* __restrict__ adjflag,
    float* __restrict__ out, int ldo)
{
  __shared__ int   nbr[MAXNB];
  __shared__ float pbuf[MAXNB];
  __shared__ int   scn[256];
  __shared__ float redf[4];
  const int i = blockIdx.x;
  const int tid = threadIdx.x;
  const int wid = tid >> 6, lane = tid & 63;
  const int fmask = *adjflag;
  const int mode = (fmask & 1) ? 2 : ((fmask & 2) ? 1 : 0);
  const size_t base = (size_t)i * NN;
  const float fsi = fs[i];

  // pass A: per-thread neighbor count + masked row max
  int mycnt = 0;
  float mymax = -3.0e38f;
  for (int j = tid; j < NN; j += 256) {
    if (adj_test(adj, base + j, mode)) {
      float e = fsi + fd[j];
      e = e > 0.f ? e : LRELU_ALPHA * e;
      mymax = fmaxf(mymax, e);
      ++mycnt;
    }
  }
  float wm = waveMax(mymax);
  if (lane == 0) redf[wid] = wm;
  __syncthreads();
  const float gmax = fmaxf(fmaxf(redf[0], redf[1]), fmaxf(redf[2], redf[3]));

  // deterministic compaction via block prefix-scan (no atomics -> fixed FP order)
  scn[tid] = mycnt;
  __syncthreads();
  for (int off = 1; off < 256; off <<= 1) {
    int v = (tid >= off) ? scn[tid - off] : 0;
    __syncthreads();
    scn[tid] += v;
    __syncthreads();
  }
  const int total = scn[255];
  const int excl = scn[tid] - mycnt;

  if (total > 0 && total <= MAXNB) {
    int pos = excl;
    for (int j = tid; j < NN; j += 256)
      if (adj_test(adj, base + j, mode)) nbr[pos++] = j;
    __syncthreads();
    // pass B: p = exp(e - max), row sum
    float mysum = 0.f;
    for (int n = tid; n < total; n += 256) {
      int j = nbr[n];
      float e = fsi + fd[j];
      e = e > 0.f ? e : LRELU_ALPHA * e;
      float p = expf(e - gmax);
      pbuf[n] = p;
      mysum += p;
    }
    float wsum = waveSum(mysum);
    __syncthreads();
    if (lane == 0) redf[wid] = wsum;
    __syncthreads();
    const float inv = 1.f / (redf[0] + redf[1] + redf[2] + redf[3]);
    // pass C: gather-accumulate over neighbors
    for (int f = tid; f < F; f += 256) {
      float acc = 0.f;
      for (int n = 0; n < total; ++n)
        acc = fmaf(pbuf[n], h[(size_t)nbr[n] * F + f], acc);
      float v = acc * inv;
      out[(size_t)i * ldo + f] = v > 0.f ? v : expm1f(v);
    }
  } else {
    // fallback: zero-neighbor row (uniform softmax) or >MAXNB overflow; chunked dense
    float mysum = 0.f;
    if (total != 0) {
      for (int j = tid; j < NN; j += 256) {
        if (adj_test(adj, base + j, mode)) {
          float e = fsi + fd[j];
          e = e > 0.f ? e : LRELU_ALPHA * e;
          mysum += expf(e - gmax);
        }
      }
    }
    float wsum = waveSum(mysum);
    __syncthreads();
    if (lane == 0) redf[wid] = wsum;
    __syncthreads();
    float gsum = redf[0] + redf[1] + redf[2] + redf[3];
    if (total == 0) gsum = (float)NN;
    float acc2[2] = {0.f, 0.f};
    for (int c = 0; c < NN; c += 256) {
      int j = c + tid;
      float p;
      if (total == 0) p = 1.f;
      else if (adj_test(adj, base + j, mode)) {
        float e = fsi + fd[j];
        e = e > 0.f ? e : LRELU_ALPHA * e;
        p = expf(e - gmax);
      } else p = 0.f;
      pbuf[tid] = p;
      __syncthreads();
      #pragma unroll
      for (int u = 0; u < 2; ++u) {
        int f = tid + u * 256;
        if (f < F) {
          float a = acc2[u];
          for (int n = 0; n < 256; ++n)
            a = fmaf(pbuf[n], h[(size_t)(c + n) * F + f], a);
          acc2[u] = a;
        }
      }
      __syncthreads();
    }
    const float inv = 1.f / gsum;
    #pragma unroll
    for (int u = 0; u < 2; ++u) {
      int f = tid + u * 256;
      if (f < F) {
        float v = acc2[u] * inv;
        out[(size_t)i * ldo + f] = v > 0.f ? v : expm1f(v);
      }
    }
  }
}

// ---- copy Y[4096,16] into a strided buffer at column offset
__global__ __launch_bounds__(256) void copy_cols(const float* __restrict__ Y,
                                                 float* __restrict__ dst, int ld, int coloff) {
  int idx = blockIdx.x * 256 + threadIdx.x;  // 4096*16
  int r = idx >> 4, c = idx & 15;
  dst[(size_t)r * ld + coloff + c] = Y[idx];
}

// ---- z = noise*exp(logstd)+mean, written into zcat (ld=272)
__global__ __launch_bounds__(256) void reparam(const float* __restrict__ mn,
                                               const float* __restrict__ lsd,
                                               const float* __restrict__ noise,
                                               float* __restrict__ zcat) {
  int idx = blockIdx.x * 256 + threadIdx.x;  // 4096*256
  int r = idx >> 8, c = idx & 255;
  zcat[(size_t)r * 272 + c] = fmaf(noise[idx], expf(lsd[idx]), mn[idx]);
}

extern "C" void kernel_launch(void* const* d_in, const int* in_sizes, int n_in,
                              void* d_out, int out_size, void* d_ws, size_t ws_size,
                              hipStream_t stream)
{
  const float* X     = (const float*)d_in[0];
  const float* Y     = (const float*)d_in[1];
  const float* noise = (const float*)d_in[2];
  const void*  adj   = d_in[3];
  const float* W0    = (const float*)d_in[4];
  const float* a0    = (const float*)d_in[5];
  const float* W1    = (const float*)d_in[6];
  const float* a1    = (const float*)d_in[7];
  const float* W2    = (const float*)d_in[8];
  const float* a2    = (const float*)d_in[9];
  const float* fc1w  = (const float*)d_in[10];
  const float* fc1b  = (const float*)d_in[11];
  const float* fc2w  = (const float*)d_in[12];
  const float* fc2b  = (const float*)d_in[13];
  float* out = (float*)d_out;
  float* w   = (float*)d_ws;

  // workspace layout (floats); ~38.4 MB total
  float* hidden_cat = w;                 // 4096*528 = 2,162,688
  float* h0   = w + 2162688;             // 4096*512 (reused as zz)
  float* h1   = w + 4259840;             // 4096*256
  float* h2   = w + 5308416;             // 4096*256
  float* mn   = w + 6356992;             // 4096*256
  float* lsd  = w + 7405568;             // 4096*256
  float* zcat = w + 8454144;             // 4096*272 = 1,114,112
  float* fs0  = w + 9568256;
  float* fd0  = fs0 + 4096;
  float* fs1  = fd0 + 4096;
  float* fd1  = fs1 + 4096;
  float* fs2  = fd1 + 4096;
  float* fd2  = fs2 + 4096;
  int*   flag = (int*)(fd2 + 4096);
  float* zz   = h0;

  zero_flag<<<1, 64, 0, stream>>>(flag);
  detect_adj<<<1024, 256, 0, stream>>>((const unsigned int*)adj, 4194304, flag);

  // GAT layer 0: h0 = X @ W0 [4096,512]
  gemm_f32<0><<<dim3(8, 64), 256, 0, stream>>>(X, 1024, W0, 512, h0, 512, 4096, 512, 1024, nullptr);
  fsrc_fdst<<<1024, 256, 0, stream>>>(h0, a0, 512, fs0, fd0);
  gat_aggregate<<<4096, 256, 0, stream>>>(h0, 512, fs0, fd0, adj, flag, hidden_cat, 528);
  copy_cols<<<256, 256, 0, stream>>>(Y, hidden_cat, 528, 512);

  // GAT layer 1 (mean): h1 = hidden_cat @ W1 [4096,256]
  gemm_f32<0><<<dim3(4, 64), 256, 0, stream>>>(hidden_cat, 528, W1, 256, h1, 256, 4096, 256, 528, nullptr);
  fsrc_fdst<<<1024, 256, 0, stream>>>(h1, a1, 256, fs1, fd1);
  gat_aggregate<<<4096, 256, 0, stream>>>(h1, 256, fs1, fd1, adj, flag, mn, 256);

  // GAT layer 2 (logstd): h2 = hidden_cat @ W2 [4096,256]
  gemm_f32<0><<<dim3(4, 64), 256, 0, stream>>>(hidden_cat, 528, W2, 256, h2, 256, 4096, 256, 528, nullptr);
  fsrc_fdst<<<1024, 256, 0, stream>>>(h2, a2, 256, fs2, fd2);
  gat_aggregate<<<4096, 256, 0, stream>>>(h2, 256, fs2, fd2, adj, flag, lsd, 256);

  // z = noise*exp(logstd)+mean; zcat = [z | Y]
  reparam<<<4096, 256, 0, stream>>>(mn, lsd, noise, zcat);
  copy_cols<<<256, 256, 0, stream>>>(Y, zcat, 272, 256);

  // decoder: zz = relu(zcat@fc1 + b); out = sigmoid(zz@fc2 + b)
  gemm_f32<1><<<dim3(8, 64), 256, 0, stream>>>(zcat, 272, fc1w, 512, zz, 512, 4096, 512, 272, fc1b);
  gemm_f32<2><<<dim3(64, 64), 256, 0, stream>>>(zz, 512, fc2w, 4096, out, 4096, 4096, 4096, 512, fc2b);
}

// Round 2
// 317.468 us; speedup vs baseline: 1.7705x; 1.7705x over previous
//
#include <hip/hip_runtime.h>

#define LRELU_ALPHA 0.2f
#define NN 4096
#define MAXNB 1024

typedef unsigned short u16;
typedef short bf16x8 __attribute__((ext_vector_type(8)));
typedef float f32x4 __attribute__((ext_vector_type(4)));
typedef u16 u16x4 __attribute__((ext_vector_type(4)));

__device__ __forceinline__ u16 f2bf(float f) {
  unsigned u = __float_as_uint(f);
  u += 0x7FFFu + ((u >> 16) & 1u);
  return (u16)(u >> 16);
}

__device__ __forceinline__ float waveSum(float v) {
  #pragma unroll
  for (int o = 32; o > 0; o >>= 1) v += __shfl_down(v, o, 64);
  return v;
}
__device__ __forceinline__ float waveMax(float v) {
  #pragma unroll
  for (int o = 32; o > 0; o >>= 1) v = fmaxf(v, __shfl_down(v, o, 64));
  return v;
}

__device__ __forceinline__ bool adj_test(const void* adj, size_t idx, int mode) {
  if (mode == 1) return ((const unsigned char*)adj)[idx] != 0;
  if (mode == 0) return ((const int*)adj)[idx] != 0;
  return ((const float*)adj)[idx] != 0.0f;
}

__device__ __forceinline__ void gload_lds16(const void* g, void* l) {
  __builtin_amdgcn_global_load_lds((const __attribute__((address_space(1))) void*)g,
                                   (__attribute__((address_space(3))) void*)l, 16, 0, 0);
}

// ---- adj dtype probe
__global__ void zero_flag(int* flag) {
  if (threadIdx.x == 0 && blockIdx.x == 0) flag[0] = 0;
}
__global__ __launch_bounds__(256) void detect_adj(const unsigned int* __restrict__ w,
                                                  int nwords, int* flag) {
  int f = 0;
  for (int idx = blockIdx.x * 256 + threadIdx.x; idx < nwords; idx += gridDim.x * 256) {
    unsigned int v = w[idx];
    if (v == 0x3F800000u) f |= 1;
    else if (v > 1u) f |= 2;
  }
  if (f) atomicOr(flag, f);
}

// ---- transpose + convert + zero-pad weights: Wt[n][k] (bf16, ld=Kpad) from W[k][n] (f32)
__global__ __launch_bounds__(256) void transpose_w(const float* __restrict__ Wsrc,
                                                   u16* __restrict__ Wt,
                                                   int K, int N, int Kpad) {
  __shared__ float t[32][33];
  const int kb = blockIdx.y * 32, nb = blockIdx.x * 32;
  const int tx = threadIdx.x, ty = threadIdx.y;  // 32 x 8
  for (int i = ty; i < 32; i += 8) {
    int k = kb + i, n = nb + tx;
    t[i][tx] = (k < K && n < N) ? Wsrc[(size_t)k * N + n] : 0.f;
  }
  __syncthreads();
  for (int i = ty; i < 32; i += 8) {
    int n = nb + i, k = kb + tx;
    if (n < N && k < Kpad) Wt[(size_t)n * Kpad + k] = f2bf(t[tx][i]);
  }
}

// ---- f32 -> bf16 elementwise (vector 4)
__global__ __launch_bounds__(256) void f32_to_bf16_v4(const float* __restrict__ src,
                                                      u16* __restrict__ dst) {
  int i = blockIdx.x * 256 + threadIdx.x;
  float4 v = ((const float4*)src)[i];
  u16x4 o = {f2bf(v.x), f2bf(v.y), f2bf(v.z), f2bf(v.w)};
  ((u16x4*)dst)[i] = o;
}

// ---- bf16 MFMA GEMM: C[M,N] = A[M,K]@B ; A row-major bf16 [M][lda], Bt row-major bf16 [N][ldb]
// tile 128x128, BK=32, 4 waves (2x2), each wave 64x64 = 4x4 frags of 16x16x32
// M%128==0, N%128==0, K%32==0, lda/ldb %8==0
template<int ACT, bool OBF>   // ACT 0=none 1=relu 2=sigmoid
__global__ __launch_bounds__(256) void gemm_mfma(
    const u16* __restrict__ A, int lda,
    const u16* __restrict__ Bt, int ldb,
    void* __restrict__ Cout, int ldc,
    int M, int N, int K, const float* __restrict__ bias)
{
  __shared__ u16 As[128 * 32];  // byte layout: row*64 + slot*16, slot pre-swizzled
  __shared__ u16 Bs[128 * 32];
  const int tid = threadIdx.x;
  const int lane = tid & 63, wv = tid >> 6;
  const int wm = wv >> 1, wn = wv & 1;
  const int m0 = blockIdx.y * 128, n0 = blockIdx.x * 128;

  f32x4 acc[4][4] = {};

  for (int k0 = 0; k0 < K; k0 += 32) {
    // stage 8KB A + 8KB B; chunk c (16B) at LDS byte c*16 holds row r=c>>2,
    // global k-slot s = (c&3) ^ ((r>>1)&3)   (inverse-swizzled source, rule 21)
    #pragma unroll
    for (int i = 0; i < 2; ++i) {
      int c = tid + i * 256;
      int r = c >> 2;
      int s = (c & 3) ^ ((r >> 1) & 3);
      char* la = (char*)As + (c & ~63) * 16;   // wave-uniform base
      char* lb = (char*)Bs + (c & ~63) * 16;
      gload_lds16(A + (size_t)(m0 + r) * lda + k0 + s * 8, la);
      gload_lds16(Bt + (size_t)(n0 + r) * ldb + k0 + s * 8, lb);
    }
    __syncthreads();

    bf16x8 af[4], bf_[4];
    #pragma unroll
    for (int mi = 0; mi < 4; ++mi) {
      int r = wm * 64 + mi * 16 + (lane & 15);
      int sp = (lane >> 4) ^ ((r >> 1) & 3);
      af[mi] = *(const bf16x8*)((const char*)As + r * 64 + sp * 16);
    }
    #pragma unroll
    for (int ni = 0; ni < 4; ++ni) {
      int r = wn * 64 + ni * 16 + (lane & 15);
      int sp = (lane >> 4) ^ ((r >> 1) & 3);
      bf_[ni] = *(const bf16x8*)((const char*)Bs + r * 64 + sp * 16);
    }
    #pragma unroll
    for (int mi = 0; mi < 4; ++mi)
      #pragma unroll
      for (int ni = 0; ni < 4; ++ni)
        acc[mi][ni] = __builtin_amdgcn_mfma_f32_16x16x32_bf16(af[mi], bf_[ni], acc[mi][ni], 0, 0, 0);
    __syncthreads();
  }

  // epilogue: D row=(lane>>4)*4+j, col=lane&15  (verified m89/m91)
  #pragma unroll
  for (int ni = 0; ni < 4; ++ni) {
    const int col = n0 + wn * 64 + ni * 16 + (lane & 15);
    const float bv = bias ? bias[col] : 0.f;
    #pragma unroll
    for (int mi = 0; mi < 4; ++mi) {
      const int row0 = m0 + wm * 64 + mi * 16 + (lane >> 4) * 4;
      #pragma unroll
      for (int j = 0; j < 4; ++j) {
        float v = acc[mi][ni][j] + bv;
        if (ACT == 1) v = fmaxf(v, 0.f);
        if (ACT == 2) v = 1.f / (1.f + expf(-v));
        if (OBF) ((u16*)Cout)[(size_t)(row0 + j) * ldc + col] = f2bf(v);
        else     ((float*)Cout)[(size_t)(row0 + j) * ldc + col] = v;
      }
    }
  }
}

// ---- per-row attention scores (f32 h)
__global__ __launch_bounds__(256) void fsrc_fdst(
    const float* __restrict__ h, const float* __restrict__ a,
    int F, float* __restrict__ fs, float* __restrict__ fd)
{
  const int wid = threadIdx.x >> 6, lane = threadIdx.x & 63;
  const int row = blockIdx.x * 4 + wid;
  const float* hr = h + (size_t)row * F;
  float s0 = 0.f, s1 = 0.f;
  for (int f = lane; f < F; f += 64) {
    float hv = hr[f];
    s0 = fmaf(hv, a[f], s0);
    s1 = fmaf(hv, a[F + f], s1);
  }
  s0 = waveSum(s0);
  s1 = waveSum(s1);
  if (lane == 0) { fs[row] = s0; fd[row] = s1; }
}

// ---- masked-softmax sparse aggregate + ELU, 1 block per row; OBF: bf16 output
template<bool OBF>
__global__ __launch_bounds__(256) void gat_aggregate(
    const float* __restrict__ h, int F,
    const float* __restrict__ fs, const float* __restrict__ fd,
    const void* __restrict__ adj, const int* __restrict__ adjflag,
    void* __restrict__ out, int ldo)
{
  __shared__ int   nbr[MAXNB];
  __shared__ float pbuf[MAXNB];
  __shared__ int   scn[256];
  __shared__ float redf[4];
  const int i = blockIdx.x;
  const int tid = threadIdx.x;
  const int wid = tid >> 6, lane = tid & 63;
  const int fmask = *adjflag;
  const int mode = (fmask & 1) ? 2 : ((fmask & 2) ? 1 : 0);
  const size_t base = (size_t)i * NN;
  const float fsi = fs[i];

  int mycnt = 0;
  float mymax = -3.0e38f;
  for (int j = tid; j < NN; j += 256) {
    if (adj_test(adj, base + j, mode)) {
      float e = fsi + fd[j];
      e = e > 0.f ? e : LRELU_ALPHA * e;
      mymax = fmaxf(mymax, e);
      ++mycnt;
    }
  }
  float wm = waveMax(mymax);
  if (lane == 0) redf[wid] = wm;
  __syncthreads();
  const float gmax = fmaxf(fmaxf(redf[0], redf[1]), fmaxf(redf[2], redf[3]));

  scn[tid] = mycnt;
  __syncthreads();
  for (int off = 1; off < 256; off <<= 1) {
    int v = (tid >= off) ? scn[tid - off] : 0;
    __syncthreads();
    scn[tid] += v;
    __syncthreads();
  }
  const int total = scn[255];
  const int excl = scn[tid] - mycnt;

  if (total > 0 && total <= MAXNB) {
    int pos = excl;
    for (int j = tid; j < NN; j += 256)
      if (adj_test(adj, base + j, mode)) nbr[pos++] = j;
    __syncthreads();
    float mysum = 0.f;
    for (int n = tid; n < total; n += 256) {
      int j = nbr[n];
      float e = fsi + fd[j];
      e = e > 0.f ? e : LRELU_ALPHA * e;
      float p = expf(e - gmax);
      pbuf[n] = p;
      mysum += p;
    }
    float wsum = waveSum(mysum);
    __syncthreads();
    if (lane == 0) redf[wid] = wsum;
    __syncthreads();
    const float inv = 1.f / (redf[0] + redf[1] + redf[2] + redf[3]);
    for (int f = tid; f < F; f += 256) {
      float acc = 0.f;
      for (int n = 0; n < total; ++n)
        acc = fmaf(pbuf[n], h[(size_t)nbr[n] * F + f], acc);
      float v = acc * inv;
      v = v > 0.f ? v : expm1f(v);
      if (OBF) ((u16*)out)[(size_t)i * ldo + f] = f2bf(v);
      else     ((float*)out)[(size_t)i * ldo + f] = v;
    }
  } else {
    float mysum = 0.f;
    if (total != 0) {
      for (int j = tid; j < NN; j += 256) {
        if (adj_test(adj, base + j, mode)) {
          float e = fsi + fd[j];
          e = e > 0.f ? e : LRELU_ALPHA * e;
          mysum += expf(e - gmax);
        }
      }
    }
    float wsum = waveSum(mysum);
    __syncthreads();
    if (lane == 0) redf[wid] = wsum;
    __syncthreads();
    float gsum = redf[0] + redf[1] + redf[2] + redf[3];
    if (total == 0) gsum = (float)NN;
    float acc2[2] = {0.f, 0.f};
    for (int c = 0; c < NN; c += 256) {
      int j = c + tid;
      float p;
      if (total == 0) p = 1.f;
      else if (adj_test(adj, base + j, mode)) {
        float e = fsi + fd[j];
        e = e > 0.f ? e : LRELU_ALPHA * e;
        p = expf(e - gmax);
      } else p = 0.f;
      pbuf[tid] = p;
      __syncthreads();
      #pragma unroll
      for (int u = 0; u < 2; ++u) {
        int f = tid + u * 256;
        if (f < F) {
          float a = acc2[u];
          for (int n = 0; n < 256; ++n)
            a = fmaf(pbuf[n], h[(size_t)(c + n) * F + f], a);
          acc2[u] = a;
        }
      }
      __syncthreads();
    }
    const float inv = 1.f / gsum;
    #pragma unroll
    for (int u = 0; u < 2; ++u) {
      int f = tid + u * 256;
      if (f < F) {
        float v = acc2[u] * inv;
        v = v > 0.f ? v : expm1f(v);
        if (OBF) ((u16*)out)[(size_t)i * ldo + f] = f2bf(v);
        else     ((float*)out)[(size_t)i * ldo + f] = v;
      }
    }
  }
}

// ---- Y [4096,16] f32 -> bf16 columns at coloff
__global__ __launch_bounds__(256) void copy_cols_bf16(const float* __restrict__ Y,
                                                      u16* __restrict__ dst, int ld, int coloff) {
  int idx = blockIdx.x * 256 + threadIdx.x;  // 4096*16
  int r = idx >> 4, c = idx & 15;
  dst[(size_t)r * ld + coloff + c] = f2bf(Y[idx]);
}

// ---- zero-pad 16 bf16 columns [c0, c0+16)
__global__ __launch_bounds__(256) void pad_bf16(u16* __restrict__ dst, int ld, int c0) {
  int idx = blockIdx.x * 256 + threadIdx.x;  // 4096*16
  int r = idx >> 4, c = idx & 15;
  dst[(size_t)r * ld + c0 + c] = 0;
}

// ---- z = noise*exp(logstd)+mean -> bf16 into zcat (ld=288)
__global__ __launch_bounds__(256) void reparam_bf16(const float* __restrict__ mn,
                                                    const float* __restrict__ lsd,
                                                    const float* __restrict__ noise,
                                                    u16* __restrict__ zcat) {
  int idx = blockIdx.x * 256 + threadIdx.x;  // 4096*256
  int r = idx >> 8, c = idx & 255;
  zcat[(size_t)r * 288 + c] = f2bf(fmaf(noise[idx], expf(lsd[idx]), mn[idx]));
}

extern "C" void kernel_launch(void* const* d_in, const int* in_sizes, int n_in,
                              void* d_out, int out_size, void* d_ws, size_t ws_size,
                              hipStream_t stream)
{
  const float* X     = (const float*)d_in[0];
  const float* Y     = (const float*)d_in[1];
  const float* noise = (const float*)d_in[2];
  const void*  adj   = d_in[3];
  const float* W0    = (const float*)d_in[4];
  const float* a0    = (const float*)d_in[5];
  const float* W1    = (const float*)d_in[6];
  const float* a1    = (const float*)d_in[7];
  const float* W2    = (const float*)d_in[8];
  const float* a2    = (const float*)d_in[9];
  const float* fc1w  = (const float*)d_in[10];
  const float* fc1b  = (const float*)d_in[11];
  const float* fc2w  = (const float*)d_in[12];
  const float* fc2b  = (const float*)d_in[13];
  float* out = (float*)d_out;
  char* W = (char*)d_ws;

  // workspace layout (bytes), ~35.8 MB; region [0,8MB) reused Xb -> (zcat,zz)
  u16*   Xb    = (u16*)(W + 0);            // 4096x1024
  u16*   zcatb = (u16*)(W + 0);            // 4096x288 (after Xb dead)
  u16*   zzb   = (u16*)(W + 2359296);      // 4096x512
  float* h0    = (float*)(W + 8388608);    // 4096x512
  float* h1    = (float*)(W + 8388608);    // 4096x256 (after h0 dead)
  float* h2    = (float*)(W + 12582912);   // 4096x256
  u16*   hb    = (u16*)(W + 16777216);     // 4096x544
  float* mn    = (float*)(W + 21233664);   // 4096x256
  float* lsd   = (float*)(W + 25427968);   // 4096x256
  u16*   W0t   = (u16*)(W + 29622272);     // 512x1024
  u16*   W1t   = (u16*)(W + 30670848);     // 256x544
  u16*   W2t   = (u16*)(W + 30949376);     // 256x544
  u16*   fc1t  = (u16*)(W + 31227904);     // 512x288
  u16*   fc2t  = (u16*)(W + 31522816);     // 4096x512
  float* fs0   = (float*)(W + 35717120);
  float* fd0   = fs0 + 4096;
  float* fs1   = fd0 + 4096;
  float* fd1   = fs1 + 4096;
  float* fs2   = fd1 + 4096;
  float* fd2   = fs2 + 4096;
  int*   flag  = (int*)(fd2 + 4096);

  zero_flag<<<1, 64, 0, stream>>>(flag);
  detect_adj<<<1024, 256, 0, stream>>>((const unsigned int*)adj, 4194304, flag);

  // weight transposes (f32 -> bf16, [N][Kpad])
  transpose_w<<<dim3(16, 32), dim3(32, 8), 0, stream>>>(W0, W0t, 1024, 512, 1024);
  transpose_w<<<dim3(8, 17),  dim3(32, 8), 0, stream>>>(W1, W1t, 528, 256, 544);
  transpose_w<<<dim3(8, 17),  dim3(32, 8), 0, stream>>>(W2, W2t, 528, 256, 544);
  transpose_w<<<dim3(16, 9),  dim3(32, 8), 0, stream>>>(fc1w, fc1t, 272, 512, 288);
  transpose_w<<<dim3(128, 16), dim3(32, 8), 0, stream>>>(fc2w, fc2t, 512, 4096, 512);
  f32_to_bf16_v4<<<4096, 256, 0, stream>>>(X, Xb);   // 4096*1024 / 4

  // GAT layer 0
  gemm_mfma<0,false><<<dim3(4, 32), 256, 0, stream>>>(Xb, 1024, W0t, 1024, h0, 512, 4096, 512, 1024, nullptr);
  fsrc_fdst<<<1024, 256, 0, stream>>>(h0, a0, 512, fs0, fd0);
  gat_aggregate<true><<<4096, 256, 0, stream>>>(h0, 512, fs0, fd0, adj, flag, hb, 544);
  copy_cols_bf16<<<256, 256, 0, stream>>>(Y, hb, 544, 512);
  pad_bf16<<<256, 256, 0, stream>>>(hb, 544, 528);

  // GAT layer 1 (mean)
  gemm_mfma<0,false><<<dim3(2, 32), 256, 0, stream>>>(hb, 544, W1t, 544, h1, 256, 4096, 256, 544, nullptr);
  fsrc_fdst<<<1024, 256, 0, stream>>>(h1, a1, 256, fs1, fd1);
  gat_aggregate<false><<<4096, 256, 0, stream>>>(h1, 256, fs1, fd1, adj, flag, mn, 256);

  // GAT layer 2 (logstd)
  gemm_mfma<0,false><<<dim3(2, 32), 256, 0, stream>>>(hb, 544, W2t, 544, h2, 256, 4096, 256, 544, nullptr);
  fsrc_fdst<<<1024, 256, 0, stream>>>(h2, a2, 256, fs2, fd2);
  gat_aggregate<false><<<4096, 256, 0, stream>>>(h2, 256, fs2, fd2, adj, flag, lsd, 256);

  // reparameterize + concat Y (bf16, ld=288, pad to 288)
  reparam_bf16<<<4096, 256, 0, stream>>>(mn, lsd, noise, zcatb);
  copy_cols_bf16<<<256, 256, 0, stream>>>(Y, zcatb, 288, 256);
  pad_bf16<<<256, 256, 0, stream>>>(zcatb, 288, 272);

  // decoder
  gemm_mfma<1,true><<<dim3(4, 32), 256, 0, stream>>>(zcatb, 288, fc1t, 288, zzb, 512, 4096, 512, 288, fc1b);
  gemm_mfma<2,false><<<dim3(32, 32), 256, 0, stream>>>(zzb, 512, fc2t, 512, out, 4096, 4096, 4096, 512, fc2b);
}

// Round 3
// 227.975 us; speedup vs baseline: 2.4656x; 1.3926x over previous
//
#include <hip/hip_runtime.h>

#define LRELU_ALPHA 0.2f
#define NN 4096
#define CAP 256

typedef unsigned short u16;
typedef short bf16x8 __attribute__((ext_vector_type(8)));
typedef float f32x4 __attribute__((ext_vector_type(4)));
typedef u16 u16x4 __attribute__((ext_vector_type(4)));
typedef u16 u16x2 __attribute__((ext_vector_type(2)));

__device__ __forceinline__ u16 f2bf(float f) {
  unsigned u = __float_as_uint(f);
  u += 0x7FFFu + ((u >> 16) & 1u);
  return (u16)(u >> 16);
}

__device__ __forceinline__ float waveSum(float v) {
  #pragma unroll
  for (int o = 32; o > 0; o >>= 1) v += __shfl_down(v, o, 64);
  return v;
}
__device__ __forceinline__ float waveMax(float v) {
  #pragma unroll
  for (int o = 32; o > 0; o >>= 1) v = fmaxf(v, __shfl_down(v, o, 64));
  return v;
}

__device__ __forceinline__ bool adj_test(const void* adj, size_t idx, int mode) {
  if (mode == 1) return ((const unsigned char*)adj)[idx] != 0;
  if (mode == 0) return ((const int*)adj)[idx] != 0;
  return ((const float*)adj)[idx] != 0.0f;
}

__device__ __forceinline__ void gload_lds16(const void* g, void* l) {
  __builtin_amdgcn_global_load_lds((const __attribute__((address_space(1))) void*)g,
                                   (__attribute__((address_space(3))) void*)l, 16, 0, 0);
}

// ---- adj dtype probe
__global__ void zero_flag(int* flag) {
  if (threadIdx.x == 0 && blockIdx.x == 0) flag[0] = 0;
}
__global__ __launch_bounds__(256) void detect_adj(const unsigned int* __restrict__ w,
                                                  int nwords, int* flag) {
  int f = 0;
  for (int idx = blockIdx.x * 256 + threadIdx.x; idx < nwords; idx += gridDim.x * 256) {
    unsigned int v = w[idx];
    if (v == 0x3F800000u) f |= 1;
    else if (v > 1u) f |= 2;
  }
  if (f) atomicOr(flag, f);
}

// ---- CSR build: one block per row, single adj pass (bitmask in registers)
__global__ __launch_bounds__(256) void build_csr(const void* __restrict__ adj,
                                                 const int* __restrict__ adjflag,
                                                 int* __restrict__ nbr,
                                                 int* __restrict__ cnt)
{
  __shared__ int scn[256];
  const int i = blockIdx.x, tid = threadIdx.x;
  const int fmask = *adjflag;
  const int mode = (fmask & 1) ? 2 : ((fmask & 2) ? 1 : 0);
  const size_t base = (size_t)i * NN;
  unsigned bits = 0;
  #pragma unroll
  for (int k = 0; k < 16; ++k) {
    int j = tid + (k << 8);
    if (adj_test(adj, base + j, mode)) bits |= (1u << k);
  }
  int mycnt = __popc(bits);
  scn[tid] = mycnt;
  __syncthreads();
  for (int off = 1; off < 256; off <<= 1) {
    int v = (tid >= off) ? scn[tid - off] : 0;
    __syncthreads();
    scn[tid] += v;
    __syncthreads();
  }
  const int total = scn[255];
  int pos = scn[tid] - mycnt;
  #pragma unroll
  for (int k = 0; k < 16; ++k) {
    if (bits & (1u << k)) {
      if (pos < CAP) nbr[(size_t)i * CAP + pos] = tid + (k << 8);
      ++pos;
    }
  }
  if (tid == 0) cnt[i] = total;
}

// ---- transpose + convert + zero-pad weights: Wt[n][k] (bf16, ld=Kpad) from W[k][n] (f32)
__global__ __launch_bounds__(256) void transpose_w(const float* __restrict__ Wsrc,
                                                   u16* __restrict__ Wt,
                                                   int K, int N, int Kpad) {
  __shared__ float t[32][33];
  const int kb = blockIdx.y * 32, nb = blockIdx.x * 32;
  const int tx = threadIdx.x, ty = threadIdx.y;  // 32 x 8
  for (int i = ty; i < 32; i += 8) {
    int k = kb + i, n = nb + tx;
    t[i][tx] = (k < K && n < N) ? Wsrc[(size_t)k * N + n] : 0.f;
  }
  __syncthreads();
  for (int i = ty; i < 32; i += 8) {
    int n = nb + i, k = kb + tx;
    if (n < N && k < Kpad) Wt[(size_t)n * Kpad + k] = f2bf(t[tx][i]);
  }
}

// ---- f32 -> bf16 elementwise (vector 4)
__global__ __launch_bounds__(256) void f32_to_bf16_v4(const float* __restrict__ src,
                                                      u16* __restrict__ dst) {
  int i = blockIdx.x * 256 + threadIdx.x;
  float4 v = ((const float4*)src)[i];
  u16x4 o = {f2bf(v.x), f2bf(v.y), f2bf(v.z), f2bf(v.w)};
  ((u16x4*)dst)[i] = o;
}

// ---- bf16 MFMA GEMM (128x128 tile, BK=32, 4 waves, gload_lds + XOR swizzle)
template<int ACT, bool OBF>   // ACT 0=none 1=relu 2=sigmoid
__global__ __launch_bounds__(256) void gemm_mfma(
    const u16* __restrict__ A, int lda,
    const u16* __restrict__ Bt, int ldb,
    void* __restrict__ Cout, int ldc,
    int M, int N, int K, const float* __restrict__ bias)
{
  __shared__ u16 As[128 * 32];
  __shared__ u16 Bs[128 * 32];
  const int tid = threadIdx.x;
  const int lane = tid & 63, wv = tid >> 6;
  const int wm = wv >> 1, wn = wv & 1;
  const int m0 = blockIdx.y * 128, n0 = blockIdx.x * 128;

  f32x4 acc[4][4] = {};

  for (int k0 = 0; k0 < K; k0 += 32) {
    #pragma unroll
    for (int i = 0; i < 2; ++i) {
      int c = tid + i * 256;
      int r = c >> 2;
      int s = (c & 3) ^ ((r >> 1) & 3);
      char* la = (char*)As + (c & ~63) * 16;
      char* lb = (char*)Bs + (c & ~63) * 16;
      gload_lds16(A + (size_t)(m0 + r) * lda + k0 + s * 8, la);
      gload_lds16(Bt + (size_t)(n0 + r) * ldb + k0 + s * 8, lb);
    }
    __syncthreads();

    bf16x8 af[4], bf_[4];
    #pragma unroll
    for (int mi = 0; mi < 4; ++mi) {
      int r = wm * 64 + mi * 16 + (lane & 15);
      int sp = (lane >> 4) ^ ((r >> 1) & 3);
      af[mi] = *(const bf16x8*)((const char*)As + r * 64 + sp * 16);
    }
    #pragma unroll
    for (int ni = 0; ni < 4; ++ni) {
      int r = wn * 64 + ni * 16 + (lane & 15);
      int sp = (lane >> 4) ^ ((r >> 1) & 3);
      bf_[ni] = *(const bf16x8*)((const char*)Bs + r * 64 + sp * 16);
    }
    #pragma unroll
    for (int mi = 0; mi < 4; ++mi)
      #pragma unroll
      for (int ni = 0; ni < 4; ++ni)
        acc[mi][ni] = __builtin_amdgcn_mfma_f32_16x16x32_bf16(af[mi], bf_[ni], acc[mi][ni], 0, 0, 0);
    __syncthreads();
  }

  #pragma unroll
  for (int ni = 0; ni < 4; ++ni) {
    const int col = n0 + wn * 64 + ni * 16 + (lane & 15);
    const float bv = bias ? bias[col] : 0.f;
    #pragma unroll
    for (int mi = 0; mi < 4; ++mi) {
      const int row0 = m0 + wm * 64 + mi * 16 + (lane >> 4) * 4;
      #pragma unroll
      for (int j = 0; j < 4; ++j) {
        float v = acc[mi][ni][j] + bv;
        if (ACT == 1) v = fmaxf(v, 0.f);
        if (ACT == 2) v = 1.f / (1.f + expf(-v));
        if (OBF) ((u16*)Cout)[(size_t)(row0 + j) * ldc + col] = f2bf(v);
        else     ((float*)Cout)[(size_t)(row0 + j) * ldc + col] = v;
      }
    }
  }
}

// ---- per-row attention scores
__global__ __launch_bounds__(256) void fsrc_fdst(
    const float* __restrict__ h, const float* __restrict__ a,
    int F, float* __restrict__ fs, float* __restrict__ fd)
{
  const int wid = threadIdx.x >> 6, lane = threadIdx.x & 63;
  const int row = blockIdx.x * 4 + wid;
  const float* hr = h + (size_t)row * F;
  float s0 = 0.f, s1 = 0.f;
  for (int f = lane; f < F; f += 64) {
    float hv = hr[f];
    s0 = fmaf(hv, a[f], s0);
    s1 = fmaf(hv, a[F + f], s1);
  }
  s0 = waveSum(s0);
  s1 = waveSum(s1);
  if (lane == 0) { fs[row] = s0; fd[row] = s1; }
}

// ---- layer-0 aggregate via CSR: out hb[row] = [elu(att@h0) bf16 (512) | Y (16) | 0 (16)]
__global__ __launch_bounds__(256) void agg_gat0(
    const float* __restrict__ h,
    const float* __restrict__ fs, const float* __restrict__ fd,
    const int* __restrict__ nbr, const int* __restrict__ cnt,
    const float* __restrict__ Y, u16* __restrict__ hb)
{
  __shared__ int   nb[CAP];
  __shared__ float pbuf[CAP];
  __shared__ float redm[4], reds[4];
  const int i = blockIdx.x, tid = threadIdx.x;
  const int wid = tid >> 6, lane = tid & 63;
  int c = cnt[i]; if (c > CAP) c = CAP;
  const float fsi = fs[i];
  float2 acc = {0.f, 0.f};

  if (c > 0) {
    float e = -3.0e38f;
    if (tid < c) {
      int j = nbr[(size_t)i * CAP + tid];
      nb[tid] = j;
      float t = fsi + fd[j];
      e = t > 0.f ? t : LRELU_ALPHA * t;
    }
    float wm = waveMax(e);
    if (lane == 0) redm[wid] = wm;
    __syncthreads();
    const float gmax = fmaxf(fmaxf(redm[0], redm[1]), fmaxf(redm[2], redm[3]));
    float p = (tid < c) ? expf(e - gmax) : 0.f;
    float ws = waveSum(p);
    if (lane == 0) reds[wid] = ws;
    __syncthreads();
    const float inv = 1.f / (reds[0] + reds[1] + reds[2] + reds[3]);
    if (tid < c) pbuf[tid] = p * inv;
    __syncthreads();
    const float* hp = h + 2 * tid;
    for (int n = 0; n < c; ++n) {
      float2 hv = *(const float2*)(hp + (size_t)nb[n] * 512);
      float pn = pbuf[n];
      acc.x = fmaf(pn, hv.x, acc.x);
      acc.y = fmaf(pn, hv.y, acc.y);
    }
  } else {
    // zero-degree: uniform softmax = column mean (never expected; correctness only)
    const float* hp = h + 2 * tid;
    for (int j = 0; j < NN; ++j) {
      float2 hv = *(const float2*)(hp + (size_t)j * 512);
      acc.x += hv.x; acc.y += hv.y;
    }
    acc.x *= (1.f / NN); acc.y *= (1.f / NN);
  }
  float vx = acc.x > 0.f ? acc.x : expm1f(acc.x);
  float vy = acc.y > 0.f ? acc.y : expm1f(acc.y);
  u16* row = hb + (size_t)i * 544;
  *(u16x2*)(row + 2 * tid) = u16x2{f2bf(vx), f2bf(vy)};
  if (tid < 8) {
    float2 yv = *(const float2*)(Y + (size_t)i * 16 + 2 * tid);
    *(u16x2*)(row + 512 + 2 * tid) = u16x2{f2bf(yv.x), f2bf(yv.y)};
  } else if (tid < 16) {
    *(u16x2*)(row + 528 + 2 * (tid - 8)) = u16x2{0, 0};
  }
}

// ---- fused layers 1+2 aggregate + reparam + concat:
// zcat[row] = [ noise*exp(elu(att2@h2)) + elu(att1@h1) (256) | Y (16) | 0 (16) ] bf16
__global__ __launch_bounds__(256) void agg_gat12(
    const float* __restrict__ h1, const float* __restrict__ h2,
    const float* __restrict__ fs1, const float* __restrict__ fd1,
    const float* __restrict__ fs2, const float* __restrict__ fd2,
    const int* __restrict__ nbr, const int* __restrict__ cnt,
    const float* __restrict__ noise, const float* __restrict__ Y,
    u16* __restrict__ zcat)
{
  __shared__ int   nb[CAP];
  __shared__ float p1[CAP], p2[CAP];
  __shared__ float mn_s[256], lsd_s[256];
  __shared__ float redm1[4], redm2[4], reds1[4], reds2[4];
  const int i = blockIdx.x, tid = threadIdx.x;
  const int wid = tid >> 6, lane = tid & 63;
  int c = cnt[i]; if (c > CAP) c = CAP;
  const int half = tid >> 7, t = tid & 127;

  float2 acc = {0.f, 0.f};
  if (c > 0) {
    float e1 = -3.0e38f, e2 = -3.0e38f;
    if (tid < c) {
      int j = nbr[(size_t)i * CAP + tid];
      nb[tid] = j;
      float a1v = fs1[i] + fd1[j];
      float a2v = fs2[i] + fd2[j];
      e1 = a1v > 0.f ? a1v : LRELU_ALPHA * a1v;
      e2 = a2v > 0.f ? a2v : LRELU_ALPHA * a2v;
    }
    float wm1 = waveMax(e1), wm2 = waveMax(e2);
    if (lane == 0) { redm1[wid] = wm1; redm2[wid] = wm2; }
    __syncthreads();
    const float g1 = fmaxf(fmaxf(redm1[0], redm1[1]), fmaxf(redm1[2], redm1[3]));
    const float g2 = fmaxf(fmaxf(redm2[0], redm2[1]), fmaxf(redm2[2], redm2[3]));
    float pp1 = (tid < c) ? expf(e1 - g1) : 0.f;
    float pp2 = (tid < c) ? expf(e2 - g2) : 0.f;
    float ws1 = waveSum(pp1), ws2 = waveSum(pp2);
    if (lane == 0) { reds1[wid] = ws1; reds2[wid] = ws2; }
    __syncthreads();
    const float inv1 = 1.f / (reds1[0] + reds1[1] + reds1[2] + reds1[3]);
    const float inv2 = 1.f / (reds2[0] + reds2[1] + reds2[2] + reds2[3]);
    if (tid < c) { p1[tid] = pp1 * inv1; p2[tid] = pp2 * inv2; }
    __syncthreads();
    const float* hh = (half ? h2 : h1) + 2 * t;
    const float* pp = half ? p2 : p1;
    for (int n = 0; n < c; ++n) {
      float2 hv = *(const float2*)(hh + (size_t)nb[n] * 256);
      float pn = pp[n];
      acc.x = fmaf(pn, hv.x, acc.x);
      acc.y = fmaf(pn, hv.y, acc.y);
    }
  } else {
    const float* hh = (half ? h2 : h1) + 2 * t;
    for (int j = 0; j < NN; ++j) {
      float2 hv = *(const float2*)(hh + (size_t)j * 256);
      acc.x += hv.x; acc.y += hv.y;
    }
    acc.x *= (1.f / NN); acc.y *= (1.f / NN);
  }
  float vx = acc.x > 0.f ? acc.x : expm1f(acc.x);
  float vy = acc.y > 0.f ? acc.y : expm1f(acc.y);
  float* dst = half ? lsd_s : mn_s;
  dst[2 * t] = vx; dst[2 * t + 1] = vy;
  __syncthreads();
  u16* row = zcat + (size_t)i * 288;
  if (tid < 128) {
    const int f = 2 * tid;
    float2 nz = *(const float2*)(noise + (size_t)i * 256 + f);
    float zx = fmaf(nz.x, expf(lsd_s[f]), mn_s[f]);
    float zy = fmaf(nz.y, expf(lsd_s[f + 1]), mn_s[f + 1]);
    *(u16x2*)(row + f) = u16x2{f2bf(zx), f2bf(zy)};
  } else if (tid < 136) {
    const int k = tid - 128;
    float2 yv = *(const float2*)(Y + (size_t)i * 16 + 2 * k);
    *(u16x2*)(row + 256 + 2 * k) = u16x2{f2bf(yv.x), f2bf(yv.y)};
  } else if (tid < 144) {
    *(u16x2*)(row + 272 + 2 * (tid - 136)) = u16x2{0, 0};
  }
}

extern "C" void kernel_launch(void* const* d_in, const int* in_sizes, int n_in,
                              void* d_out, int out_size, void* d_ws, size_t ws_size,
                              hipStream_t stream)
{
  const float* X     = (const float*)d_in[0];
  const float* Y     = (const float*)d_in[1];
  const float* noise = (const float*)d_in[2];
  const void*  adj   = d_in[3];
  const float* W0    = (const float*)d_in[4];
  const float* a0    = (const float*)d_in[5];
  const float* W1    = (const float*)d_in[6];
  const float* a1    = (const float*)d_in[7];
  const float* W2    = (const float*)d_in[8];
  const float* a2    = (const float*)d_in[9];
  const float* fc1w  = (const float*)d_in[10];
  const float* fc1b  = (const float*)d_in[11];
  const float* fc2w  = (const float*)d_in[12];
  const float* fc2b  = (const float*)d_in[13];
  float* out = (float*)d_out;
  char* W = (char*)d_ws;

  // workspace layout (bytes), ~31.7 MB
  u16*   Xb    = (u16*)(W + 0);            // 4096x1024 bf16 (dead after gemm0)
  u16*   zcatb = (u16*)(W + 0);            // 4096x288 bf16
  u16*   zzb   = (u16*)(W + 2359296);      // 4096x512 bf16
  float* h0    = (float*)(W + 8388608);    // 4096x512 f32 (dead after agg0/fsrc0)
  float* h1    = (float*)(W + 8388608);    // 4096x256 f32
  float* h2    = (float*)(W + 12582912);   // 4096x256 f32
  u16*   hb    = (u16*)(W + 16777216);     // 4096x544 bf16
  u16*   W0t   = (u16*)(W + 21233664);     // 512x1024
  u16*   W1t   = (u16*)(W + 22282240);     // 256x544
  u16*   W2t   = (u16*)(W + 22560768);     // 256x544
  u16*   fc1t  = (u16*)(W + 22839296);     // 512x288
  u16*   fc2t  = (u16*)(W + 23134208);     // 4096x512
  int*   nbr   = (int*)(W + 27328512);     // 4096x256 int
  int*   cnt   = (int*)(W + 31522816);     // 4096 int
  float* fs0   = (float*)(W + 31539200);
  float* fd0   = fs0 + 4096;
  float* fs1   = fd0 + 4096;
  float* fd1   = fs1 + 4096;
  float* fs2   = fd1 + 4096;
  float* fd2   = fs2 + 4096;
  int*   flag  = (int*)(fd2 + 4096);

  zero_flag<<<1, 64, 0, stream>>>(flag);
  detect_adj<<<1024, 256, 0, stream>>>((const unsigned int*)adj, 4194304, flag);
  build_csr<<<4096, 256, 0, stream>>>(adj, flag, nbr, cnt);

  // weight transposes (f32 -> bf16, [N][Kpad])
  transpose_w<<<dim3(16, 32), dim3(32, 8), 0, stream>>>(W0, W0t, 1024, 512, 1024);
  transpose_w<<<dim3(8, 17),  dim3(32, 8), 0, stream>>>(W1, W1t, 528, 256, 544);
  transpose_w<<<dim3(8, 17),  dim3(32, 8), 0, stream>>>(W2, W2t, 528, 256, 544);
  transpose_w<<<dim3(16, 9),  dim3(32, 8), 0, stream>>>(fc1w, fc1t, 272, 512, 288);
  transpose_w<<<dim3(128, 16), dim3(32, 8), 0, stream>>>(fc2w, fc2t, 512, 4096, 512);
  f32_to_bf16_v4<<<4096, 256, 0, stream>>>(X, Xb);

  // GAT layer 0
  gemm_mfma<0,false><<<dim3(4, 32), 256, 0, stream>>>(Xb, 1024, W0t, 1024, h0, 512, 4096, 512, 1024, nullptr);
  fsrc_fdst<<<1024, 256, 0, stream>>>(h0, a0, 512, fs0, fd0);
  agg_gat0<<<4096, 256, 0, stream>>>(h0, fs0, fd0, nbr, cnt, Y, hb);

  // GAT layers 1 & 2 (mean, logstd)
  gemm_mfma<0,false><<<dim3(2, 32), 256, 0, stream>>>(hb, 544, W1t, 544, h1, 256, 4096, 256, 544, nullptr);
  fsrc_fdst<<<1024, 256, 0, stream>>>(h1, a1, 256, fs1, fd1);
  gemm_mfma<0,false><<<dim3(2, 32), 256, 0, stream>>>(hb, 544, W2t, 544, h2, 256, 4096, 256, 544, nullptr);
  fsrc_fdst<<<1024, 256, 0, stream>>>(h2, a2, 256, fs2, fd2);
  agg_gat12<<<4096, 256, 0, stream>>>(h1, h2, fs1, fd1, fs2, fd2, nbr, cnt, noise, Y, zcatb);

  // decoder
  gemm_mfma<1,true><<<dim3(4, 32), 256, 0, stream>>>(zcatb, 288, fc1t, 288, zzb, 512, 4096, 512, 288, fc1b);
  gemm_mfma<2,false><<<dim3(32, 32), 256, 0, stream>>>(zzb, 512, fc2t, 512, out, 4096, 4096, 4096, 512, fc2b);
}

// Round 4
// 197.332 us; speedup vs baseline: 2.8484x; 1.1553x over previous
//
#include <hip/hip_runtime.h>

#define LRELU_ALPHA 0.2f
#define NN 4096
#define CAP 256

typedef unsigned short u16;
typedef short bf16x8 __attribute__((ext_vector_type(8)));
typedef float f32x4 __attribute__((ext_vector_type(4)));
typedef u16 u16x4 __attribute__((ext_vector_type(4)));
typedef u16 u16x2 __attribute__((ext_vector_type(2)));

__device__ __forceinline__ u16 f2bf(float f) {
  unsigned u = __float_as_uint(f);
  u += 0x7FFFu + ((u >> 16) & 1u);
  return (u16)(u >> 16);
}

__device__ __forceinline__ float waveSum(float v) {
  #pragma unroll
  for (int o = 32; o > 0; o >>= 1) v += __shfl_down(v, o, 64);
  return v;
}
__device__ __forceinline__ float waveMax(float v) {
  #pragma unroll
  for (int o = 32; o > 0; o >>= 1) v = fmaxf(v, __shfl_down(v, o, 64));
  return v;
}

__device__ __forceinline__ bool adj_test(const void* adj, size_t idx, int mode) {
  if (mode == 1) return ((const unsigned char*)adj)[idx] != 0;
  if (mode == 0) return ((const int*)adj)[idx] != 0;
  return ((const float*)adj)[idx] != 0.0f;
}

__device__ __forceinline__ void gload_lds16(const void* g, void* l) {
  __builtin_amdgcn_global_load_lds((const __attribute__((address_space(1))) void*)g,
                                   (__attribute__((address_space(3))) void*)l, 16, 0, 0);
}

// ---- adj dtype probe (first 2MB is enough: any nonzero word discriminates)
__global__ void zero_flag(int* flag) {
  if (threadIdx.x == 0 && blockIdx.x == 0) flag[0] = 0;
}
__global__ __launch_bounds__(256) void detect_adj(const unsigned int* __restrict__ w,
                                                  int nwords, int* flag) {
  int f = 0;
  for (int idx = blockIdx.x * 256 + threadIdx.x; idx < nwords; idx += gridDim.x * 256) {
    unsigned int v = w[idx];
    if (v == 0x3F800000u) f |= 1;
    else if (v > 1u) f |= 2;
  }
  if (f) atomicOr(flag, f);
}

// ---- CSR build: one block per row, single adj pass
__global__ __launch_bounds__(256) void build_csr(const void* __restrict__ adj,
                                                 const int* __restrict__ adjflag,
                                                 int* __restrict__ nbr,
                                                 int* __restrict__ cnt)
{
  __shared__ int scn[256];
  const int i = blockIdx.x, tid = threadIdx.x;
  const int fmask = *adjflag;
  const int mode = (fmask & 1) ? 2 : ((fmask & 2) ? 1 : 0);
  const size_t base = (size_t)i * NN;
  unsigned bits = 0;
  #pragma unroll
  for (int k = 0; k < 16; ++k) {
    int j = tid + (k << 8);
    if (adj_test(adj, base + j, mode)) bits |= (1u << k);
  }
  int mycnt = __popc(bits);
  scn[tid] = mycnt;
  __syncthreads();
  for (int off = 1; off < 256; off <<= 1) {
    int v = (tid >= off) ? scn[tid - off] : 0;
    __syncthreads();
    scn[tid] += v;
    __syncthreads();
  }
  const int total = scn[255];
  int pos = scn[tid] - mycnt;
  #pragma unroll
  for (int k = 0; k < 16; ++k) {
    if (bits & (1u << k)) {
      if (pos < CAP) nbr[(size_t)i * CAP + pos] = tid + (k << 8);
      ++pos;
    }
  }
  if (tid == 0) cnt[i] = total;
}

// ---- transpose + convert + zero-pad: Wt[n][k] (bf16, ld=Kpad) from W[k][n] (f32)
__global__ __launch_bounds__(256) void transpose_w(const float* __restrict__ Wsrc,
                                                   u16* __restrict__ Wt,
                                                   int K, int N, int Kpad) {
  __shared__ float t[32][33];
  const int kb = blockIdx.y * 32, nb = blockIdx.x * 32;
  const int tx = threadIdx.x, ty = threadIdx.y;  // 32 x 8
  for (int i = ty; i < 32; i += 8) {
    int k = kb + i, n = nb + tx;
    t[i][tx] = (k < K && n < N) ? Wsrc[(size_t)k * N + n] : 0.f;
  }
  __syncthreads();
  for (int i = ty; i < 32; i += 8) {
    int n = nb + i, k = kb + tx;
    if (n < N && k < Kpad) Wt[(size_t)n * Kpad + k] = f2bf(t[tx][i]);
  }
}

// ---- f32 -> bf16 elementwise (vector 4)
__global__ __launch_bounds__(256) void f32_to_bf16_v4(const float* __restrict__ src,
                                                      u16* __restrict__ dst) {
  int i = blockIdx.x * 256 + threadIdx.x;
  float4 v = ((const float4*)src)[i];
  u16x4 o = {f2bf(v.x), f2bf(v.y), f2bf(v.z), f2bf(v.w)};
  ((u16x4*)dst)[i] = o;
}

// ---- bf16 MFMA GEMM 128x128 tile, BK=32, 4 waves (for the skinny GEMMs)
template<int ACT, bool OBF>   // ACT 0=none 1=relu 2=sigmoid
__global__ __launch_bounds__(256) void gemm_mfma(
    const u16* __restrict__ A, int lda,
    const u16* __restrict__ Bt, int ldb,
    void* __restrict__ Cout, int ldc,
    int M, int N, int K, const float* __restrict__ bias)
{
  __shared__ u16 As[128 * 32];
  __shared__ u16 Bs[128 * 32];
  const int tid = threadIdx.x;
  const int lane = tid & 63, wv = tid >> 6;
  const int wm = wv >> 1, wn = wv & 1;
  const int m0 = blockIdx.y * 128, n0 = blockIdx.x * 128;

  f32x4 acc[4][4] = {};

  for (int k0 = 0; k0 < K; k0 += 32) {
    #pragma unroll
    for (int i = 0; i < 2; ++i) {
      int c = tid + i * 256;
      int r = c >> 2;
      int s = (c & 3) ^ ((r >> 1) & 3);
      char* la = (char*)As + (c & ~63) * 16;
      char* lb = (char*)Bs + (c & ~63) * 16;
      gload_lds16(A + (size_t)(m0 + r) * lda + k0 + s * 8, la);
      gload_lds16(Bt + (size_t)(n0 + r) * ldb + k0 + s * 8, lb);
    }
    __syncthreads();

    bf16x8 af[4], bf_[4];
    #pragma unroll
    for (int mi = 0; mi < 4; ++mi) {
      int r = wm * 64 + mi * 16 + (lane & 15);
      int sp = (lane >> 4) ^ ((r >> 1) & 3);
      af[mi] = *(const bf16x8*)((const char*)As + r * 64 + sp * 16);
    }
    #pragma unroll
    for (int ni = 0; ni < 4; ++ni) {
      int r = wn * 64 + ni * 16 + (lane & 15);
      int sp = (lane >> 4) ^ ((r >> 1) & 3);
      bf_[ni] = *(const bf16x8*)((const char*)Bs + r * 64 + sp * 16);
    }
    #pragma unroll
    for (int mi = 0; mi < 4; ++mi)
      #pragma unroll
      for (int ni = 0; ni < 4; ++ni)
        acc[mi][ni] = __builtin_amdgcn_mfma_f32_16x16x32_bf16(af[mi], bf_[ni], acc[mi][ni], 0, 0, 0);
    __syncthreads();
  }

  #pragma unroll
  for (int ni = 0; ni < 4; ++ni) {
    const int col = n0 + wn * 64 + ni * 16 + (lane & 15);
    const float bv = bias ? bias[col] : 0.f;
    #pragma unroll
    for (int mi = 0; mi < 4; ++mi) {
      const int row0 = m0 + wm * 64 + mi * 16 + (lane >> 4) * 4;
      #pragma unroll
      for (int j = 0; j < 4; ++j) {
        float v = acc[mi][ni][j] + bv;
        if (ACT == 1) v = fmaxf(v, 0.f);
        if (ACT == 2) v = 1.f / (1.f + expf(-v));
        if (OBF) ((u16*)Cout)[(size_t)(row0 + j) * ldc + col] = f2bf(v);
        else     ((float*)Cout)[(size_t)(row0 + j) * ldc + col] = v;
      }
    }
  }
}

// ---- bf16 MFMA GEMM 256x256 tile, BK=64, 8 waves, double-buffered LDS (T3 2-phase)
// grid must tile M,N by 256; K % 64 == 0; lda/ldb % 8 == 0
template<int ACT>
__global__ __launch_bounds__(512, 2) void gemm_mfma256(
    const u16* __restrict__ A, int lda,
    const u16* __restrict__ Bt, int ldb,
    float* __restrict__ Cout, int ldc,
    int K, const float* __restrict__ bias)
{
  __shared__ u16 As[2][256 * 64];   // 32KB each buf
  __shared__ u16 Bs[2][256 * 64];
  const int tid = threadIdx.x;
  const int lane = tid & 63, wv = tid >> 6;   // 8 waves
  const int wm = wv >> 2, wn = wv & 3;        // 2 x 4; wave owns 128x64
  const int m0 = blockIdx.y * 256, n0 = blockIdx.x * 256;

  f32x4 acc[8][4] = {};

  // stage one K-tile (256 rows x 64 cols, A and B) into buf; 4 chunks each/thread.
  // LDS chunk c: row r=c>>3, lds slot sl=c&7 holds global slot sg=sl^(r&7) (swizzle via source)
  const int nk = K >> 6;
  auto STAGE = [&](int buf, int kt) {
    const u16* Ap = A + (size_t)m0 * lda + kt * 64;
    const u16* Bp = Bt + (size_t)n0 * ldb + kt * 64;
    #pragma unroll
    for (int i = 0; i < 4; ++i) {
      int c = tid + i * 512;
      int r = c >> 3, sl = c & 7;
      int sg = sl ^ (r & 7);
      gload_lds16(Ap + (size_t)r * lda + sg * 8, (char*)As[buf] + (c & ~63) * 16);
      gload_lds16(Bp + (size_t)r * ldb + sg * 8, (char*)Bs[buf] + (c & ~63) * 16);
    }
  };

  STAGE(0, 0);
  __syncthreads();

  int cur = 0;
  for (int kt = 0; kt < nk; ++kt) {
    if (kt + 1 < nk) STAGE(cur ^ 1, kt + 1);   // prefetch next tile (issue-early)
    #pragma unroll
    for (int ks = 0; ks < 2; ++ks) {           // two k-steps of 32
      bf16x8 af[8], bf_[4];
      #pragma unroll
      for (int mi = 0; mi < 8; ++mi) {
        int r = wm * 128 + mi * 16 + (lane & 15);
        int sg = ks * 4 + (lane >> 4);
        int sl = sg ^ (r & 7);
        af[mi] = *(const bf16x8*)((const char*)As[cur] + r * 128 + sl * 16);
      }
      #pragma unroll
      for (int ni = 0; ni < 4; ++ni) {
        int r = wn * 64 + ni * 16 + (lane & 15);
        int sg = ks * 4 + (lane >> 4);
        int sl = sg ^ (r & 7);
        bf_[ni] = *(const bf16x8*)((const char*)Bs[cur] + r * 128 + sl * 16);
      }
      __builtin_amdgcn_s_setprio(1);
      #pragma unroll
      for (int mi = 0; mi < 8; ++mi)
        #pragma unroll
        for (int ni = 0; ni < 4; ++ni)
          acc[mi][ni] = __builtin_amdgcn_mfma_f32_16x16x32_bf16(af[mi], bf_[ni], acc[mi][ni], 0, 0, 0);
      __builtin_amdgcn_s_setprio(0);
    }
    __syncthreads();   // drains prefetch (vmcnt0) AFTER ~600cyc of compute
    cur ^= 1;
  }

  #pragma unroll
  for (int ni = 0; ni < 4; ++ni) {
    const int col = n0 + wn * 64 + ni * 16 + (lane & 15);
    const float bv = bias ? bias[col] : 0.f;
    #pragma unroll
    for (int mi = 0; mi < 8; ++mi) {
      const int row0 = m0 + wm * 128 + mi * 16 + (lane >> 4) * 4;
      #pragma unroll
      for (int j = 0; j < 4; ++j) {
        float v = acc[mi][ni][j] + bv;
        if (ACT == 1) v = fmaxf(v, 0.f);
        if (ACT == 2) v = 1.f / (1.f + expf(-v));
        Cout[(size_t)(row0 + j) * ldc + col] = v;
      }
    }
  }
}

// ---- per-row attention scores (layer 0)
__global__ __launch_bounds__(256) void fsrc_fdst(
    const float* __restrict__ h, const float* __restrict__ a,
    int F, float* __restrict__ fs, float* __restrict__ fd)
{
  const int wid = threadIdx.x >> 6, lane = threadIdx.x & 63;
  const int row = blockIdx.x * 4 + wid;
  const float* hr = h + (size_t)row * F;
  float s0 = 0.f, s1 = 0.f;
  for (int f = lane; f < F; f += 64) {
    float hv = hr[f];
    s0 = fmaf(hv, a[f], s0);
    s1 = fmaf(hv, a[F + f], s1);
  }
  s0 = waveSum(s0);
  s1 = waveSum(s1);
  if (lane == 0) { fs[row] = s0; fd[row] = s1; }
}

// ---- merged scores for layers 1&2 over h12 [4096][512] (cols 0-255 = h1, 256-511 = h2)
__global__ __launch_bounds__(256) void fsrc_fdst12(
    const float* __restrict__ h12,
    const float* __restrict__ a1, const float* __restrict__ a2,
    float* __restrict__ fs1, float* __restrict__ fd1,
    float* __restrict__ fs2, float* __restrict__ fd2)
{
  const int wid = threadIdx.x >> 6, lane = threadIdx.x & 63;
  const int row = blockIdx.x * 4 + wid;
  const float* hr = h12 + (size_t)row * 512;
  float s0 = 0.f, s1 = 0.f, s2 = 0.f, s3 = 0.f;
  #pragma unroll
  for (int f = lane; f < 256; f += 64) {
    float h1v = hr[f], h2v = hr[256 + f];
    s0 = fmaf(h1v, a1[f], s0);
    s1 = fmaf(h1v, a1[256 + f], s1);
    s2 = fmaf(h2v, a2[f], s2);
    s3 = fmaf(h2v, a2[256 + f], s3);
  }
  s0 = waveSum(s0); s1 = waveSum(s1); s2 = waveSum(s2); s3 = waveSum(s3);
  if (lane == 0) { fs1[row] = s0; fd1[row] = s1; fs2[row] = s2; fd2[row] = s3; }
}

// ---- layer-0 aggregate via CSR: hb[row] = [elu(att@h0) bf16 (512) | Y (16) | 0 (16)]
__global__ __launch_bounds__(256) void agg_gat0(
    const float* __restrict__ h,
    const float* __restrict__ fs, const float* __restrict__ fd,
    const int* __restrict__ nbr, const int* __restrict__ cnt,
    const float* __restrict__ Y, u16* __restrict__ hb)
{
  __shared__ int   nb[CAP];
  __shared__ float pbuf[CAP];
  __shared__ float redm[4], reds[4];
  const int i = blockIdx.x, tid = threadIdx.x;
  const int wid = tid >> 6, lane = tid & 63;
  int c = cnt[i]; if (c > CAP) c = CAP;
  const float fsi = fs[i];
  float2 acc = {0.f, 0.f};

  if (c > 0) {
    float e = -3.0e38f;
    if (tid < c) {
      int j = nbr[(size_t)i * CAP + tid];
      nb[tid] = j;
      float t = fsi + fd[j];
      e = t > 0.f ? t : LRELU_ALPHA * t;
    }
    float wm = waveMax(e);
    if (lane == 0) redm[wid] = wm;
    __syncthreads();
    const float gmax = fmaxf(fmaxf(redm[0], redm[1]), fmaxf(redm[2], redm[3]));
    float p = (tid < c) ? expf(e - gmax) : 0.f;
    float ws = waveSum(p);
    if (lane == 0) reds[wid] = ws;
    __syncthreads();
    const float inv = 1.f / (reds[0] + reds[1] + reds[2] + reds[3]);
    if (tid < c) pbuf[tid] = p * inv;
    __syncthreads();
    const float* hp = h + 2 * tid;
    #pragma unroll 4
    for (int n = 0; n < c; ++n) {
      float2 hv = *(const float2*)(hp + (size_t)nb[n] * 512);
      float pn = pbuf[n];
      acc.x = fmaf(pn, hv.x, acc.x);
      acc.y = fmaf(pn, hv.y, acc.y);
    }
  } else {
    const float* hp = h + 2 * tid;
    for (int j = 0; j < NN; ++j) {
      float2 hv = *(const float2*)(hp + (size_t)j * 512);
      acc.x += hv.x; acc.y += hv.y;
    }
    acc.x *= (1.f / NN); acc.y *= (1.f / NN);
  }
  float vx = acc.x > 0.f ? acc.x : expm1f(acc.x);
  float vy = acc.y > 0.f ? acc.y : expm1f(acc.y);
  u16* row = hb + (size_t)i * 544;
  *(u16x2*)(row + 2 * tid) = u16x2{f2bf(vx), f2bf(vy)};
  if (tid < 8) {
    float2 yv = *(const float2*)(Y + (size_t)i * 16 + 2 * tid);
    *(u16x2*)(row + 512 + 2 * tid) = u16x2{f2bf(yv.x), f2bf(yv.y)};
  } else if (tid < 16) {
    *(u16x2*)(row + 528 + 2 * (tid - 8)) = u16x2{0, 0};
  }
}

// ---- fused layers 1+2 aggregate + reparam + concat (h12 strided ld=512)
__global__ __launch_bounds__(256) void agg_gat12(
    const float* __restrict__ h12,
    const float* __restrict__ fs1, const float* __restrict__ fd1,
    const float* __restrict__ fs2, const float* __restrict__ fd2,
    const int* __restrict__ nbr, const int* __restrict__ cnt,
    const float* __restrict__ noise, const float* __restrict__ Y,
    u16* __restrict__ zcat)
{
  __shared__ int   nb[CAP];
  __shared__ float p1[CAP], p2[CAP];
  __shared__ float mn_s[256], lsd_s[256];
  __shared__ float redm1[4], redm2[4], reds1[4], reds2[4];
  const int i = blockIdx.x, tid = threadIdx.x;
  const int wid = tid >> 6, lane = tid & 63;
  int c = cnt[i]; if (c > CAP) c = CAP;
  const int half = tid >> 7, t = tid & 127;

  float2 acc = {0.f, 0.f};
  if (c > 0) {
    float e1 = -3.0e38f, e2 = -3.0e38f;
    if (tid < c) {
      int j = nbr[(size_t)i * CAP + tid];
      nb[tid] = j;
      float a1v = fs1[i] + fd1[j];
      float a2v = fs2[i] + fd2[j];
      e1 = a1v > 0.f ? a1v : LRELU_ALPHA * a1v;
      e2 = a2v > 0.f ? a2v : LRELU_ALPHA * a2v;
    }
    float wm1 = waveMax(e1), wm2 = waveMax(e2);
    if (lane == 0) { redm1[wid] = wm1; redm2[wid] = wm2; }
    __syncthreads();
    const float g1 = fmaxf(fmaxf(redm1[0], redm1[1]), fmaxf(redm1[2], redm1[3]));
    const float g2 = fmaxf(fmaxf(redm2[0], redm2[1]), fmaxf(redm2[2], redm2[3]));
    float pp1 = (tid < c) ? expf(e1 - g1) : 0.f;
    float pp2 = (tid < c) ? expf(e2 - g2) : 0.f;
    float ws1 = waveSum(pp1), ws2 = waveSum(pp2);
    if (lane == 0) { reds1[wid] = ws1; reds2[wid] = ws2; }
    __syncthreads();
    const float inv1 = 1.f / (reds1[0] + reds1[1] + reds1[2] + reds1[3]);
    const float inv2 = 1.f / (reds2[0] + reds2[1] + reds2[2] + reds2[3]);
    if (tid < c) { p1[tid] = pp1 * inv1; p2[tid] = pp2 * inv2; }
    __syncthreads();
    const float* hh = h12 + (half ? 256 : 0) + 2 * t;
    const float* pp = half ? p2 : p1;
    #pragma unroll 4
    for (int n = 0; n < c; ++n) {
      float2 hv = *(const float2*)(hh + (size_t)nb[n] * 512);
      float pn = pp[n];
      acc.x = fmaf(pn, hv.x, acc.x);
      acc.y = fmaf(pn, hv.y, acc.y);
    }
  } else {
    const float* hh = h12 + (half ? 256 : 0) + 2 * t;
    for (int j = 0; j < NN; ++j) {
      float2 hv = *(const float2*)(hh + (size_t)j * 512);
      acc.x += hv.x; acc.y += hv.y;
    }
    acc.x *= (1.f / NN); acc.y *= (1.f / NN);
  }
  float vx = acc.x > 0.f ? acc.x : expm1f(acc.x);
  float vy = acc.y > 0.f ? acc.y : expm1f(acc.y);
  float* dst = half ? lsd_s : mn_s;
  dst[2 * t] = vx; dst[2 * t + 1] = vy;
  __syncthreads();
  u16* row = zcat + (size_t)i * 288;
  if (tid < 128) {
    const int f = 2 * tid;
    float2 nz = *(const float2*)(noise + (size_t)i * 256 + f);
    float zx = fmaf(nz.x, expf(lsd_s[f]), mn_s[f]);
    float zy = fmaf(nz.y, expf(lsd_s[f + 1]), mn_s[f + 1]);
    *(u16x2*)(row + f) = u16x2{f2bf(zx), f2bf(zy)};
  } else if (tid < 136) {
    const int k = tid - 128;
    float2 yv = *(const float2*)(Y + (size_t)i * 16 + 2 * k);
    *(u16x2*)(row + 256 + 2 * k) = u16x2{f2bf(yv.x), f2bf(yv.y)};
  } else if (tid < 144) {
    *(u16x2*)(row + 272 + 2 * (tid - 136)) = u16x2{0, 0};
  }
}

extern "C" void kernel_launch(void* const* d_in, const int* in_sizes, int n_in,
                              void* d_out, int out_size, void* d_ws, size_t ws_size,
                              hipStream_t stream)
{
  const float* X     = (const float*)d_in[0];
  const float* Y     = (const float*)d_in[1];
  const float* noise = (const float*)d_in[2];
  const void*  adj   = d_in[3];
  const float* W0    = (const float*)d_in[4];
  const float* a0    = (const float*)d_in[5];
  const float* W1    = (const float*)d_in[6];
  const float* a1    = (const float*)d_in[7];
  const float* W2    = (const float*)d_in[8];
  const float* a2    = (const float*)d_in[9];
  const float* fc1w  = (const float*)d_in[10];
  const float* fc1b  = (const float*)d_in[11];
  const float* fc2w  = (const float*)d_in[12];
  const float* fc2b  = (const float*)d_in[13];
  float* out = (float*)d_out;
  char* W = (char*)d_ws;

  // workspace layout (bytes), ~31.7 MB
  u16*   Xb    = (u16*)(W + 0);            // 4096x1024 bf16 (dead after gemm0)
  u16*   zcatb = (u16*)(W + 0);            // 4096x288 bf16
  u16*   zzb   = (u16*)(W + 2359296);      // 4096x512 bf16
  float* h0    = (float*)(W + 8388608);    // 4096x512 f32 (dead after agg0/fsrc0)
  float* h12   = (float*)(W + 8388608);    // 4096x512 f32 (reuses h0)
  u16*   hb    = (u16*)(W + 16777216);     // 4096x544 bf16
  u16*   W0t   = (u16*)(W + 21233664);     // 512x1024
  u16*   W12t  = (u16*)(W + 22282240);     // 512x544 (rows 0-255: W1t, 256-511: W2t)
  u16*   fc1t  = (u16*)(W + 22839296);     // 512x288
  u16*   fc2t  = (u16*)(W + 23134208);     // 4096x512
  int*   nbr   = (int*)(W + 27328512);     // 4096x256 int
  int*   cnt   = (int*)(W + 31522816);     // 4096 int
  float* fs0   = (float*)(W + 31539200);
  float* fd0   = fs0 + 4096;
  float* fs1   = fd0 + 4096;
  float* fd1   = fs1 + 4096;
  float* fs2   = fd1 + 4096;
  float* fd2   = fs2 + 4096;
  int*   flag  = (int*)(fd2 + 4096);

  zero_flag<<<1, 64, 0, stream>>>(flag);
  detect_adj<<<256, 256, 0, stream>>>((const unsigned int*)adj, 524288, flag);  // 2MB sample
  build_csr<<<4096, 256, 0, stream>>>(adj, flag, nbr, cnt);

  // weight transposes (f32 -> bf16, [N][Kpad])
  transpose_w<<<dim3(16, 32), dim3(32, 8), 0, stream>>>(W0, W0t, 1024, 512, 1024);
  transpose_w<<<dim3(8, 17),  dim3(32, 8), 0, stream>>>(W1, W12t, 528, 256, 544);
  transpose_w<<<dim3(8, 17),  dim3(32, 8), 0, stream>>>(W2, W12t + 256 * 544, 528, 256, 544);
  transpose_w<<<dim3(16, 9),  dim3(32, 8), 0, stream>>>(fc1w, fc1t, 272, 512, 288);
  transpose_w<<<dim3(128, 16), dim3(32, 8), 0, stream>>>(fc2w, fc2t, 512, 4096, 512);
  f32_to_bf16_v4<<<4096, 256, 0, stream>>>(X, Xb);

  // GAT layer 0
  gemm_mfma<0,false><<<dim3(4, 32), 256, 0, stream>>>(Xb, 1024, W0t, 1024, h0, 512, 4096, 512, 1024, nullptr);
  fsrc_fdst<<<1024, 256, 0, stream>>>(h0, a0, 512, fs0, fd0);
  agg_gat0<<<4096, 256, 0, stream>>>(h0, fs0, fd0, nbr, cnt, Y, hb);

  // GAT layers 1 & 2 merged: h12 = hb @ [W1|W2]
  gemm_mfma<0,false><<<dim3(4, 32), 256, 0, stream>>>(hb, 544, W12t, 544, h12, 512, 4096, 512, 544, nullptr);
  fsrc_fdst12<<<1024, 256, 0, stream>>>(h12, a1, a2, fs1, fd1, fs2, fd2);
  agg_gat12<<<4096, 256, 0, stream>>>(h12, fs1, fd1, fs2, fd2, nbr, cnt, noise, Y, zcatb);

  // decoder
  gemm_mfma<1,true><<<dim3(4, 32), 256, 0, stream>>>(zcatb, 288, fc1t, 288, zzb, 512, 4096, 512, 288, fc1b);
  gemm_mfma256<2><<<dim3(16, 16), 512, 0, stream>>>(zzb, 512, fc2t, 512, out, 4096, 512, fc2b);
}

// Round 5
// 177.018 us; speedup vs baseline: 3.1753x; 1.1148x over previous
//
#include <hip/hip_runtime.h>

#define LRELU_ALPHA 0.2f
#define NN 4096
#define CAP 256

typedef unsigned short u16;
typedef short bf16x8 __attribute__((ext_vector_type(8)));
typedef float f32x4 __attribute__((ext_vector_type(4)));
typedef u16 u16x4 __attribute__((ext_vector_type(4)));
typedef u16 u16x2 __attribute__((ext_vector_type(2)));
typedef u16 u16x8 __attribute__((ext_vector_type(8)));

__device__ __forceinline__ u16 f2bf(float f) {
  unsigned u = __float_as_uint(f);
  u += 0x7FFFu + ((u >> 16) & 1u);
  return (u16)(u >> 16);
}
__device__ __forceinline__ float bf2f(u16 u) {
  return __uint_as_float(((unsigned)u) << 16);
}

__device__ __forceinline__ float waveSum(float v) {
  #pragma unroll
  for (int o = 32; o > 0; o >>= 1) v += __shfl_down(v, o, 64);
  return v;
}
__device__ __forceinline__ float waveMax(float v) {
  #pragma unroll
  for (int o = 32; o > 0; o >>= 1) v = fmaxf(v, __shfl_down(v, o, 64));
  return v;
}

__device__ __forceinline__ bool adj_test(const void* adj, size_t idx, int mode) {
  if (mode == 1) return ((const unsigned char*)adj)[idx] != 0;
  if (mode == 0) return ((const int*)adj)[idx] != 0;
  return ((const float*)adj)[idx] != 0.0f;
}

__device__ __forceinline__ void gload_lds16(const void* g, void* l) {
  __builtin_amdgcn_global_load_lds((const __attribute__((address_space(1))) void*)g,
                                   (__attribute__((address_space(3))) void*)l, 16, 0, 0);
}

// ---- adj dtype probe (2MB sample is enough to discriminate)
__global__ void zero_flag(int* flag) {
  if (threadIdx.x == 0 && blockIdx.x == 0) flag[0] = 0;
}
__global__ __launch_bounds__(256) void detect_adj(const unsigned int* __restrict__ w,
                                                  int nwords, int* flag) {
  int f = 0;
  for (int idx = blockIdx.x * 256 + threadIdx.x; idx < nwords; idx += gridDim.x * 256) {
    unsigned int v = w[idx];
    if (v == 0x3F800000u) f |= 1;
    else if (v > 1u) f |= 2;
  }
  if (f) atomicOr(flag, f);
}

// ---- CSR build: one block per row, single adj pass
__global__ __launch_bounds__(256) void build_csr(const void* __restrict__ adj,
                                                 const int* __restrict__ adjflag,
                                                 int* __restrict__ nbr,
                                                 int* __restrict__ cnt)
{
  __shared__ int scn[256];
  const int i = blockIdx.x, tid = threadIdx.x;
  const int fmask = *adjflag;
  const int mode = (fmask & 1) ? 2 : ((fmask & 2) ? 1 : 0);
  const size_t base = (size_t)i * NN;
  unsigned bits = 0;
  #pragma unroll
  for (int k = 0; k < 16; ++k) {
    int j = tid + (k << 8);
    if (adj_test(adj, base + j, mode)) bits |= (1u << k);
  }
  int mycnt = __popc(bits);
  scn[tid] = mycnt;
  __syncthreads();
  for (int off = 1; off < 256; off <<= 1) {
    int v = (tid >= off) ? scn[tid - off] : 0;
    __syncthreads();
    scn[tid] += v;
    __syncthreads();
  }
  const int total = scn[255];
  int pos = scn[tid] - mycnt;
  #pragma unroll
  for (int k = 0; k < 16; ++k) {
    if (bits & (1u << k)) {
      if (pos < CAP) nbr[(size_t)i * CAP + pos] = tid + (k << 8);
      ++pos;
    }
  }
  if (tid == 0) cnt[i] = total;
}

// ---- transpose + convert + zero-pad: Wt[n][k] (bf16, ld=Kpad) from W[k][n] (f32)
__device__ __forceinline__ void transpose_body(const float* Wsrc, u16* Wt,
                                               int K, int N, int Kpad,
                                               int bx, int by) {
  __shared__ float t[32][33];
  const int kb = by * 32, nb = bx * 32;
  const int tx = threadIdx.x, ty = threadIdx.y;  // 32 x 8
  for (int i = ty; i < 32; i += 8) {
    int k = kb + i, n = nb + tx;
    t[i][tx] = (k < K && n < N) ? Wsrc[(size_t)k * N + n] : 0.f;
  }
  __syncthreads();
  for (int i = ty; i < 32; i += 8) {
    int n = nb + i, k = kb + tx;
    if (n < N && k < Kpad) Wt[(size_t)n * Kpad + k] = f2bf(t[tx][i]);
  }
}
__global__ __launch_bounds__(256) void transpose_w(const float* __restrict__ Wsrc,
                                                   u16* __restrict__ Wt,
                                                   int K, int N, int Kpad) {
  transpose_body(Wsrc, Wt, K, N, Kpad, blockIdx.x, blockIdx.y);
}
// two same-shape transposes in one dispatch (z selects matrix)
__global__ __launch_bounds__(256) void transpose_w2(const float* __restrict__ S0, u16* __restrict__ D0,
                                                    const float* __restrict__ S1, u16* __restrict__ D1,
                                                    int K, int N, int Kpad) {
  transpose_body(blockIdx.z ? S1 : S0, blockIdx.z ? D1 : D0, K, N, Kpad, blockIdx.x, blockIdx.y);
}

// ---- f32 -> bf16 elementwise (vector 4)
__global__ __launch_bounds__(256) void f32_to_bf16_v4(const float* __restrict__ src,
                                                      u16* __restrict__ dst) {
  int i = blockIdx.x * 256 + threadIdx.x;
  float4 v = ((const float4*)src)[i];
  u16x4 o = {f2bf(v.x), f2bf(v.y), f2bf(v.z), f2bf(v.w)};
  ((u16x4*)dst)[i] = o;
}

// ---- bf16 MFMA GEMM 128x128 tile, BK=32, 4 waves, dbuf + counted vmcnt (T3/T4 depth-2)
template<int ACT, bool OBF>   // ACT 0=none 1=relu 2=sigmoid
__global__ __launch_bounds__(256) void gemm_mfma(
    const u16* __restrict__ A, int lda,
    const u16* __restrict__ Bt, int ldb,
    void* __restrict__ Cout, int ldc,
    int M, int N, int K, const float* __restrict__ bias)
{
  __shared__ u16 As[2][128 * 32];
  __shared__ u16 Bs[2][128 * 32];
  const int tid = threadIdx.x;
  const int lane = tid & 63, wv = tid >> 6;
  const int wm = wv >> 1, wn = wv & 1;
  const int m0 = blockIdx.y * 128, n0 = blockIdx.x * 128;
  const int nk = K >> 5;

  f32x4 acc[4][4] = {};

  auto STAGE = [&](int buf, int kt) {   // 4 loads/thread
    #pragma unroll
    for (int i = 0; i < 2; ++i) {
      int c = tid + i * 256;
      int r = c >> 2;
      int s = (c & 3) ^ ((r >> 1) & 3);
      gload_lds16(A + (size_t)(m0 + r) * lda + kt * 32 + s * 8, (char*)As[buf] + (c & ~63) * 16);
      gload_lds16(Bt + (size_t)(n0 + r) * ldb + kt * 32 + s * 8, (char*)Bs[buf] + (c & ~63) * 16);
    }
  };

  STAGE(0, 0);
  if (nk > 1) STAGE(1, 1);

  int cur = 0;
  for (int kt = 0; kt < nk; ++kt) {
    if (kt + 2 < nk) { asm volatile("s_waitcnt vmcnt(4)" ::: "memory"); }
    else             { asm volatile("s_waitcnt vmcnt(0)" ::: "memory"); }
    __builtin_amdgcn_s_barrier();

    bf16x8 af[4], bf_[4];
    #pragma unroll
    for (int mi = 0; mi < 4; ++mi) {
      int r = wm * 64 + mi * 16 + (lane & 15);
      int sp = (lane >> 4) ^ ((r >> 1) & 3);
      af[mi] = *(const bf16x8*)((const char*)As[cur] + r * 64 + sp * 16);
    }
    #pragma unroll
    for (int ni = 0; ni < 4; ++ni) {
      int r = wn * 64 + ni * 16 + (lane & 15);
      int sp = (lane >> 4) ^ ((r >> 1) & 3);
      bf_[ni] = *(const bf16x8*)((const char*)Bs[cur] + r * 64 + sp * 16);
    }
    __builtin_amdgcn_s_setprio(1);
    #pragma unroll
    for (int mi = 0; mi < 4; ++mi)
      #pragma unroll
      for (int ni = 0; ni < 4; ++ni)
        acc[mi][ni] = __builtin_amdgcn_mfma_f32_16x16x32_bf16(af[mi], bf_[ni], acc[mi][ni], 0, 0, 0);
    __builtin_amdgcn_s_setprio(0);

    __builtin_amdgcn_s_barrier();          // all waves done reading buf cur
    if (kt + 2 < nk) STAGE(cur, kt + 2);   // refill it; loads fly across next 2 phases
    cur ^= 1;
  }

  #pragma unroll
  for (int ni = 0; ni < 4; ++ni) {
    const int col = n0 + wn * 64 + ni * 16 + (lane & 15);
    const float bv = bias ? bias[col] : 0.f;
    #pragma unroll
    for (int mi = 0; mi < 4; ++mi) {
      const int row0 = m0 + wm * 64 + mi * 16 + (lane >> 4) * 4;
      #pragma unroll
      for (int j = 0; j < 4; ++j) {
        float v = acc[mi][ni][j] + bv;
        if (ACT == 1) v = fmaxf(v, 0.f);
        if (ACT == 2) v = 1.f / (1.f + expf(-v));
        if (OBF) ((u16*)Cout)[(size_t)(row0 + j) * ldc + col] = f2bf(v);
        else     ((float*)Cout)[(size_t)(row0 + j) * ldc + col] = v;
      }
    }
  }
}

// ---- bf16 MFMA GEMM 256x256 tile, BK=64, 8 waves, dbuf + counted vmcnt (depth-2)
template<int ACT>
__global__ __launch_bounds__(512) void gemm_mfma256(
    const u16* __restrict__ A, int lda,
    const u16* __restrict__ Bt, int ldb,
    float* __restrict__ Cout, int ldc,
    int K, const float* __restrict__ bias)
{
  __shared__ u16 As[2][256 * 64];   // 32KB each buf
  __shared__ u16 Bs[2][256 * 64];
  const int tid = threadIdx.x;
  const int lane = tid & 63, wv = tid >> 6;   // 8 waves
  const int wm = wv >> 2, wn = wv & 3;        // 2 x 4; wave owns 128x64
  const int m0 = blockIdx.y * 256, n0 = blockIdx.x * 256;
  const int nk = K >> 6;

  f32x4 acc[8][4] = {};

  auto STAGE = [&](int buf, int kt) {   // 8 loads/thread
    const u16* Ap = A + (size_t)m0 * lda + kt * 64;
    const u16* Bp = Bt + (size_t)n0 * ldb + kt * 64;
    #pragma unroll
    for (int i = 0; i < 4; ++i) {
      int c = tid + i * 512;
      int r = c >> 3, sl = c & 7;
      int sg = sl ^ (r & 7);
      gload_lds16(Ap + (size_t)r * lda + sg * 8, (char*)As[buf] + (c & ~63) * 16);
      gload_lds16(Bp + (size_t)r * ldb + sg * 8, (char*)Bs[buf] + (c & ~63) * 16);
    }
  };

  STAGE(0, 0);
  if (nk > 1) STAGE(1, 1);

  int cur = 0;
  for (int kt = 0; kt < nk; ++kt) {
    if (kt + 2 < nk) { asm volatile("s_waitcnt vmcnt(8)" ::: "memory"); }
    else             { asm volatile("s_waitcnt vmcnt(0)" ::: "memory"); }
    __builtin_amdgcn_s_barrier();

    #pragma unroll
    for (int ks = 0; ks < 2; ++ks) {           // two k-steps of 32
      bf16x8 af[8], bf_[4];
      #pragma unroll
      for (int mi = 0; mi < 8; ++mi) {
        int r = wm * 128 + mi * 16 + (lane & 15);
        int sg = ks * 4 + (lane >> 4);
        int sl = sg ^ (r & 7);
        af[mi] = *(const bf16x8*)((const char*)As[cur] + r * 128 + sl * 16);
      }
      #pragma unroll
      for (int ni = 0; ni < 4; ++ni) {
        int r = wn * 64 + ni * 16 + (lane & 15);
        int sg = ks * 4 + (lane >> 4);
        int sl = sg ^ (r & 7);
        bf_[ni] = *(const bf16x8*)((const char*)Bs[cur] + r * 128 + sl * 16);
      }
      __builtin_amdgcn_s_setprio(1);
      #pragma unroll
      for (int mi = 0; mi < 8; ++mi)
        #pragma unroll
        for (int ni = 0; ni < 4; ++ni)
          acc[mi][ni] = __builtin_amdgcn_mfma_f32_16x16x32_bf16(af[mi], bf_[ni], acc[mi][ni], 0, 0, 0);
      __builtin_amdgcn_s_setprio(0);
    }

    __builtin_amdgcn_s_barrier();          // all waves done reading buf cur
    if (kt + 2 < nk) STAGE(cur, kt + 2);
    cur ^= 1;
  }

  #pragma unroll
  for (int ni = 0; ni < 4; ++ni) {
    const int col = n0 + wn * 64 + ni * 16 + (lane & 15);
    const float bv = bias ? bias[col] : 0.f;
    #pragma unroll
    for (int mi = 0; mi < 8; ++mi) {
      const int row0 = m0 + wm * 128 + mi * 16 + (lane >> 4) * 4;
      #pragma unroll
      for (int j = 0; j < 4; ++j) {
        float v = acc[mi][ni][j] + bv;
        if (ACT == 1) v = fmaxf(v, 0.f);
        if (ACT == 2) v = 1.f / (1.f + expf(-v));
        Cout[(size_t)(row0 + j) * ldc + col] = v;
      }
    }
  }
}

// ---- per-row attention scores, bf16 h (layer 0, F=512)
__global__ __launch_bounds__(256) void fsrc_fdst_bf16(
    const u16* __restrict__ h, const float* __restrict__ a,
    float* __restrict__ fs, float* __restrict__ fd)
{
  const int wid = threadIdx.x >> 6, lane = threadIdx.x & 63;
  const int row = blockIdx.x * 4 + wid;
  u16x8 hv = *(const u16x8*)(h + (size_t)row * 512 + lane * 8);
  float s0 = 0.f, s1 = 0.f;
  #pragma unroll
  for (int j = 0; j < 8; ++j) {
    float x = bf2f(hv[j]);
    s0 = fmaf(x, a[lane * 8 + j], s0);
    s1 = fmaf(x, a[512 + lane * 8 + j], s1);
  }
  s0 = waveSum(s0);
  s1 = waveSum(s1);
  if (lane == 0) { fs[row] = s0; fd[row] = s1; }
}

// ---- merged scores for layers 1&2 over h12 [4096][512] f32 (cols 0-255 h1, 256-511 h2)
__global__ __launch_bounds__(256) void fsrc_fdst12(
    const float* __restrict__ h12,
    const float* __restrict__ a1, const float* __restrict__ a2,
    float* __restrict__ fs1, float* __restrict__ fd1,
    float* __restrict__ fs2, float* __restrict__ fd2)
{
  const int wid = threadIdx.x >> 6, lane = threadIdx.x & 63;
  const int row = blockIdx.x * 4 + wid;
  const float* hr = h12 + (size_t)row * 512;
  float s0 = 0.f, s1 = 0.f, s2 = 0.f, s3 = 0.f;
  #pragma unroll
  for (int f = lane; f < 256; f += 64) {
    float h1v = hr[f], h2v = hr[256 + f];
    s0 = fmaf(h1v, a1[f], s0);
    s1 = fmaf(h1v, a1[256 + f], s1);
    s2 = fmaf(h2v, a2[f], s2);
    s3 = fmaf(h2v, a2[256 + f], s3);
  }
  s0 = waveSum(s0); s1 = waveSum(s1); s2 = waveSum(s2); s3 = waveSum(s3);
  if (lane == 0) { fs1[row] = s0; fd1[row] = s1; fs2[row] = s2; fd2[row] = s3; }
}

// ---- layer-0 aggregate via CSR (bf16 h): hb[row] = [elu(att@h0) bf16 (512) | Y (16) | 0 (16)]
__global__ __launch_bounds__(256) void agg_gat0(
    const u16* __restrict__ h,
    const float* __restrict__ fs, const float* __restrict__ fd,
    const int* __restrict__ nbr, const int* __restrict__ cnt,
    const float* __restrict__ Y, u16* __restrict__ hb)
{
  __shared__ int   nb[CAP];
  __shared__ float pbuf[CAP];
  __shared__ float redm[4], reds[4];
  const int i = blockIdx.x, tid = threadIdx.x;
  const int wid = tid >> 6, lane = tid & 63;
  int c = cnt[i]; if (c > CAP) c = CAP;
  const float fsi = fs[i];
  float2 acc = {0.f, 0.f};

  if (c > 0) {
    float e = -3.0e38f;
    if (tid < c) {
      int j = nbr[(size_t)i * CAP + tid];
      nb[tid] = j;
      float t = fsi + fd[j];
      e = t > 0.f ? t : LRELU_ALPHA * t;
    }
    float wm = waveMax(e);
    if (lane == 0) redm[wid] = wm;
    __syncthreads();
    const float gmax = fmaxf(fmaxf(redm[0], redm[1]), fmaxf(redm[2], redm[3]));
    float p = (tid < c) ? expf(e - gmax) : 0.f;
    float ws = waveSum(p);
    if (lane == 0) reds[wid] = ws;
    __syncthreads();
    const float inv = 1.f / (reds[0] + reds[1] + reds[2] + reds[3]);
    if (tid < c) pbuf[tid] = p * inv;
    __syncthreads();
    const u16* hp = h + 2 * tid;
    #pragma unroll 4
    for (int n = 0; n < c; ++n) {
      u16x2 hv = *(const u16x2*)(hp + (size_t)nb[n] * 512);
      float pn = pbuf[n];
      acc.x = fmaf(pn, bf2f(hv[0]), acc.x);
      acc.y = fmaf(pn, bf2f(hv[1]), acc.y);
    }
  } else {
    const u16* hp = h + 2 * tid;
    for (int j = 0; j < NN; ++j) {
      u16x2 hv = *(const u16x2*)(hp + (size_t)j * 512);
      acc.x += bf2f(hv[0]); acc.y += bf2f(hv[1]);
    }
    acc.x *= (1.f / NN); acc.y *= (1.f / NN);
  }
  float vx = acc.x > 0.f ? acc.x : expm1f(acc.x);
  float vy = acc.y > 0.f ? acc.y : expm1f(acc.y);
  u16* row = hb + (size_t)i * 544;
  *(u16x2*)(row + 2 * tid) = u16x2{f2bf(vx), f2bf(vy)};
  if (tid < 8) {
    float2 yv = *(const float2*)(Y + (size_t)i * 16 + 2 * tid);
    *(u16x2*)(row + 512 + 2 * tid) = u16x2{f2bf(yv.x), f2bf(yv.y)};
  } else if (tid < 16) {
    *(u16x2*)(row + 528 + 2 * (tid - 8)) = u16x2{0, 0};
  }
}

// ---- fused layers 1+2 aggregate + reparam + concat (h12 f32, ld=512)
__global__ __launch_bounds__(256) void agg_gat12(
    const float* __restrict__ h12,
    const float* __restrict__ fs1, const float* __restrict__ fd1,
    const float* __restrict__ fs2, const float* __restrict__ fd2,
    const int* __restrict__ nbr, const int* __restrict__ cnt,
    const float* __restrict__ noise, const float* __restrict__ Y,
    u16* __restrict__ zcat)
{
  __shared__ int   nb[CAP];
  __shared__ float p1[CAP], p2[CAP];
  __shared__ float mn_s[256], lsd_s[256];
  __shared__ float redm1[4], redm2[4], reds1[4], reds2[4];
  const int i = blockIdx.x, tid = threadIdx.x;
  const int wid = tid >> 6, lane = tid & 63;
  int c = cnt[i]; if (c > CAP) c = CAP;
  const int half = tid >> 7, t = tid & 127;

  float2 acc = {0.f, 0.f};
  if (c > 0) {
    float e1 = -3.0e38f, e2 = -3.0e38f;
    if (tid < c) {
      int j = nbr[(size_t)i * CAP + tid];
      nb[tid] = j;
      float a1v = fs1[i] + fd1[j];
      float a2v = fs2[i] + fd2[j];
      e1 = a1v > 0.f ? a1v : LRELU_ALPHA * a1v;
      e2 = a2v > 0.f ? a2v : LRELU_ALPHA * a2v;
    }
    float wm1 = waveMax(e1), wm2 = waveMax(e2);
    if (lane == 0) { redm1[wid] = wm1; redm2[wid] = wm2; }
    __syncthreads();
    const float g1 = fmaxf(fmaxf(redm1[0], redm1[1]), fmaxf(redm1[2], redm1[3]));
    const float g2 = fmaxf(fmaxf(redm2[0], redm2[1]), fmaxf(redm2[2], redm2[3]));
    float pp1 = (tid < c) ? expf(e1 - g1) : 0.f;
    float pp2 = (tid < c) ? expf(e2 - g2) : 0.f;
    float ws1 = waveSum(pp1), ws2 = waveSum(pp2);
    if (lane == 0) { reds1[wid] = ws1; reds2[wid] = ws2; }
    __syncthreads();
    const float inv1 = 1.f / (reds1[0] + reds1[1] + reds1[2] + reds1[3]);
    const float inv2 = 1.f / (reds2[0] + reds2[1] + reds2[2] + reds2[3]);
    if (tid < c) { p1[tid] = pp1 * inv1; p2[tid] = pp2 * inv2; }
    __syncthreads();
    const float* hh = h12 + (half ? 256 : 0) + 2 * t;
    const float* pp = half ? p2 : p1;
    #pragma unroll 4
    for (int n = 0; n < c; ++n) {
      float2 hv = *(const float2*)(hh + (size_t)nb[n] * 512);
      float pn = pp[n];
      acc.x = fmaf(pn, hv.x, acc.x);
      acc.y = fmaf(pn, hv.y, acc.y);
    }
  } else {
    const float* hh = h12 + (half ? 256 : 0) + 2 * t;
    for (int j = 0; j < NN; ++j) {
      float2 hv = *(const float2*)(hh + (size_t)j * 512);
      acc.x += hv.x; acc.y += hv.y;
    }
    acc.x *= (1.f / NN); acc.y *= (1.f / NN);
  }
  float vx = acc.x > 0.f ? acc.x : expm1f(acc.x);
  float vy = acc.y > 0.f ? acc.y : expm1f(acc.y);
  float* dst = half ? lsd_s : mn_s;
  dst[2 * t] = vx; dst[2 * t + 1] = vy;
  __syncthreads();
  u16* row = zcat + (size_t)i * 288;
  if (tid < 128) {
    const int f = 2 * tid;
    float2 nz = *(const float2*)(noise + (size_t)i * 256 + f);
    float zx = fmaf(nz.x, expf(lsd_s[f]), mn_s[f]);
    float zy = fmaf(nz.y, expf(lsd_s[f + 1]), mn_s[f + 1]);
    *(u16x2*)(row + f) = u16x2{f2bf(zx), f2bf(zy)};
  } else if (tid < 136) {
    const int k = tid - 128;
    float2 yv = *(const float2*)(Y + (size_t)i * 16 + 2 * k);
    *(u16x2*)(row + 256 + 2 * k) = u16x2{f2bf(yv.x), f2bf(yv.y)};
  } else if (tid < 144) {
    *(u16x2*)(row + 272 + 2 * (tid - 136)) = u16x2{0, 0};
  }
}

extern "C" void kernel_launch(void* const* d_in, const int* in_sizes, int n_in,
                              void* d_out, int out_size, void* d_ws, size_t ws_size,
                              hipStream_t stream)
{
  const float* X     = (const float*)d_in[0];
  const float* Y     = (const float*)d_in[1];
  const float* noise = (const float*)d_in[2];
  const void*  adj   = d_in[3];
  const float* W0    = (const float*)d_in[4];
  const float* a0    = (const float*)d_in[5];
  const float* W1    = (const float*)d_in[6];
  const float* a1    = (const float*)d_in[7];
  const float* W2    = (const float*)d_in[8];
  const float* a2    = (const float*)d_in[9];
  const float* fc1w  = (const float*)d_in[10];
  const float* fc1b  = (const float*)d_in[11];
  const float* fc2w  = (const float*)d_in[12];
  const float* fc2b  = (const float*)d_in[13];
  float* out = (float*)d_out;
  char* W = (char*)d_ws;

  // workspace layout (bytes), ~31.7 MB
  u16*   Xb    = (u16*)(W + 0);            // 4096x1024 bf16 (dead after gemm0)
  u16*   zcatb = (u16*)(W + 0);            // 4096x288 bf16
  u16*   zzb   = (u16*)(W + 2359296);      // 4096x512 bf16
  u16*   h0b   = (u16*)(W + 8388608);      // 4096x512 bf16 (dead after agg0)
  float* h12   = (float*)(W + 8388608);    // 4096x512 f32 (reuses h0b region)
  u16*   hb    = (u16*)(W + 16777216);     // 4096x544 bf16
  u16*   W0t   = (u16*)(W + 21233664);     // 512x1024
  u16*   W12t  = (u16*)(W + 22282240);     // 512x544 (rows 0-255: W1t, 256-511: W2t)
  u16*   fc1t  = (u16*)(W + 22839296);     // 512x288
  u16*   fc2t  = (u16*)(W + 23134208);     // 4096x512
  int*   nbr   = (int*)(W + 27328512);     // 4096x256 int
  int*   cnt   = (int*)(W + 31522816);     // 4096 int
  float* fs0   = (float*)(W + 31539200);
  float* fd0   = fs0 + 4096;
  float* fs1   = fd0 + 4096;
  float* fd1   = fs1 + 4096;
  float* fs2   = fd1 + 4096;
  float* fd2   = fs2 + 4096;
  int*   flag  = (int*)(fd2 + 4096);

  zero_flag<<<1, 64, 0, stream>>>(flag);
  detect_adj<<<256, 256, 0, stream>>>((const unsigned int*)adj, 524288, flag);
  build_csr<<<4096, 256, 0, stream>>>(adj, flag, nbr, cnt);

  // weight transposes (f32 -> bf16, [N][Kpad])
  transpose_w<<<dim3(16, 32), dim3(32, 8), 0, stream>>>(W0, W0t, 1024, 512, 1024);
  transpose_w2<<<dim3(8, 17, 2), dim3(32, 8), 0, stream>>>(W1, W12t, W2, W12t + 256 * 544, 528, 256, 544);
  transpose_w<<<dim3(16, 9),  dim3(32, 8), 0, stream>>>(fc1w, fc1t, 272, 512, 288);
  transpose_w<<<dim3(128, 16), dim3(32, 8), 0, stream>>>(fc2w, fc2t, 512, 4096, 512);
  f32_to_bf16_v4<<<4096, 256, 0, stream>>>(X, Xb);

  // GAT layer 0 (h0 kept in bf16 for the gather)
  gemm_mfma<0,true><<<dim3(4, 32), 256, 0, stream>>>(Xb, 1024, W0t, 1024, h0b, 512, 4096, 512, 1024, nullptr);
  fsrc_fdst_bf16<<<1024, 256, 0, stream>>>(h0b, a0, fs0, fd0);
  agg_gat0<<<4096, 256, 0, stream>>>(h0b, fs0, fd0, nbr, cnt, Y, hb);

  // GAT layers 1 & 2 merged: h12 = hb @ [W1|W2] (f32 for accuracy on logstd path)
  gemm_mfma<0,false><<<dim3(4, 32), 256, 0, stream>>>(hb, 544, W12t, 544, h12, 512, 4096, 512, 544, nullptr);
  fsrc_fdst12<<<1024, 256, 0, stream>>>(h12, a1, a2, fs1, fd1, fs2, fd2);
  agg_gat12<<<4096, 256, 0, stream>>>(h12, fs1, fd1, fs2, fd2, nbr, cnt, noise, Y, zcatb);

  // decoder
  gemm_mfma<1,true><<<dim3(4, 32), 256, 0, stream>>>(zcatb, 288, fc1t, 288, zzb, 512, 4096, 512, 288, fc1b);
  gemm_mfma256<2><<<dim3(16, 16), 512, 0, stream>>>(zzb, 512, fc2t, 512, out, 4096, 512, fc2b);
}

// Round 6
// 157.576 us; speedup vs baseline: 3.5671x; 1.1234x over previous
//
#include <hip/hip_runtime.h>

#define LRELU_ALPHA 0.2f
#define NN 4096
#define CAP 256

typedef unsigned short u16;
typedef short bf16x8 __attribute__((ext_vector_type(8)));
typedef float f32x4 __attribute__((ext_vector_type(4)));
typedef u16 u16x4 __attribute__((ext_vector_type(4)));
typedef u16 u16x2 __attribute__((ext_vector_type(2)));
typedef u16 u16x8 __attribute__((ext_vector_type(8)));

__device__ __forceinline__ u16 f2bf(float f) {
  unsigned u = __float_as_uint(f);
  u += 0x7FFFu + ((u >> 16) & 1u);
  return (u16)(u >> 16);
}
__device__ __forceinline__ float bf2f(u16 u) {
  return __uint_as_float(((unsigned)u) << 16);
}

__device__ __forceinline__ float waveSum(float v) {
  #pragma unroll
  for (int o = 32; o > 0; o >>= 1) v += __shfl_down(v, o, 64);
  return v;
}
__device__ __forceinline__ float waveMax(float v) {
  #pragma unroll
  for (int o = 32; o > 0; o >>= 1) v = fmaxf(v, __shfl_down(v, o, 64));
  return v;
}

__device__ __forceinline__ bool adj_test(const void* adj, size_t idx, int mode) {
  if (mode == 1) return ((const unsigned char*)adj)[idx] != 0;
  if (mode == 0) return ((const int*)adj)[idx] != 0;
  return ((const float*)adj)[idx] != 0.0f;
}

__device__ __forceinline__ void gload_lds16(const void* g, void* l) {
  __builtin_amdgcn_global_load_lds((const __attribute__((address_space(1))) void*)g,
                                   (__attribute__((address_space(3))) void*)l, 16, 0, 0);
}

// ---- adj dtype probe (2MB sample)
__global__ __launch_bounds__(256) void detect_adj(const unsigned int* __restrict__ w,
                                                  int nwords, int* flag) {
  int f = 0;
  for (int idx = blockIdx.x * 256 + threadIdx.x; idx < nwords; idx += gridDim.x * 256) {
    unsigned int v = w[idx];
    if (v == 0x3F800000u) f |= 1;
    else if (v > 1u) f |= 2;
  }
  if (f) atomicOr(flag, f);
}

// ---- CSR build: one block per row, single adj pass
__global__ __launch_bounds__(256) void build_csr(const void* __restrict__ adj,
                                                 const int* __restrict__ adjflag,
                                                 int* __restrict__ nbr,
                                                 int* __restrict__ cnt)
{
  __shared__ int scn[256];
  const int i = blockIdx.x, tid = threadIdx.x;
  const int fmask = *adjflag;
  const int mode = (fmask & 1) ? 2 : ((fmask & 2) ? 1 : 0);
  const size_t base = (size_t)i * NN;
  unsigned bits = 0;
  #pragma unroll
  for (int k = 0; k < 16; ++k) {
    int j = tid + (k << 8);
    if (adj_test(adj, base + j, mode)) bits |= (1u << k);
  }
  int mycnt = __popc(bits);
  scn[tid] = mycnt;
  __syncthreads();
  for (int off = 1; off < 256; off <<= 1) {
    int v = (tid >= off) ? scn[tid - off] : 0;
    __syncthreads();
    scn[tid] += v;
    __syncthreads();
  }
  const int total = scn[255];
  int pos = scn[tid] - mycnt;
  #pragma unroll
  for (int k = 0; k < 16; ++k) {
    if (bits & (1u << k)) {
      if (pos < CAP) nbr[(size_t)i * CAP + pos] = tid + (k << 8);
      ++pos;
    }
  }
  if (tid == 0) cnt[i] = total;
}

// ---- transpose helper: Wt[n][k] (bf16, ld=Kpad) from W[k][n] (f32)
__device__ __forceinline__ void transpose_body(const float* Wsrc, u16* Wt,
                                               int K, int N, int Kpad,
                                               int bx, int by) {
  __shared__ float t[32][33];
  const int kb = by * 32, nb = bx * 32;
  const int tx = threadIdx.x, ty = threadIdx.y;  // 32 x 8
  for (int i = ty; i < 32; i += 8) {
    int k = kb + i, n = nb + tx;
    t[i][tx] = (k < K && n < N) ? Wsrc[(size_t)k * N + n] : 0.f;
  }
  __syncthreads();
  for (int i = ty; i < 32; i += 8) {
    int n = nb + i, k = kb + tx;
    if (n < N && k < Kpad) Wt[(size_t)n * Kpad + k] = f2bf(t[tx][i]);
  }
}

// ---- ALL weight transposes + X f32->bf16 + flag zero in ONE dispatch
// ranges: [0,2048) fc2 | [2048,2560) W0 | [2560,2696) W1 | [2696,2832) W2 |
//         [2832,2976) fc1 | [2976,7072) X convert
__global__ __launch_bounds__(256) void prep_all(
    const float* __restrict__ W0, u16* __restrict__ W0t,
    const float* __restrict__ W1, u16* __restrict__ W1t,
    const float* __restrict__ W2, u16* __restrict__ W2t,
    const float* __restrict__ fc1w, u16* __restrict__ fc1t,
    const float* __restrict__ fc2w, u16* __restrict__ fc2t,
    const float* __restrict__ X, u16* __restrict__ Xb,
    int* __restrict__ flag)
{
  const int i = blockIdx.x;
  if (i == 0 && threadIdx.x == 0 && threadIdx.y == 0) *flag = 0;
  if (i < 2048) {
    transpose_body(fc2w, fc2t, 512, 4096, 512, i & 127, i >> 7);
  } else if (i < 2560) {
    int j = i - 2048;
    transpose_body(W0, W0t, 1024, 512, 1024, j & 15, j >> 4);
  } else if (i < 2696) {
    int j = i - 2560;
    transpose_body(W1, W1t, 528, 256, 544, j & 7, j >> 3);
  } else if (i < 2832) {
    int j = i - 2696;
    transpose_body(W2, W2t, 528, 256, 544, j & 7, j >> 3);
  } else if (i < 2976) {
    int j = i - 2832;
    transpose_body(fc1w, fc1t, 272, 512, 288, j & 15, j >> 4);
  } else {
    int j = i - 2976;
    int idx = j * 256 + threadIdx.y * 32 + threadIdx.x;
    float4 v = ((const float4*)X)[idx];
    u16x4 o = {f2bf(v.x), f2bf(v.y), f2bf(v.z), f2bf(v.w)};
    ((u16x4*)Xb)[idx] = o;
  }
}

// ---- bf16 MFMA GEMM 128x128 tile, BK=32, 4 waves, dbuf + counted vmcnt depth-2
template<int ACT, bool OBF>   // ACT 0=none 1=relu 2=sigmoid
__global__ __launch_bounds__(256) void gemm_mfma(
    const u16* __restrict__ A, int lda,
    const u16* __restrict__ Bt, int ldb,
    void* __restrict__ Cout, int ldc,
    int K, const float* __restrict__ bias)
{
  __shared__ u16 As[2][128 * 32];
  __shared__ u16 Bs[2][128 * 32];
  const int tid = threadIdx.x;
  const int lane = tid & 63, wv = tid >> 6;
  const int wm = wv >> 1, wn = wv & 1;
  const int m0 = blockIdx.y * 128, n0 = blockIdx.x * 128;
  const int nk = K >> 5;

  f32x4 acc[4][4] = {};

  auto STAGE = [&](int buf, int kt) {   // 4 loads/thread
    #pragma unroll
    for (int i = 0; i < 2; ++i) {
      int c = tid + i * 256;
      int r = c >> 2;
      int s = (c & 3) ^ ((r >> 1) & 3);
      gload_lds16(A + (size_t)(m0 + r) * lda + kt * 32 + s * 8, (char*)As[buf] + (c & ~63) * 16);
      gload_lds16(Bt + (size_t)(n0 + r) * ldb + kt * 32 + s * 8, (char*)Bs[buf] + (c & ~63) * 16);
    }
  };

  STAGE(0, 0);
  if (nk > 1) STAGE(1, 1);

  int cur = 0;
  for (int kt = 0; kt < nk; ++kt) {
    if (kt + 1 < nk) { asm volatile("s_waitcnt vmcnt(4)" ::: "memory"); }
    else             { asm volatile("s_waitcnt vmcnt(0)" ::: "memory"); }
    __builtin_amdgcn_s_barrier();

    bf16x8 af[4], bf_[4];
    #pragma unroll
    for (int mi = 0; mi < 4; ++mi) {
      int r = wm * 64 + mi * 16 + (lane & 15);
      int sp = (lane >> 4) ^ ((r >> 1) & 3);
      af[mi] = *(const bf16x8*)((const char*)As[cur] + r * 64 + sp * 16);
    }
    #pragma unroll
    for (int ni = 0; ni < 4; ++ni) {
      int r = wn * 64 + ni * 16 + (lane & 15);
      int sp = (lane >> 4) ^ ((r >> 1) & 3);
      bf_[ni] = *(const bf16x8*)((const char*)Bs[cur] + r * 64 + sp * 16);
    }
    __builtin_amdgcn_s_setprio(1);
    #pragma unroll
    for (int mi = 0; mi < 4; ++mi)
      #pragma unroll
      for (int ni = 0; ni < 4; ++ni)
        acc[mi][ni] = __builtin_amdgcn_mfma_f32_16x16x32_bf16(af[mi], bf_[ni], acc[mi][ni], 0, 0, 0);
    __builtin_amdgcn_s_setprio(0);

    __builtin_amdgcn_s_barrier();          // all waves done reading buf cur
    if (kt + 2 < nk) STAGE(cur, kt + 2);
    cur ^= 1;
  }

  #pragma unroll
  for (int ni = 0; ni < 4; ++ni) {
    const int col = n0 + wn * 64 + ni * 16 + (lane & 15);
    const float bv = bias ? bias[col] : 0.f;
    #pragma unroll
    for (int mi = 0; mi < 4; ++mi) {
      const int row0 = m0 + wm * 64 + mi * 16 + (lane >> 4) * 4;
      #pragma unroll
      for (int j = 0; j < 4; ++j) {
        float v = acc[mi][ni][j] + bv;
        if (ACT == 1) v = fmaxf(v, 0.f);
        if (ACT == 2) v = 1.f / (1.f + expf(-v));
        if (OBF) ((u16*)Cout)[(size_t)(row0 + j) * ldc + col] = f2bf(v);
        else     ((float*)Cout)[(size_t)(row0 + j) * ldc + col] = v;
      }
    }
  }
}

// ---- bf16 MFMA GEMM 128x64 tile (for N=512 GEMMs: 2x the blocks -> full CU coverage)
// 4 waves 2x2, wave tile 64x32; LDS 24KB -> ~6 blocks/CU
template<int ACT, bool OBF>
__global__ __launch_bounds__(256) void gemm_mfma64(
    const u16* __restrict__ A, int lda,
    const u16* __restrict__ Bt, int ldb,
    void* __restrict__ Cout, int ldc,
    int K, const float* __restrict__ bias)
{
  __shared__ u16 As[2][128 * 32];
  __shared__ u16 Bs[2][64 * 32];
  const int tid = threadIdx.x;
  const int lane = tid & 63, wv = tid >> 6;
  const int wm = wv >> 1, wn = wv & 1;
  const int m0 = blockIdx.y * 128, n0 = blockIdx.x * 64;
  const int nk = K >> 5;

  f32x4 acc[4][2] = {};

  auto STAGE = [&](int buf, int kt) {   // 3 loads/thread
    #pragma unroll
    for (int i = 0; i < 2; ++i) {
      int c = tid + i * 256;
      int r = c >> 2;
      int s = (c & 3) ^ ((r >> 1) & 3);
      gload_lds16(A + (size_t)(m0 + r) * lda + kt * 32 + s * 8, (char*)As[buf] + (c & ~63) * 16);
    }
    {
      int c = tid;
      int r = c >> 2;
      int s = (c & 3) ^ ((r >> 1) & 3);
      gload_lds16(Bt + (size_t)(n0 + r) * ldb + kt * 32 + s * 8, (char*)Bs[buf] + (c & ~63) * 16);
    }
  };

  STAGE(0, 0);
  if (nk > 1) STAGE(1, 1);

  int cur = 0;
  for (int kt = 0; kt < nk; ++kt) {
    if (kt + 1 < nk) { asm volatile("s_waitcnt vmcnt(3)" ::: "memory"); }
    else             { asm volatile("s_waitcnt vmcnt(0)" ::: "memory"); }
    __builtin_amdgcn_s_barrier();

    bf16x8 af[4], bf_[2];
    #pragma unroll
    for (int mi = 0; mi < 4; ++mi) {
      int r = wm * 64 + mi * 16 + (lane & 15);
      int sp = (lane >> 4) ^ ((r >> 1) & 3);
      af[mi] = *(const bf16x8*)((const char*)As[cur] + r * 64 + sp * 16);
    }
    #pragma unroll
    for (int ni = 0; ni < 2; ++ni) {
      int r = wn * 32 + ni * 16 + (lane & 15);
      int sp = (lane >> 4) ^ ((r >> 1) & 3);
      bf_[ni] = *(const bf16x8*)((const char*)Bs[cur] + r * 64 + sp * 16);
    }
    __builtin_amdgcn_s_setprio(1);
    #pragma unroll
    for (int mi = 0; mi < 4; ++mi)
      #pragma unroll
      for (int ni = 0; ni < 2; ++ni)
        acc[mi][ni] = __builtin_amdgcn_mfma_f32_16x16x32_bf16(af[mi], bf_[ni], acc[mi][ni], 0, 0, 0);
    __builtin_amdgcn_s_setprio(0);

    __builtin_amdgcn_s_barrier();
    if (kt + 2 < nk) STAGE(cur, kt + 2);
    cur ^= 1;
  }

  #pragma unroll
  for (int ni = 0; ni < 2; ++ni) {
    const int col = n0 + wn * 32 + ni * 16 + (lane & 15);
    const float bv = bias ? bias[col] : 0.f;
    #pragma unroll
    for (int mi = 0; mi < 4; ++mi) {
      const int row0 = m0 + wm * 64 + mi * 16 + (lane >> 4) * 4;
      #pragma unroll
      for (int j = 0; j < 4; ++j) {
        float v = acc[mi][ni][j] + bv;
        if (ACT == 1) v = fmaxf(v, 0.f);
        if (ACT == 2) v = 1.f / (1.f + expf(-v));
        if (OBF) ((u16*)Cout)[(size_t)(row0 + j) * ldc + col] = f2bf(v);
        else     ((float*)Cout)[(size_t)(row0 + j) * ldc + col] = v;
      }
    }
  }
}

// ---- per-row attention scores, bf16 h (layer 0, F=512)
__global__ __launch_bounds__(256) void fsrc_fdst_bf16(
    const u16* __restrict__ h, const float* __restrict__ a,
    float* __restrict__ fs, float* __restrict__ fd)
{
  const int wid = threadIdx.x >> 6, lane = threadIdx.x & 63;
  const int row = blockIdx.x * 4 + wid;
  u16x8 hv = *(const u16x8*)(h + (size_t)row * 512 + lane * 8);
  float s0 = 0.f, s1 = 0.f;
  #pragma unroll
  for (int j = 0; j < 8; ++j) {
    float x = bf2f(hv[j]);
    s0 = fmaf(x, a[lane * 8 + j], s0);
    s1 = fmaf(x, a[512 + lane * 8 + j], s1);
  }
  s0 = waveSum(s0);
  s1 = waveSum(s1);
  if (lane == 0) { fs[row] = s0; fd[row] = s1; }
}

// ---- merged scores for layers 1&2 over h12 [4096][512] f32
__global__ __launch_bounds__(256) void fsrc_fdst12(
    const float* __restrict__ h12,
    const float* __restrict__ a1, const float* __restrict__ a2,
    float* __restrict__ fs1, float* __restrict__ fd1,
    float* __restrict__ fs2, float* __restrict__ fd2)
{
  const int wid = threadIdx.x >> 6, lane = threadIdx.x & 63;
  const int row = blockIdx.x * 4 + wid;
  const float* hr = h12 + (size_t)row * 512;
  float s0 = 0.f, s1 = 0.f, s2 = 0.f, s3 = 0.f;
  #pragma unroll
  for (int f = lane; f < 256; f += 64) {
    float h1v = hr[f], h2v = hr[256 + f];
    s0 = fmaf(h1v, a1[f], s0);
    s1 = fmaf(h1v, a1[256 + f], s1);
    s2 = fmaf(h2v, a2[f], s2);
    s3 = fmaf(h2v, a2[256 + f], s3);
  }
  s0 = waveSum(s0); s1 = waveSum(s1); s2 = waveSum(s2); s3 = waveSum(s3);
  if (lane == 0) { fs1[row] = s0; fd1[row] = s1; fs2[row] = s2; fd2[row] = s3; }
}

// ---- layer-0 aggregate via CSR (bf16 h): hb[row] = [elu(att@h0) (512) | Y (16) | 0 (16)]
__global__ __launch_bounds__(256) void agg_gat0(
    const u16* __restrict__ h,
    const float* __restrict__ fs, const float* __restrict__ fd,
    const int* __restrict__ nbr, const int* __restrict__ cnt,
    const float* __restrict__ Y, u16* __restrict__ hb)
{
  __shared__ int   nb[CAP];
  __shared__ float pbuf[CAP];
  __shared__ float redm[4], reds[4];
  const int i = blockIdx.x, tid = threadIdx.x;
  const int wid = tid >> 6, lane = tid & 63;
  int c = cnt[i]; if (c > CAP) c = CAP;
  const float fsi = fs[i];
  float2 acc = {0.f, 0.f};

  if (c > 0) {
    float e = -3.0e38f;
    if (tid < c) {
      int j = nbr[(size_t)i * CAP + tid];
      nb[tid] = j;
      float t = fsi + fd[j];
      e = t > 0.f ? t : LRELU_ALPHA * t;
    }
    float wm = waveMax(e);
    if (lane == 0) redm[wid] = wm;
    __syncthreads();
    const float gmax = fmaxf(fmaxf(redm[0], redm[1]), fmaxf(redm[2], redm[3]));
    float p = (tid < c) ? expf(e - gmax) : 0.f;
    float ws = waveSum(p);
    if (lane == 0) reds[wid] = ws;
    __syncthreads();
    const float inv = 1.f / (reds[0] + reds[1] + reds[2] + reds[3]);
    if (tid < c) pbuf[tid] = p * inv;
    __syncthreads();
    const u16* hp = h + 2 * tid;
    #pragma unroll 4
    for (int n = 0; n < c; ++n) {
      u16x2 hv = *(const u16x2*)(hp + (size_t)nb[n] * 512);
      float pn = pbuf[n];
      acc.x = fmaf(pn, bf2f(hv[0]), acc.x);
      acc.y = fmaf(pn, bf2f(hv[1]), acc.y);
    }
  } else {
    const u16* hp = h + 2 * tid;
    for (int j = 0; j < NN; ++j) {
      u16x2 hv = *(const u16x2*)(hp + (size_t)j * 512);
      acc.x += bf2f(hv[0]); acc.y += bf2f(hv[1]);
    }
    acc.x *= (1.f / NN); acc.y *= (1.f / NN);
  }
  float vx = acc.x > 0.f ? acc.x : expm1f(acc.x);
  float vy = acc.y > 0.f ? acc.y : expm1f(acc.y);
  u16* row = hb + (size_t)i * 544;
  *(u16x2*)(row + 2 * tid) = u16x2{f2bf(vx), f2bf(vy)};
  if (tid < 8) {
    float2 yv = *(const float2*)(Y + (size_t)i * 16 + 2 * tid);
    *(u16x2*)(row + 512 + 2 * tid) = u16x2{f2bf(yv.x), f2bf(yv.y)};
  } else if (tid < 16) {
    *(u16x2*)(row + 528 + 2 * (tid - 8)) = u16x2{0, 0};
  }
}

// ---- fused layers 1+2 aggregate + reparam + concat (h12 f32, ld=512)
__global__ __launch_bounds__(256) void agg_gat12(
    const float* __restrict__ h12,
    const float* __restrict__ fs1, const float* __restrict__ fd1,
    const float* __restrict__ fs2, const float* __restrict__ fd2,
    const int* __restrict__ nbr, const int* __restrict__ cnt,
    const float* __restrict__ noise, const float* __restrict__ Y,
    u16* __restrict__ zcat)
{
  __shared__ int   nb[CAP];
  __shared__ float p1[CAP], p2[CAP];
  __shared__ float mn_s[256], lsd_s[256];
  __shared__ float redm1[4], redm2[4], reds1[4], reds2[4];
  const int i = blockIdx.x, tid = threadIdx.x;
  const int wid = tid >> 6, lane = tid & 63;
  int c = cnt[i]; if (c > CAP) c = CAP;
  const int half = tid >> 7, t = tid & 127;

  float2 acc = {0.f, 0.f};
  if (c > 0) {
    float e1 = -3.0e38f, e2 = -3.0e38f;
    if (tid < c) {
      int j = nbr[(size_t)i * CAP + tid];
      nb[tid] = j;
      float a1v = fs1[i] + fd1[j];
      float a2v = fs2[i] + fd2[j];
      e1 = a1v > 0.f ? a1v : LRELU_ALPHA * a1v;
      e2 = a2v > 0.f ? a2v : LRELU_ALPHA * a2v;
    }
    float wm1 = waveMax(e1), wm2 = waveMax(e2);
    if (lane == 0) { redm1[wid] = wm1; redm2[wid] = wm2; }
    __syncthreads();
    const float g1 = fmaxf(fmaxf(redm1[0], redm1[1]), fmaxf(redm1[2], redm1[3]));
    const float g2 = fmaxf(fmaxf(redm2[0], redm2[1]), fmaxf(redm2[2], redm2[3]));
    float pp1 = (tid < c) ? expf(e1 - g1) : 0.f;
    float pp2 = (tid < c) ? expf(e2 - g2) : 0.f;
    float ws1 = waveSum(pp1), ws2 = waveSum(pp2);
    if (lane == 0) { reds1[wid] = ws1; reds2[wid] = ws2; }
    __syncthreads();
    const float inv1 = 1.f / (reds1[0] + reds1[1] + reds1[2] + reds1[3]);
    const float inv2 = 1.f / (reds2[0] + reds2[1] + reds2[2] + reds2[3]);
    if (tid < c) { p1[tid] = pp1 * inv1; p2[tid] = pp2 * inv2; }
    __syncthreads();
    const float* hh = h12 + (half ? 256 : 0) + 2 * t;
    const float* pp = half ? p2 : p1;
    #pragma unroll 4
    for (int n = 0; n < c; ++n) {
      float2 hv = *(const float2*)(hh + (size_t)nb[n] * 512);
      float pn = pp[n];
      acc.x = fmaf(pn, hv.x, acc.x);
      acc.y = fmaf(pn, hv.y, acc.y);
    }
  } else {
    const float* hh = h12 + (half ? 256 : 0) + 2 * t;
    for (int j = 0; j < NN; ++j) {
      float2 hv = *(const float2*)(hh + (size_t)j * 512);
      acc.x += hv.x; acc.y += hv.y;
    }
    acc.x *= (1.f / NN); acc.y *= (1.f / NN);
  }
  float vx = acc.x > 0.f ? acc.x : expm1f(acc.x);
  float vy = acc.y > 0.f ? acc.y : expm1f(acc.y);
  float* dst = half ? lsd_s : mn_s;
  dst[2 * t] = vx; dst[2 * t + 1] = vy;
  __syncthreads();
  u16* row = zcat + (size_t)i * 288;
  if (tid < 128) {
    const int f = 2 * tid;
    float2 nz = *(const float2*)(noise + (size_t)i * 256 + f);
    float zx = fmaf(nz.x, expf(lsd_s[f]), mn_s[f]);
    float zy = fmaf(nz.y, expf(lsd_s[f + 1]), mn_s[f + 1]);
    *(u16x2*)(row + f) = u16x2{f2bf(zx), f2bf(zy)};
  } else if (tid < 136) {
    const int k = tid - 128;
    float2 yv = *(const float2*)(Y + (size_t)i * 16 + 2 * k);
    *(u16x2*)(row + 256 + 2 * k) = u16x2{f2bf(yv.x), f2bf(yv.y)};
  } else if (tid < 144) {
    *(u16x2*)(row + 272 + 2 * (tid - 136)) = u16x2{0, 0};
  }
}

extern "C" void kernel_launch(void* const* d_in, const int* in_sizes, int n_in,
                              void* d_out, int out_size, void* d_ws, size_t ws_size,
                              hipStream_t stream)
{
  const float* X     = (const float*)d_in[0];
  const float* Y     = (const float*)d_in[1];
  const float* noise = (const float*)d_in[2];
  const void*  adj   = d_in[3];
  const float* W0    = (const float*)d_in[4];
  const float* a0    = (const float*)d_in[5];
  const float* W1    = (const float*)d_in[6];
  const float* a1    = (const float*)d_in[7];
  const float* W2    = (const float*)d_in[8];
  const float* a2    = (const float*)d_in[9];
  const float* fc1w  = (const float*)d_in[10];
  const float* fc1b  = (const float*)d_in[11];
  const float* fc2w  = (const float*)d_in[12];
  const float* fc2b  = (const float*)d_in[13];
  float* out = (float*)d_out;
  char* W = (char*)d_ws;

  // workspace layout (bytes), ~31.7 MB
  u16*   Xb    = (u16*)(W + 0);            // 4096x1024 bf16 (dead after gemm0)
  u16*   zcatb = (u16*)(W + 0);            // 4096x288 bf16
  u16*   zzb   = (u16*)(W + 2359296);      // 4096x512 bf16
  u16*   h0b   = (u16*)(W + 8388608);      // 4096x512 bf16 (dead after agg0)
  float* h12   = (float*)(W + 8388608);    // 4096x512 f32 (reuses h0b region)
  u16*   hb    = (u16*)(W + 16777216);     // 4096x544 bf16
  u16*   W0t   = (u16*)(W + 21233664);     // 512x1024
  u16*   W12t  = (u16*)(W + 22282240);     // 512x544 (rows 0-255: W1t, 256-511: W2t)
  u16*   fc1t  = (u16*)(W + 22839296);     // 512x288
  u16*   fc2t  = (u16*)(W + 23134208);     // 4096x512
  int*   nbr   = (int*)(W + 27328512);     // 4096x256 int
  int*   cnt   = (int*)(W + 31522816);     // 4096 int
  float* fs0   = (float*)(W + 31539200);
  float* fd0   = fs0 + 4096;
  float* fs1   = fd0 + 4096;
  float* fd1   = fs1 + 4096;
  float* fs2   = fd1 + 4096;
  float* fd2   = fs2 + 4096;
  int*   flag  = (int*)(fd2 + 4096);

  // prep: all transposes + X convert + flag zero (stream-ordered before detect_adj)
  prep_all<<<7072, dim3(32, 8), 0, stream>>>(W0, W0t, W1, W12t, W2, W12t + 256 * 544,
                                             fc1w, fc1t, fc2w, fc2t, X, Xb, flag);
  detect_adj<<<256, 256, 0, stream>>>((const unsigned int*)adj, 524288, flag);
  build_csr<<<4096, 256, 0, stream>>>(adj, flag, nbr, cnt);

  // GAT layer 0 (h0 in bf16 for the gather)
  gemm_mfma64<0,true><<<dim3(8, 32), 256, 0, stream>>>(Xb, 1024, W0t, 1024, h0b, 512, 1024, nullptr);
  fsrc_fdst_bf16<<<1024, 256, 0, stream>>>(h0b, a0, fs0, fd0);
  agg_gat0<<<4096, 256, 0, stream>>>(h0b, fs0, fd0, nbr, cnt, Y, hb);

  // GAT layers 1 & 2 merged: h12 = hb @ [W1|W2] (f32)
  gemm_mfma64<0,false><<<dim3(8, 32), 256, 0, stream>>>(hb, 544, W12t, 544, h12, 512, 544, nullptr);
  fsrc_fdst12<<<1024, 256, 0, stream>>>(h12, a1, a2, fs1, fd1, fs2, fd2);
  agg_gat12<<<4096, 256, 0, stream>>>(h12, fs1, fd1, fs2, fd2, nbr, cnt, noise, Y, zcatb);

  // decoder
  gemm_mfma64<1,true><<<dim3(8, 32), 256, 0, stream>>>(zcatb, 288, fc1t, 288, zzb, 512, 288, fc1b);
  gemm_mfma<2,false><<<dim3(32, 32), 256, 0, stream>>>(zzb, 512, fc2t, 512, out, 4096, 512, fc2b);
}

// Round 7
// 148.803 us; speedup vs baseline: 3.7774x; 1.0590x over previous
//
#include <hip/hip_runtime.h>

#define LRELU_ALPHA 0.2f
#define NN 4096
#define CAP 256

typedef unsigned short u16;
typedef short bf16x8 __attribute__((ext_vector_type(8)));
typedef float f32x4 __attribute__((ext_vector_type(4)));
typedef u16 u16x4 __attribute__((ext_vector_type(4)));
typedef u16 u16x2 __attribute__((ext_vector_type(2)));
typedef u16 u16x8 __attribute__((ext_vector_type(8)));

__device__ __forceinline__ u16 f2bf(float f) {
  unsigned u = __float_as_uint(f);
  u += 0x7FFFu + ((u >> 16) & 1u);
  return (u16)(u >> 16);
}
__device__ __forceinline__ float bf2f(u16 u) {
  return __uint_as_float(((unsigned)u) << 16);
}

__device__ __forceinline__ float waveSum(float v) {
  #pragma unroll
  for (int o = 32; o > 0; o >>= 1) v += __shfl_down(v, o, 64);
  return v;
}
__device__ __forceinline__ float waveMax(float v) {
  #pragma unroll
  for (int o = 32; o > 0; o >>= 1) v = fmaxf(v, __shfl_down(v, o, 64));
  return v;
}

__device__ __forceinline__ void gload_lds16(const void* g, void* l) {
  __builtin_amdgcn_global_load_lds((const __attribute__((address_space(1))) void*)g,
                                   (__attribute__((address_space(3))) void*)l, 16, 0, 0);
}

// ---- adj dtype probe (2MB sample)
__global__ __launch_bounds__(256) void detect_adj(const unsigned int* __restrict__ w,
                                                  int nwords, int* flag) {
  int f = 0;
  for (int idx = blockIdx.x * 256 + threadIdx.x; idx < nwords; idx += gridDim.x * 256) {
    unsigned int v = w[idx];
    if (v == 0x3F800000u) f |= 1;
    else if (v > 1u) f |= 2;
  }
  if (f) atomicOr(flag, f);
}

// ---- CSR build: one block per row, single pass, uint4-vectorized (16 elems/thread)
__global__ __launch_bounds__(256) void build_csr(const unsigned* __restrict__ adjw,
                                                 const int* __restrict__ adjflag,
                                                 int* __restrict__ nbr,
                                                 int* __restrict__ cnt)
{
  __shared__ int scn[256];
  const int i = blockIdx.x, tid = threadIdx.x;
  const int fmask = *adjflag;
  const bool bytemode = (fmask & 2) && !(fmask & 1);
  unsigned bits = 0;
  if (!bytemode) {
    // 4-byte elements (int32 or f32): 4096 words/row; nonzero word == true
    const unsigned* row = adjw + (size_t)i * 4096 + tid * 16;
    #pragma unroll
    for (int ck = 0; ck < 4; ++ck) {
      uint4 v = *(const uint4*)(row + ck * 4);
      if (v.x) bits |= 1u << (ck * 4 + 0);
      if (v.y) bits |= 1u << (ck * 4 + 1);
      if (v.z) bits |= 1u << (ck * 4 + 2);
      if (v.w) bits |= 1u << (ck * 4 + 3);
    }
  } else {
    // byte-bool: 1024 words/row; 16 bytes/thread
    const unsigned* row = adjw + (size_t)i * 1024 + tid * 4;
    uint4 v = *(const uint4*)row;
    unsigned w4[4] = {v.x, v.y, v.z, v.w};
    #pragma unroll
    for (int wi = 0; wi < 4; ++wi)
      #pragma unroll
      for (int b = 0; b < 4; ++b)
        if ((w4[wi] >> (b * 8)) & 0xFFu) bits |= 1u << (wi * 4 + b);
  }
  int mycnt = __popc(bits);
  scn[tid] = mycnt;
  __syncthreads();
  for (int off = 1; off < 256; off <<= 1) {
    int v = (tid >= off) ? scn[tid - off] : 0;
    __syncthreads();
    scn[tid] += v;
    __syncthreads();
  }
  const int total = scn[255];
  int pos = scn[tid] - mycnt;
  #pragma unroll
  for (int b = 0; b < 16; ++b) {
    if (bits & (1u << b)) {
      if (pos < CAP) nbr[(size_t)i * CAP + pos] = tid * 16 + b;
      ++pos;
    }
  }
  if (tid == 0) cnt[i] = total;
}

// ---- transpose helper: Wt[n][k] (bf16, ld=Kpad) from W[k][n] (f32)
__device__ __forceinline__ void transpose_body(const float* Wsrc, u16* Wt,
                                               int K, int N, int Kpad,
                                               int bx, int by) {
  __shared__ float t[32][33];
  const int kb = by * 32, nb = bx * 32;
  const int tx = threadIdx.x, ty = threadIdx.y;  // 32 x 8
  for (int i = ty; i < 32; i += 8) {
    int k = kb + i, n = nb + tx;
    t[i][tx] = (k < K && n < N) ? Wsrc[(size_t)k * N + n] : 0.f;
  }
  __syncthreads();
  for (int i = ty; i < 32; i += 8) {
    int n = nb + i, k = kb + tx;
    if (n < N && k < Kpad) Wt[(size_t)n * Kpad + k] = f2bf(t[tx][i]);
  }
}

// ---- ALL weight transposes + X f32->bf16 + flag zero in ONE dispatch
__global__ __launch_bounds__(256) void prep_all(
    const float* __restrict__ W0, u16* __restrict__ W0t,
    const float* __restrict__ W1, u16* __restrict__ W1t,
    const float* __restrict__ W2, u16* __restrict__ W2t,
    const float* __restrict__ fc1w, u16* __restrict__ fc1t,
    const float* __restrict__ fc2w, u16* __restrict__ fc2t,
    const float* __restrict__ X, u16* __restrict__ Xb,
    int* __restrict__ flag)
{
  const int i = blockIdx.x;
  if (i == 0 && threadIdx.x == 0 && threadIdx.y == 0) *flag = 0;
  if (i < 2048) {
    transpose_body(fc2w, fc2t, 512, 4096, 512, i & 127, i >> 7);
  } else if (i < 2560) {
    int j = i - 2048;
    transpose_body(W0, W0t, 1024, 512, 1024, j & 15, j >> 4);
  } else if (i < 2696) {
    int j = i - 2560;
    transpose_body(W1, W1t, 528, 256, 544, j & 7, j >> 3);
  } else if (i < 2832) {
    int j = i - 2696;
    transpose_body(W2, W2t, 528, 256, 544, j & 7, j >> 3);
  } else if (i < 2976) {
    int j = i - 2832;
    transpose_body(fc1w, fc1t, 272, 512, 288, j & 15, j >> 4);
  } else {
    int j = i - 2976;
    int idx = j * 256 + threadIdx.y * 32 + threadIdx.x;
    float4 v = ((const float4*)X)[idx];
    u16x4 o = {f2bf(v.x), f2bf(v.y), f2bf(v.z), f2bf(v.w)};
    ((u16x4*)Xb)[idx] = o;
  }
}

// ---- bf16 MFMA GEMM 128x128 tile, BK=32, 4 waves, dbuf + counted vmcnt depth-2,
//      LDS-staged coalesced epilogue
template<int ACT, bool OBF>   // ACT 0=none 1=relu 2=sigmoid
__global__ __launch_bounds__(256) void gemm_mfma(
    const u16* __restrict__ A, int lda,
    const u16* __restrict__ Bt, int ldb,
    void* __restrict__ Cout, int ldc,
    int K, const float* __restrict__ bias)
{
  __shared__ u16 AB[2][2][128 * 32];   // [buf][A/B], 32KB total
  const int tid = threadIdx.x;
  const int lane = tid & 63, wv = tid >> 6;
  const int wm = wv >> 1, wn = wv & 1;
  const int m0 = blockIdx.y * 128, n0 = blockIdx.x * 128;
  const int nk = K >> 5;

  f32x4 acc[4][4] = {};

  auto STAGE = [&](int buf, int kt) {   // 4 loads/thread
    #pragma unroll
    for (int i = 0; i < 2; ++i) {
      int c = tid + i * 256;
      int r = c >> 2;
      int s = (c & 3) ^ ((r >> 1) & 3);
      gload_lds16(A + (size_t)(m0 + r) * lda + kt * 32 + s * 8, (char*)AB[buf][0] + (c & ~63) * 16);
      gload_lds16(Bt + (size_t)(n0 + r) * ldb + kt * 32 + s * 8, (char*)AB[buf][1] + (c & ~63) * 16);
    }
  };

  STAGE(0, 0);
  if (nk > 1) STAGE(1, 1);

  int cur = 0;
  for (int kt = 0; kt < nk; ++kt) {
    if (kt + 1 < nk) { asm volatile("s_waitcnt vmcnt(4)" ::: "memory"); }
    else             { asm volatile("s_waitcnt vmcnt(0)" ::: "memory"); }
    __builtin_amdgcn_s_barrier();

    bf16x8 af[4], bf_[4];
    #pragma unroll
    for (int mi = 0; mi < 4; ++mi) {
      int r = wm * 64 + mi * 16 + (lane & 15);
      int sp = (lane >> 4) ^ ((r >> 1) & 3);
      af[mi] = *(const bf16x8*)((const char*)AB[cur][0] + r * 64 + sp * 16);
    }
    #pragma unroll
    for (int ni = 0; ni < 4; ++ni) {
      int r = wn * 64 + ni * 16 + (lane & 15);
      int sp = (lane >> 4) ^ ((r >> 1) & 3);
      bf_[ni] = *(const bf16x8*)((const char*)AB[cur][1] + r * 64 + sp * 16);
    }
    __builtin_amdgcn_s_setprio(1);
    #pragma unroll
    for (int mi = 0; mi < 4; ++mi)
      #pragma unroll
      for (int ni = 0; ni < 4; ++ni)
        acc[mi][ni] = __builtin_amdgcn_mfma_f32_16x16x32_bf16(af[mi], bf_[ni], acc[mi][ni], 0, 0, 0);
    __builtin_amdgcn_s_setprio(0);

    __builtin_amdgcn_s_barrier();
    if (kt + 2 < nk) STAGE(cur, kt + 2);
    cur ^= 1;
  }

  // epilogue: per-mi 32-row x 128-col band staged in LDS, coalesced writeback
  float bv4[4];
  #pragma unroll
  for (int ni = 0; ni < 4; ++ni)
    bv4[ni] = bias ? bias[n0 + wn * 64 + ni * 16 + (lane & 15)] : 0.f;
  float* sc = (float*)AB;   // 32 x 128 f32 = 16KB
  #pragma unroll
  for (int mi = 0; mi < 4; ++mi) {
    __syncthreads();
    const int lr = wm * 16 + (lane >> 4) * 4;
    #pragma unroll
    for (int ni = 0; ni < 4; ++ni) {
      const int lc = wn * 64 + ni * 16 + (lane & 15);
      #pragma unroll
      for (int j = 0; j < 4; ++j) {
        float v = acc[mi][ni][j] + bv4[ni];
        if (ACT == 1) v = fmaxf(v, 0.f);
        if (ACT == 2) v = 1.f / (1.f + __expf(-v));
        sc[(lr + j) * 128 + lc] = v;
      }
    }
    __syncthreads();
    #pragma unroll
    for (int u = 0; u < 4; ++u) {
      int idx = tid + u * 256;
      int r = idx >> 5, c4 = (idx & 31) * 4;
      int grow = m0 + (r >> 4) * 64 + mi * 16 + (r & 15);
      float4 v4 = *(const float4*)(sc + r * 128 + c4);
      if (OBF) {
        u16x4 o = {f2bf(v4.x), f2bf(v4.y), f2bf(v4.z), f2bf(v4.w)};
        *(u16x4*)((u16*)Cout + (size_t)grow * ldc + n0 + c4) = o;
      } else {
        *(float4*)((float*)Cout + (size_t)grow * ldc + n0 + c4) = v4;
      }
    }
  }
}

// ---- bf16 MFMA GEMM 128x64 tile (N=512 GEMMs), dbuf + counted vmcnt, staged epilogue
template<int ACT, bool OBF>
__global__ __launch_bounds__(256) void gemm_mfma64(
    const u16* __restrict__ A, int lda,
    const u16* __restrict__ Bt, int ldb,
    void* __restrict__ Cout, int ldc,
    int K, const float* __restrict__ bias)
{
  __shared__ u16 As[2][128 * 32];   // 16KB
  __shared__ u16 Bs[2][64 * 32];    // 8KB
  const int tid = threadIdx.x;
  const int lane = tid & 63, wv = tid >> 6;
  const int wm = wv >> 1, wn = wv & 1;
  const int m0 = blockIdx.y * 128, n0 = blockIdx.x * 64;
  const int nk = K >> 5;

  f32x4 acc[4][2] = {};

  auto STAGE = [&](int buf, int kt) {   // 3 loads/thread
    #pragma unroll
    for (int i = 0; i < 2; ++i) {
      int c = tid + i * 256;
      int r = c >> 2;
      int s = (c & 3) ^ ((r >> 1) & 3);
      gload_lds16(A + (size_t)(m0 + r) * lda + kt * 32 + s * 8, (char*)As[buf] + (c & ~63) * 16);
    }
    {
      int c = tid;
      int r = c >> 2;
      int s = (c & 3) ^ ((r >> 1) & 3);
      gload_lds16(Bt + (size_t)(n0 + r) * ldb + kt * 32 + s * 8, (char*)Bs[buf] + (c & ~63) * 16);
    }
  };

  STAGE(0, 0);
  if (nk > 1) STAGE(1, 1);

  int cur = 0;
  for (int kt = 0; kt < nk; ++kt) {
    if (kt + 1 < nk) { asm volatile("s_waitcnt vmcnt(3)" ::: "memory"); }
    else             { asm volatile("s_waitcnt vmcnt(0)" ::: "memory"); }
    __builtin_amdgcn_s_barrier();

    bf16x8 af[4], bf_[2];
    #pragma unroll
    for (int mi = 0; mi < 4; ++mi) {
      int r = wm * 64 + mi * 16 + (lane & 15);
      int sp = (lane >> 4) ^ ((r >> 1) & 3);
      af[mi] = *(const bf16x8*)((const char*)As[cur] + r * 64 + sp * 16);
    }
    #pragma unroll
    for (int ni = 0; ni < 2; ++ni) {
      int r = wn * 32 + ni * 16 + (lane & 15);
      int sp = (lane >> 4) ^ ((r >> 1) & 3);
      bf_[ni] = *(const bf16x8*)((const char*)Bs[cur] + r * 64 + sp * 16);
    }
    __builtin_amdgcn_s_setprio(1);
    #pragma unroll
    for (int mi = 0; mi < 4; ++mi)
      #pragma unroll
      for (int ni = 0; ni < 2; ++ni)
        acc[mi][ni] = __builtin_amdgcn_mfma_f32_16x16x32_bf16(af[mi], bf_[ni], acc[mi][ni], 0, 0, 0);
    __builtin_amdgcn_s_setprio(0);

    __builtin_amdgcn_s_barrier();
    if (kt + 2 < nk) STAGE(cur, kt + 2);
    cur ^= 1;
  }

  // epilogue: per-mi 32-row x 64-col band staged in LDS
  float bv2[2];
  #pragma unroll
  for (int ni = 0; ni < 2; ++ni)
    bv2[ni] = bias ? bias[n0 + wn * 32 + ni * 16 + (lane & 15)] : 0.f;
  float* sc = (float*)As;   // 32 x 64 f32 = 8KB
  #pragma unroll
  for (int mi = 0; mi < 4; ++mi) {
    __syncthreads();
    const int lr = wm * 16 + (lane >> 4) * 4;
    #pragma unroll
    for (int ni = 0; ni < 2; ++ni) {
      const int lc = wn * 32 + ni * 16 + (lane & 15);
      #pragma unroll
      for (int j = 0; j < 4; ++j) {
        float v = acc[mi][ni][j] + bv2[ni];
        if (ACT == 1) v = fmaxf(v, 0.f);
        if (ACT == 2) v = 1.f / (1.f + __expf(-v));
        sc[(lr + j) * 64 + lc] = v;
      }
    }
    __syncthreads();
    #pragma unroll
    for (int u = 0; u < 2; ++u) {
      int idx = tid + u * 256;
      int r = idx >> 4, c4 = (idx & 15) * 4;
      int grow = m0 + (r >> 4) * 64 + mi * 16 + (r & 15);
      float4 v4 = *(const float4*)(sc + r * 64 + c4);
      if (OBF) {
        u16x4 o = {f2bf(v4.x), f2bf(v4.y), f2bf(v4.z), f2bf(v4.w)};
        *(u16x4*)((u16*)Cout + (size_t)grow * ldc + n0 + c4) = o;
      } else {
        *(float4*)((float*)Cout + (size_t)grow * ldc + n0 + c4) = v4;
      }
    }
  }
}

// ---- per-row attention scores, bf16 h (layer 0, F=512)
__global__ __launch_bounds__(256) void fsrc_fdst_bf16(
    const u16* __restrict__ h, const float* __restrict__ a,
    float* __restrict__ fs, float* __restrict__ fd)
{
  const int wid = threadIdx.x >> 6, lane = threadIdx.x & 63;
  const int row = blockIdx.x * 4 + wid;
  u16x8 hv = *(const u16x8*)(h + (size_t)row * 512 + lane * 8);
  float s0 = 0.f, s1 = 0.f;
  #pragma unroll
  for (int j = 0; j < 8; ++j) {
    float x = bf2f(hv[j]);
    s0 = fmaf(x, a[lane * 8 + j], s0);
    s1 = fmaf(x, a[512 + lane * 8 + j], s1);
  }
  s0 = waveSum(s0);
  s1 = waveSum(s1);
  if (lane == 0) { fs[row] = s0; fd[row] = s1; }
}

// ---- merged scores for layers 1&2 over h12 [4096][512] f32
__global__ __launch_bounds__(256) void fsrc_fdst12(
    const float* __restrict__ h12,
    const float* __restrict__ a1, const float* __restrict__ a2,
    float* __restrict__ fs1, float* __restrict__ fd1,
    float* __restrict__ fs2, float* __restrict__ fd2)
{
  const int wid = threadIdx.x >> 6, lane = threadIdx.x & 63;
  const int row = blockIdx.x * 4 + wid;
  const float* hr = h12 + (size_t)row * 512;
  float s0 = 0.f, s1 = 0.f, s2 = 0.f, s3 = 0.f;
  #pragma unroll
  for (int f = lane; f < 256; f += 64) {
    float h1v = hr[f], h2v = hr[256 + f];
    s0 = fmaf(h1v, a1[f], s0);
    s1 = fmaf(h1v, a1[256 + f], s1);
    s2 = fmaf(h2v, a2[f], s2);
    s3 = fmaf(h2v, a2[256 + f], s3);
  }
  s0 = waveSum(s0); s1 = waveSum(s1); s2 = waveSum(s2); s3 = waveSum(s3);
  if (lane == 0) { fs1[row] = s0; fd1[row] = s1; fs2[row] = s2; fd2[row] = s3; }
}

// ---- layer-0 aggregate via CSR (bf16 h): hb[row] = [elu(att@h0) (512) | Y (16) | 0 (16)]
__global__ __launch_bounds__(256) void agg_gat0(
    const u16* __restrict__ h,
    const float* __restrict__ fs, const float* __restrict__ fd,
    const int* __restrict__ nbr, const int* __restrict__ cnt,
    const float* __restrict__ Y, u16* __restrict__ hb)
{
  __shared__ int   nb[CAP];
  __shared__ float pbuf[CAP];
  __shared__ float redm[4], reds[4];
  const int i = blockIdx.x, tid = threadIdx.x;
  const int wid = tid >> 6, lane = tid & 63;
  int c = cnt[i]; if (c > CAP) c = CAP;
  const float fsi = fs[i];
  float2 acc = {0.f, 0.f};

  if (c > 0) {
    float e = -3.0e38f;
    if (tid < c) {
      int j = nbr[(size_t)i * CAP + tid];
      nb[tid] = j;
      float t = fsi + fd[j];
      e = t > 0.f ? t : LRELU_ALPHA * t;
    }
    float wm = waveMax(e);
    if (lane == 0) redm[wid] = wm;
    __syncthreads();
    const float gmax = fmaxf(fmaxf(redm[0], redm[1]), fmaxf(redm[2], redm[3]));
    float p = (tid < c) ? expf(e - gmax) : 0.f;
    float ws = waveSum(p);
    if (lane == 0) reds[wid] = ws;
    __syncthreads();
    const float inv = 1.f / (reds[0] + reds[1] + reds[2] + reds[3]);
    if (tid < c) pbuf[tid] = p * inv;
    __syncthreads();
    const u16* hp = h + 2 * tid;
    #pragma unroll 4
    for (int n = 0; n < c; ++n) {
      u16x2 hv = *(const u16x2*)(hp + (size_t)nb[n] * 512);
      float pn = pbuf[n];
      acc.x = fmaf(pn, bf2f(hv[0]), acc.x);
      acc.y = fmaf(pn, bf2f(hv[1]), acc.y);
    }
  } else {
    const u16* hp = h + 2 * tid;
    for (int j = 0; j < NN; ++j) {
      u16x2 hv = *(const u16x2*)(hp + (size_t)j * 512);
      acc.x += bf2f(hv[0]); acc.y += bf2f(hv[1]);
    }
    acc.x *= (1.f / NN); acc.y *= (1.f / NN);
  }
  float vx = acc.x > 0.f ? acc.x : expm1f(acc.x);
  float vy = acc.y > 0.f ? acc.y : expm1f(acc.y);
  u16* row = hb + (size_t)i * 544;
  *(u16x2*)(row + 2 * tid) = u16x2{f2bf(vx), f2bf(vy)};
  if (tid < 8) {
    float2 yv = *(const float2*)(Y + (size_t)i * 16 + 2 * tid);
    *(u16x2*)(row + 512 + 2 * tid) = u16x2{f2bf(yv.x), f2bf(yv.y)};
  } else if (tid < 16) {
    *(u16x2*)(row + 528 + 2 * (tid - 8)) = u16x2{0, 0};
  }
}

// ---- fused layers 1+2 aggregate + reparam + concat (h12 f32, ld=512)
__global__ __launch_bounds__(256) void agg_gat12(
    const float* __restrict__ h12,
    const float* __restrict__ fs1, const float* __restrict__ fd1,
    const float* __restrict__ fs2, const float* __restrict__ fd2,
    const int* __restrict__ nbr, const int* __restrict__ cnt,
    const float* __restrict__ noise, const float* __restrict__ Y,
    u16* __restrict__ zcat)
{
  __shared__ int   nb[CAP];
  __shared__ float p1[CAP], p2[CAP];
  __shared__ float mn_s[256], lsd_s[256];
  __shared__ float redm1[4], redm2[4], reds1[4], reds2[4];
  const int i = blockIdx.x, tid = threadIdx.x;
  const int wid = tid >> 6, lane = tid & 63;
  int c = cnt[i]; if (c > CAP) c = CAP;
  const int half = tid >> 7, t = tid & 127;

  float2 acc = {0.f, 0.f};
  if (c > 0) {
    float e1 = -3.0e38f, e2 = -3.0e38f;
    if (tid < c) {
      int j = nbr[(size_t)i * CAP + tid];
      nb[tid] = j;
      float a1v = fs1[i] + fd1[j];
      float a2v = fs2[i] + fd2[j];
      e1 = a1v > 0.f ? a1v : LRELU_ALPHA * a1v;
      e2 = a2v > 0.f ? a2v : LRELU_ALPHA * a2v;
    }
    float wm1 = waveMax(e1), wm2 = waveMax(e2);
    if (lane == 0) { redm1[wid] = wm1; redm2[wid] = wm2; }
    __syncthreads();
    const float g1 = fmaxf(fmaxf(redm1[0], redm1[1]), fmaxf(redm1[2], redm1[3]));
    const float g2 = fmaxf(fmaxf(redm2[0], redm2[1]), fmaxf(redm2[2], redm2[3]));
    float pp1 = (tid < c) ? expf(e1 - g1) : 0.f;
    float pp2 = (tid < c) ? expf(e2 - g2) : 0.f;
    float ws1 = waveSum(pp1), ws2 = waveSum(pp2);
    if (lane == 0) { reds1[wid] = ws1; reds2[wid] = ws2; }
    __syncthreads();
    const float inv1 = 1.f / (reds1[0] + reds1[1] + reds1[2] + reds1[3]);
    const float inv2 = 1.f / (reds2[0] + reds2[1] + reds2[2] + reds2[3]);
    if (tid < c) { p1[tid] = pp1 * inv1; p2[tid] = pp2 * inv2; }
    __syncthreads();
    const float* hh = h12 + (half ? 256 : 0) + 2 * t;
    const float* pp = half ? p2 : p1;
    #pragma unroll 4
    for (int n = 0; n < c; ++n) {
      float2 hv = *(const float2*)(hh + (size_t)nb[n] * 512);
      float pn = pp[n];
      acc.x = fmaf(pn, hv.x, acc.x);
      acc.y = fmaf(pn, hv.y, acc.y);
    }
  } else {
    const float* hh = h12 + (half ? 256 : 0) + 2 * t;
    for (int j = 0; j < NN; ++j) {
      float2 hv = *(const float2*)(hh + (size_t)j * 512);
      acc.x += hv.x; acc.y += hv.y;
    }
    acc.x *= (1.f / NN); acc.y *= (1.f / NN);
  }
  float vx = acc.x > 0.f ? acc.x : expm1f(acc.x);
  float vy = acc.y > 0.f ? acc.y : expm1f(acc.y);
  float* dst = half ? lsd_s : mn_s;
  dst[2 * t] = vx; dst[2 * t + 1] = vy;
  __syncthreads();
  u16* row = zcat + (size_t)i * 288;
  if (tid < 128) {
    const int f = 2 * tid;
    float2 nz = *(const float2*)(noise + (size_t)i * 256 + f);
    float zx = fmaf(nz.x, expf(lsd_s[f]), mn_s[f]);
    float zy = fmaf(nz.y, expf(lsd_s[f + 1]), mn_s[f + 1]);
    *(u16x2*)(row + f) = u16x2{f2bf(zx), f2bf(zy)};
  } else if (tid < 136) {
    const int k = tid - 128;
    float2 yv = *(const float2*)(Y + (size_t)i * 16 + 2 * k);
    *(u16x2*)(row + 256 + 2 * k) = u16x2{f2bf(yv.x), f2bf(yv.y)};
  } else if (tid < 144) {
    *(u16x2*)(row + 272 + 2 * (tid - 136)) = u16x2{0, 0};
  }
}

extern "C" void kernel_launch(void* const* d_in, const int* in_sizes, int n_in,
                              void* d_out, int out_size, void* d_ws, size_t ws_size,
                              hipStream_t stream)
{
  const float* X     = (const float*)d_in[0];
  const float* Y     = (const float*)d_in[1];
  const float* noise = (const float*)d_in[2];
  const void*  adj   = d_in[3];
  const float* W0    = (const float*)d_in[4];
  const float* a0    = (const float*)d_in[5];
  const float* W1    = (const float*)d_in[6];
  const float* a1    = (const float*)d_in[7];
  const float* W2    = (const float*)d_in[8];
  const float* a2    = (const float*)d_in[9];
  const float* fc1w  = (const float*)d_in[10];
  const float* fc1b  = (const float*)d_in[11];
  const float* fc2w  = (const float*)d_in[12];
  const float* fc2b  = (const float*)d_in[13];
  float* out = (float*)d_out;
  char* W = (char*)d_ws;

  // workspace layout (bytes), ~31.7 MB
  u16*   Xb    = (u16*)(W + 0);            // 4096x1024 bf16 (dead after gemm0)
  u16*   zcatb = (u16*)(W + 0);            // 4096x288 bf16
  u16*   zzb   = (u16*)(W + 2359296);      // 4096x512 bf16
  u16*   h0b   = (u16*)(W + 8388608);      // 4096x512 bf16 (dead after agg0)
  float* h12   = (float*)(W + 8388608);    // 4096x512 f32 (reuses h0b region)
  u16*   hb    = (u16*)(W + 16777216);     // 4096x544 bf16
  u16*   W0t   = (u16*)(W + 21233664);     // 512x1024
  u16*   W12t  = (u16*)(W + 22282240);     // 512x544
  u16*   fc1t  = (u16*)(W + 22839296);     // 512x288
  u16*   fc2t  = (u16*)(W + 23134208);     // 4096x512
  int*   nbr   = (int*)(W + 27328512);     // 4096x256 int
  int*   cnt   = (int*)(W + 31522816);     // 4096 int
  float* fs0   = (float*)(W + 31539200);
  float* fd0   = fs0 + 4096;
  float* fs1   = fd0 + 4096;
  float* fd1   = fs1 + 4096;
  float* fs2   = fd1 + 4096;
  float* fd2   = fs2 + 4096;
  int*   flag  = (int*)(fd2 + 4096);

  prep_all<<<7072, dim3(32, 8), 0, stream>>>(W0, W0t, W1, W12t, W2, W12t + 256 * 544,
                                             fc1w, fc1t, fc2w, fc2t, X, Xb, flag);
  detect_adj<<<256, 256, 0, stream>>>((const unsigned int*)adj, 524288, flag);
  build_csr<<<4096, 256, 0, stream>>>((const unsigned*)adj, flag, nbr, cnt);

  // GAT layer 0 (h0 in bf16 for the gather)
  gemm_mfma64<0,true><<<dim3(8, 32), 256, 0, stream>>>(Xb, 1024, W0t, 1024, h0b, 512, 1024, nullptr);
  fsrc_fdst_bf16<<<1024, 256, 0, stream>>>(h0b, a0, fs0, fd0);
  agg_gat0<<<4096, 256, 0, stream>>>(h0b, fs0, fd0, nbr, cnt, Y, hb);

  // GAT layers 1 & 2 merged: h12 = hb @ [W1|W2] (f32)
  gemm_mfma64<0,false><<<dim3(8, 32), 256, 0, stream>>>(hb, 544, W12t, 544, h12, 512, 544, nullptr);
  fsrc_fdst12<<<1024, 256, 0, stream>>>(h12, a1, a2, fs1, fd1, fs2, fd2);
  agg_gat12<<<4096, 256, 0, stream>>>(h12, fs1, fd1, fs2, fd2, nbr, cnt, noise, Y, zcatb);

  // decoder
  gemm_mfma64<1,true><<<dim3(8, 32), 256, 0, stream>>>(zcatb, 288, fc1t, 288, zzb, 512, 288, fc1b);
  gemm_mfma<2,false><<<dim3(32, 32), 256, 0, stream>>>(zzb, 512, fc2t, 512, out, 4096, 512, fc2b);
}

// Round 9
// 148.602 us; speedup vs baseline: 3.7825x; 1.0014x over previous
//
#include <hip/hip_runtime.h>

#define LRELU_ALPHA 0.2f
#define NN 4096
#define CAP 256

typedef unsigned short u16;
typedef short bf16x8 __attribute__((ext_vector_type(8)));
typedef float f32x4 __attribute__((ext_vector_type(4)));
typedef u16 u16x4 __attribute__((ext_vector_type(4)));
typedef u16 u16x2 __attribute__((ext_vector_type(2)));
typedef u16 u16x8 __attribute__((ext_vector_type(8)));

__device__ __forceinline__ u16 f2bf(float f) {
  unsigned u = __float_as_uint(f);
  u += 0x7FFFu + ((u >> 16) & 1u);
  return (u16)(u >> 16);
}
__device__ __forceinline__ float bf2f(u16 u) {
  return __uint_as_float(((unsigned)u) << 16);
}

__device__ __forceinline__ float waveSum(float v) {
  #pragma unroll
  for (int o = 32; o > 0; o >>= 1) v += __shfl_down(v, o, 64);
  return v;
}
__device__ __forceinline__ float waveMax(float v) {
  #pragma unroll
  for (int o = 32; o > 0; o >>= 1) v = fmaxf(v, __shfl_down(v, o, 64));
  return v;
}

__device__ __forceinline__ void gload_lds16(const void* g, void* l) {
  __builtin_amdgcn_global_load_lds((const __attribute__((address_space(1))) void*)g,
                                   (__attribute__((address_space(3))) void*)l, 16, 0, 0);
}

// ---- adj dtype probe (2MB sample)
__global__ __launch_bounds__(256) void detect_adj(const unsigned int* __restrict__ w,
                                                  int nwords, int* flag) {
  int f = 0;
  for (int idx = blockIdx.x * 256 + threadIdx.x; idx < nwords; idx += gridDim.x * 256) {
    unsigned int v = w[idx];
    if (v == 0x3F800000u) f |= 1;
    else if (v > 1u) f |= 2;
  }
  if (f) atomicOr(flag, f);
}

// ---- CSR build: one block per row, single pass, uint4-vectorized
__global__ __launch_bounds__(256) void build_csr(const unsigned* __restrict__ adjw,
                                                 const int* __restrict__ adjflag,
                                                 int* __restrict__ nbr,
                                                 int* __restrict__ cnt)
{
  __shared__ int scn[256];
  const int i = blockIdx.x, tid = threadIdx.x;
  const int fmask = *adjflag;
  const bool bytemode = (fmask & 2) && !(fmask & 1);
  unsigned bits = 0;
  if (!bytemode) {
    const unsigned* row = adjw + (size_t)i * 4096 + tid * 16;
    #pragma unroll
    for (int ck = 0; ck < 4; ++ck) {
      uint4 v = *(const uint4*)(row + ck * 4);
      if (v.x) bits |= 1u << (ck * 4 + 0);
      if (v.y) bits |= 1u << (ck * 4 + 1);
      if (v.z) bits |= 1u << (ck * 4 + 2);
      if (v.w) bits |= 1u << (ck * 4 + 3);
    }
  } else {
    const unsigned* row = adjw + (size_t)i * 1024 + tid * 4;
    uint4 v = *(const uint4*)row;
    unsigned w4[4] = {v.x, v.y, v.z, v.w};
    #pragma unroll
    for (int wi = 0; wi < 4; ++wi)
      #pragma unroll
      for (int b = 0; b < 4; ++b)
        if ((w4[wi] >> (b * 8)) & 0xFFu) bits |= 1u << (wi * 4 + b);
  }
  int mycnt = __popc(bits);
  scn[tid] = mycnt;
  __syncthreads();
  for (int off = 1; off < 256; off <<= 1) {
    int v = (tid >= off) ? scn[tid - off] : 0;
    __syncthreads();
    scn[tid] += v;
    __syncthreads();
  }
  const int total = scn[255];
  int pos = scn[tid] - mycnt;
  #pragma unroll
  for (int b = 0; b < 16; ++b) {
    if (bits & (1u << b)) {
      if (pos < CAP) nbr[(size_t)i * CAP + pos] = tid * 16 + b;
      ++pos;
    }
  }
  if (tid == 0) cnt[i] = total;
}

// ---- transpose helper: Wt[n][k] (bf16, ld=Kpad) from W[k][n] (f32)
__device__ __forceinline__ void transpose_body(const float* Wsrc, u16* Wt,
                                               int K, int N, int Kpad,
                                               int bx, int by) {
  __shared__ float t[32][33];
  const int kb = by * 32, nb = bx * 32;
  const int tx = threadIdx.x, ty = threadIdx.y;  // 32 x 8
  for (int i = ty; i < 32; i += 8) {
    int k = kb + i, n = nb + tx;
    t[i][tx] = (k < K && n < N) ? Wsrc[(size_t)k * N + n] : 0.f;
  }
  __syncthreads();
  for (int i = ty; i < 32; i += 8) {
    int n = nb + i, k = kb + tx;
    if (n < N && k < Kpad) Wt[(size_t)n * Kpad + k] = f2bf(t[tx][i]);
  }
}

// ---- ALL weight transposes + X f32->bf16 + flag zero in ONE dispatch
__global__ __launch_bounds__(256) void prep_all(
    const float* __restrict__ W0, u16* __restrict__ W0t,
    const float* __restrict__ W1, u16* __restrict__ W1t,
    const float* __restrict__ W2, u16* __restrict__ W2t,
    const float* __restrict__ fc1w, u16* __restrict__ fc1t,
    const float* __restrict__ fc2w, u16* __restrict__ fc2t,
    const float* __restrict__ X, u16* __restrict__ Xb,
    int* __restrict__ flag)
{
  const int i = blockIdx.x;
  if (i == 0 && threadIdx.x == 0 && threadIdx.y == 0) *flag = 0;
  if (i < 2048) {
    transpose_body(fc2w, fc2t, 512, 4096, 512, i & 127, i >> 7);
  } else if (i < 2560) {
    int j = i - 2048;
    transpose_body(W0, W0t, 1024, 512, 1024, j & 15, j >> 4);
  } else if (i < 2696) {
    int j = i - 2560;
    transpose_body(W1, W1t, 528, 256, 544, j & 7, j >> 3);
  } else if (i < 2832) {
    int j = i - 2696;
    transpose_body(W2, W2t, 528, 256, 544, j & 7, j >> 3);
  } else if (i < 2976) {
    int j = i - 2832;
    transpose_body(fc1w, fc1t, 272, 512, 288, j & 15, j >> 4);
  } else {
    int j = i - 2976;
    int idx = j * 256 + threadIdx.y * 32 + threadIdx.x;
    float4 v = ((const float4*)X)[idx];
    u16x4 o = {f2bf(v.x), f2bf(v.y), f2bf(v.z), f2bf(v.w)};
    ((u16x4*)Xb)[idx] = o;
  }
}

// ---- bf16 MFMA GEMM 256x256 tile, BK=64, 8 waves, dbuf + counted vmcnt depth-2,
//      LDS-staged coalesced NONTEMPORAL epilogue, XCD-chunk swizzle (grid must be 16x16)
template<int ACT>
__global__ __launch_bounds__(512) void gemm_mfma256(
    const u16* __restrict__ A, int lda,
    const u16* __restrict__ Bt, int ldb,
    float* __restrict__ Cout, int ldc,
    int K, const float* __restrict__ bias)
{
  __shared__ u16 As[2][256 * 64];   // 32KB each buf
  __shared__ u16 Bs[2][256 * 64];
  const int tid = threadIdx.x;
  const int lane = tid & 63, wv = tid >> 6;   // 8 waves
  const int wm = wv >> 2, wn = wv & 3;        // 2 x 4; wave owns 128x64
  // XCD-chunk swizzle: nwg=256, 8 XCDs, 32 blocks/XCD contiguous in tile space
  const int bid = blockIdx.y * 16 + blockIdx.x;
  const int swz = ((bid & 7) << 5) | (bid >> 3);
  const int m0 = (swz >> 4) * 256, n0 = (swz & 15) * 256;
  const int nk = K >> 6;

  f32x4 acc[8][4] = {};

  auto STAGE = [&](int buf, int kt) {   // 8 loads/thread
    const u16* Ap = A + (size_t)m0 * lda + kt * 64;
    const u16* Bp = Bt + (size_t)n0 * ldb + kt * 64;
    #pragma unroll
    for (int i = 0; i < 4; ++i) {
      int c = tid + i * 512;
      int r = c >> 3, sl = c & 7;
      int sg = sl ^ (r & 7);
      gload_lds16(Ap + (size_t)r * lda + sg * 8, (char*)As[buf] + (c & ~63) * 16);
      gload_lds16(Bp + (size_t)r * ldb + sg * 8, (char*)Bs[buf] + (c & ~63) * 16);
    }
  };

  STAGE(0, 0);
  if (nk > 1) STAGE(1, 1);

  int cur = 0;
  for (int kt = 0; kt < nk; ++kt) {
    if (kt + 1 < nk) { asm volatile("s_waitcnt vmcnt(8)" ::: "memory"); }
    else             { asm volatile("s_waitcnt vmcnt(0)" ::: "memory"); }
    __builtin_amdgcn_s_barrier();

    #pragma unroll
    for (int ks = 0; ks < 2; ++ks) {           // two k-steps of 32
      bf16x8 af[8], bf_[4];
      #pragma unroll
      for (int mi = 0; mi < 8; ++mi) {
        int r = wm * 128 + mi * 16 + (lane & 15);
        int sg = ks * 4 + (lane >> 4);
        int sl = sg ^ (r & 7);
        af[mi] = *(const bf16x8*)((const char*)As[cur] + r * 128 + sl * 16);
      }
      #pragma unroll
      for (int ni = 0; ni < 4; ++ni) {
        int r = wn * 64 + ni * 16 + (lane & 15);
        int sg = ks * 4 + (lane >> 4);
        int sl = sg ^ (r & 7);
        bf_[ni] = *(const bf16x8*)((const char*)Bs[cur] + r * 128 + sl * 16);
      }
      __builtin_amdgcn_s_setprio(1);
      #pragma unroll
      for (int mi = 0; mi < 8; ++mi)
        #pragma unroll
        for (int ni = 0; ni < 4; ++ni)
          acc[mi][ni] = __builtin_amdgcn_mfma_f32_16x16x32_bf16(af[mi], bf_[ni], acc[mi][ni], 0, 0, 0);
      __builtin_amdgcn_s_setprio(0);
    }

    __builtin_amdgcn_s_barrier();          // all waves done reading buf cur
    if (kt + 2 < nk) STAGE(cur, kt + 2);
    cur ^= 1;
  }

  // epilogue: per-mi 32-row x 256-col band staged in LDS, coalesced NT writeback
  float bv4[4];
  #pragma unroll
  for (int ni = 0; ni < 4; ++ni)
    bv4[ni] = bias ? bias[n0 + wn * 64 + ni * 16 + (lane & 15)] : 0.f;
  float* sc = (float*)As;   // 32 x 256 f32 = 32KB
  #pragma unroll
  for (int mi = 0; mi < 8; ++mi) {
    __syncthreads();
    const int lr = wm * 16 + (lane >> 4) * 4;
    #pragma unroll
    for (int ni = 0; ni < 4; ++ni) {
      const int lc = wn * 64 + ni * 16 + (lane & 15);
      #pragma unroll
      for (int j = 0; j < 4; ++j) {
        float v = acc[mi][ni][j] + bv4[ni];
        if (ACT == 1) v = fmaxf(v, 0.f);
        if (ACT == 2) v = 1.f / (1.f + __expf(-v));
        sc[(lr + j) * 256 + lc] = v;
      }
    }
    __syncthreads();
    #pragma unroll
    for (int u = 0; u < 4; ++u) {
      int idx = tid + u * 512;
      int r = idx >> 6, c4 = (idx & 63) * 4;
      int grow = m0 + (r >> 4) * 128 + mi * 16 + (r & 15);
      f32x4 v4 = *(const f32x4*)(sc + r * 256 + c4);
      __builtin_nontemporal_store(v4, (f32x4*)(Cout + (size_t)grow * ldc + n0 + c4));
    }
  }
}

// ---- bf16 MFMA GEMM 128x64 tile (N=512 GEMMs), dbuf + counted vmcnt, staged epilogue,
//      XCD-chunk swizzle (grid must be 8x32)
template<int ACT, bool OBF>
__global__ __launch_bounds__(256) void gemm_mfma64(
    const u16* __restrict__ A, int lda,
    const u16* __restrict__ Bt, int ldb,
    void* __restrict__ Cout, int ldc,
    int K, const float* __restrict__ bias)
{
  __shared__ u16 As[2][128 * 32];   // 16KB
  __shared__ u16 Bs[2][64 * 32];    // 8KB
  const int tid = threadIdx.x;
  const int lane = tid & 63, wv = tid >> 6;
  const int wm = wv >> 1, wn = wv & 1;
  const int bid = blockIdx.y * 8 + blockIdx.x;
  const int swz = ((bid & 7) << 5) | (bid >> 3);
  const int m0 = (swz >> 3) * 128, n0 = (swz & 7) * 64;
  const int nk = K >> 5;

  f32x4 acc[4][2] = {};

  auto STAGE = [&](int buf, int kt) {   // 3 loads/thread
    #pragma unroll
    for (int i = 0; i < 2; ++i) {
      int c = tid + i * 256;
      int r = c >> 2;
      int s = (c & 3) ^ ((r >> 1) & 3);
      gload_lds16(A + (size_t)(m0 + r) * lda + kt * 32 + s * 8, (char*)As[buf] + (c & ~63) * 16);
    }
    {
      int c = tid;
      int r = c >> 2;
      int s = (c & 3) ^ ((r >> 1) & 3);
      gload_lds16(Bt + (size_t)(n0 + r) * ldb + kt * 32 + s * 8, (char*)Bs[buf] + (c & ~63) * 16);
    }
  };

  STAGE(0, 0);
  if (nk > 1) STAGE(1, 1);

  int cur = 0;
  for (int kt = 0; kt < nk; ++kt) {
    if (kt + 1 < nk) { asm volatile("s_waitcnt vmcnt(3)" ::: "memory"); }
    else             { asm volatile("s_waitcnt vmcnt(0)" ::: "memory"); }
    __builtin_amdgcn_s_barrier();

    bf16x8 af[4], bf_[2];
    #pragma unroll
    for (int mi = 0; mi < 4; ++mi) {
      int r = wm * 64 + mi * 16 + (lane & 15);
      int sp = (lane >> 4) ^ ((r >> 1) & 3);
      af[mi] = *(const bf16x8*)((const char*)As[cur] + r * 64 + sp * 16);
    }
    #pragma unroll
    for (int ni = 0; ni < 2; ++ni) {
      int r = wn * 32 + ni * 16 + (lane & 15);
      int sp = (lane >> 4) ^ ((r >> 1) & 3);
      bf_[ni] = *(const bf16x8*)((const char*)Bs[cur] + r * 64 + sp * 16);
    }
    __builtin_amdgcn_s_setprio(1);
    #pragma unroll
    for (int mi = 0; mi < 4; ++mi)
      #pragma unroll
      for (int ni = 0; ni < 2; ++ni)
        acc[mi][ni] = __builtin_amdgcn_mfma_f32_16x16x32_bf16(af[mi], bf_[ni], acc[mi][ni], 0, 0, 0);
    __builtin_amdgcn_s_setprio(0);

    __builtin_amdgcn_s_barrier();
    if (kt + 2 < nk) STAGE(cur, kt + 2);
    cur ^= 1;
  }

  // epilogue: per-mi 32-row x 64-col band staged in LDS
  float bv2[2];
  #pragma unroll
  for (int ni = 0; ni < 2; ++ni)
    bv2[ni] = bias ? bias[n0 + wn * 32 + ni * 16 + (lane & 15)] : 0.f;
  float* sc = (float*)As;   // 32 x 64 f32 = 8KB
  #pragma unroll
  for (int mi = 0; mi < 4; ++mi) {
    __syncthreads();
    const int lr = wm * 16 + (lane >> 4) * 4;
    #pragma unroll
    for (int ni = 0; ni < 2; ++ni) {
      const int lc = wn * 32 + ni * 16 + (lane & 15);
      #pragma unroll
      for (int j = 0; j < 4; ++j) {
        float v = acc[mi][ni][j] + bv2[ni];
        if (ACT == 1) v = fmaxf(v, 0.f);
        if (ACT == 2) v = 1.f / (1.f + __expf(-v));
        sc[(lr + j) * 64 + lc] = v;
      }
    }
    __syncthreads();
    #pragma unroll
    for (int u = 0; u < 2; ++u) {
      int idx = tid + u * 256;
      int r = idx >> 4, c4 = (idx & 15) * 4;
      int grow = m0 + (r >> 4) * 64 + mi * 16 + (r & 15);
      float4 v4 = *(const float4*)(sc + r * 64 + c4);
      if (OBF) {
        u16x4 o = {f2bf(v4.x), f2bf(v4.y), f2bf(v4.z), f2bf(v4.w)};
        *(u16x4*)((u16*)Cout + (size_t)grow * ldc + n0 + c4) = o;
      } else {
        *(float4*)((float*)Cout + (size_t)grow * ldc + n0 + c4) = v4;
      }
    }
  }
}

// ---- per-row attention scores, bf16 h (layer 0, F=512)
__global__ __launch_bounds__(256) void fsrc_fdst_bf16(
    const u16* __restrict__ h, const float* __restrict__ a,
    float* __restrict__ fs, float* __restrict__ fd)
{
  const int wid = threadIdx.x >> 6, lane = threadIdx.x & 63;
  const int row = blockIdx.x * 4 + wid;
  u16x8 hv = *(const u16x8*)(h + (size_t)row * 512 + lane * 8);
  float s0 = 0.f, s1 = 0.f;
  #pragma unroll
  for (int j = 0; j < 8; ++j) {
    float x = bf2f(hv[j]);
    s0 = fmaf(x, a[lane * 8 + j], s0);
    s1 = fmaf(x, a[512 + lane * 8 + j], s1);
  }
  s0 = waveSum(s0);
  s1 = waveSum(s1);
  if (lane == 0) { fs[row] = s0; fd[row] = s1; }
}

// ---- merged scores for layers 1&2 over h12 [4096][512] f32
__global__ __launch_bounds__(256) void fsrc_fdst12(
    const float* __restrict__ h12,
    const float* __restrict__ a1, const float* __restrict__ a2,
    float* __restrict__ fs1, float* __restrict__ fd1,
    float* __restrict__ fs2, float* __restrict__ fd2)
{
  const int wid = threadIdx.x >> 6, lane = threadIdx.x & 63;
  const int row = blockIdx.x * 4 + wid;
  const float* hr = h12 + (size_t)row * 512;
  float s0 = 0.f, s1 = 0.f, s2 = 0.f, s3 = 0.f;
  #pragma unroll
  for (int f = lane; f < 256; f += 64) {
    float h1v = hr[f], h2v = hr[256 + f];
    s0 = fmaf(h1v, a1[f], s0);
    s1 = fmaf(h1v, a1[256 + f], s1);
    s2 = fmaf(h2v, a2[f], s2);
    s3 = fmaf(h2v, a2[256 + f], s3);
  }
  s0 = waveSum(s0); s1 = waveSum(s1); s2 = waveSum(s2); s3 = waveSum(s3);
  if (lane == 0) { fs1[row] = s0; fd1[row] = s1; fs2[row] = s2; fd2[row] = s3; }
}

// ---- layer-0 aggregate via CSR (bf16 h): hb[row] = [elu(att@h0) (512) | Y (16) | 0 (16)]
__global__ __launch_bounds__(256) void agg_gat0(
    const u16* __restrict__ h,
    const float* __restrict__ fs, const float* __restrict__ fd,
    const int* __restrict__ nbr, const int* __restrict__ cnt,
    const float* __restrict__ Y, u16* __restrict__ hb)
{
  __shared__ int   nb[CAP];
  __shared__ float pbuf[CAP];
  __shared__ float redm[4], reds[4];
  const int i = blockIdx.x, tid = threadIdx.x;
  const int wid = tid >> 6, lane = tid & 63;
  int c = cnt[i]; if (c > CAP) c = CAP;
  const float fsi = fs[i];
  float2 acc = {0.f, 0.f};

  if (c > 0) {
    float e = -3.0e38f;
    if (tid < c) {
      int j = nbr[(size_t)i * CAP + tid];
      nb[tid] = j;
      float t = fsi + fd[j];
      e = t > 0.f ? t : LRELU_ALPHA * t;
    }
    float wm = waveMax(e);
    if (lane == 0) redm[wid] = wm;
    __syncthreads();
    const float gmax = fmaxf(fmaxf(redm[0], redm[1]), fmaxf(redm[2], redm[3]));
    float p = (tid < c) ? expf(e - gmax) : 0.f;
    float ws = waveSum(p);
    if (lane == 0) reds[wid] = ws;
    __syncthreads();
    const float inv = 1.f / (reds[0] + reds[1] + reds[2] + reds[3]);
    if (tid < c) pbuf[tid] = p * inv;
    __syncthreads();
    const u16* hp = h + 2 * tid;
    #pragma unroll 4
    for (int n = 0; n < c; ++n) {
      u16x2 hv = *(const u16x2*)(hp + (size_t)nb[n] * 512);
      float pn = pbuf[n];
      acc.x = fmaf(pn, bf2f(hv[0]), acc.x);
      acc.y = fmaf(pn, bf2f(hv[1]), acc.y);
    }
  } else {
    const u16* hp = h + 2 * tid;
    for (int j = 0; j < NN; ++j) {
      u16x2 hv = *(const u16x2*)(hp + (size_t)j * 512);
      acc.x += bf2f(hv[0]); acc.y += bf2f(hv[1]);
    }
    acc.x *= (1.f / NN); acc.y *= (1.f / NN);
  }
  float vx = acc.x > 0.f ? acc.x : expm1f(acc.x);
  float vy = acc.y > 0.f ? acc.y : expm1f(acc.y);
  u16* row = hb + (size_t)i * 544;
  *(u16x2*)(row + 2 * tid) = u16x2{f2bf(vx), f2bf(vy)};
  if (tid < 8) {
    float2 yv = *(const float2*)(Y + (size_t)i * 16 + 2 * tid);
    *(u16x2*)(row + 512 + 2 * tid) = u16x2{f2bf(yv.x), f2bf(yv.y)};
  } else if (tid < 16) {
    *(u16x2*)(row + 528 + 2 * (tid - 8)) = u16x2{0, 0};
  }
}

// ---- fused layers 1+2 aggregate + reparam + concat (h12 f32, ld=512)
__global__ __launch_bounds__(256) void agg_gat12(
    const float* __restrict__ h12,
    const float* __restrict__ fs1, const float* __restrict__ fd1,
    const float* __restrict__ fs2, const float* __restrict__ fd2,
    const int* __restrict__ nbr, const int* __restrict__ cnt,
    const float* __restrict__ noise, const float* __restrict__ Y,
    u16* __restrict__ zcat)
{
  __shared__ int   nb[CAP];
  __shared__ float p1[CAP], p2[CAP];
  __shared__ float mn_s[256], lsd_s[256];
  __shared__ float redm1[4], redm2[4], reds1[4], reds2[4];
  const int i = blockIdx.x, tid = threadIdx.x;
  const int wid = tid >> 6, lane = tid & 63;
  int c = cnt[i]; if (c > CAP) c = CAP;
  const int half = tid >> 7, t = tid & 127;

  float2 acc = {0.f, 0.f};
  if (c > 0) {
    float e1 = -3.0e38f, e2 = -3.0e38f;
    if (tid < c) {
      int j = nbr[(size_t)i * CAP + tid];
      nb[tid] = j;
      float a1v = fs1[i] + fd1[j];
      float a2v = fs2[i] + fd2[j];
      e1 = a1v > 0.f ? a1v : LRELU_ALPHA * a1v;
      e2 = a2v > 0.f ? a2v : LRELU_ALPHA * a2v;
    }
    float wm1 = waveMax(e1), wm2 = waveMax(e2);
    if (lane == 0) { redm1[wid] = wm1; redm2[wid] = wm2; }
    __syncthreads();
    const float g1 = fmaxf(fmaxf(redm1[0], redm1[1]), fmaxf(redm1[2], redm1[3]));
    const float g2 = fmaxf(fmaxf(redm2[0], redm2[1]), fmaxf(redm2[2], redm2[3]));
    float pp1 = (tid < c) ? expf(e1 - g1) : 0.f;
    float pp2 = (tid < c) ? expf(e2 - g2) : 0.f;
    float ws1 = waveSum(pp1), ws2 = waveSum(pp2);
    if (lane == 0) { reds1[wid] = ws1; reds2[wid] = ws2; }
    __syncthreads();
    const float inv1 = 1.f / (reds1[0] + reds1[1] + reds1[2] + reds1[3]);
    const float inv2 = 1.f / (reds2[0] + reds2[1] + reds2[2] + reds2[3]);
    if (tid < c) { p1[tid] = pp1 * inv1; p2[tid] = pp2 * inv2; }
    __syncthreads();
    const float* hh = h12 + (half ? 256 : 0) + 2 * t;
    const float* pp = half ? p2 : p1;
    #pragma unroll 4
    for (int n = 0; n < c; ++n) {
      float2 hv = *(const float2*)(hh + (size_t)nb[n] * 512);
      float pn = pp[n];
      acc.x = fmaf(pn, hv.x, acc.x);
      acc.y = fmaf(pn, hv.y, acc.y);
    }
  } else {
    const float* hh = h12 + (half ? 256 : 0) + 2 * t;
    for (int j = 0; j < NN; ++j) {
      float2 hv = *(const float2*)(hh + (size_t)j * 512);
      acc.x += hv.x; acc.y += hv.y;
    }
    acc.x *= (1.f / NN); acc.y *= (1.f / NN);
  }
  float vx = acc.x > 0.f ? acc.x : expm1f(acc.x);
  float vy = acc.y > 0.f ? acc.y : expm1f(acc.y);
  float* dst = half ? lsd_s : mn_s;
  dst[2 * t] = vx; dst[2 * t + 1] = vy;
  __syncthreads();
  u16* row = zcat + (size_t)i * 288;
  if (tid < 128) {
    const int f = 2 * tid;
    float2 nz = *(const float2*)(noise + (size_t)i * 256 + f);
    float zx = fmaf(nz.x, expf(lsd_s[f]), mn_s[f]);
    float zy = fmaf(nz.y, expf(lsd_s[f + 1]), mn_s[f + 1]);
    *(u16x2*)(row + f) = u16x2{f2bf(zx), f2bf(zy)};
  } else if (tid < 136) {
    const int k = tid - 128;
    float2 yv = *(const float2*)(Y + (size_t)i * 16 + 2 * k);
    *(u16x2*)(row + 256 + 2 * k) = u16x2{f2bf(yv.x), f2bf(yv.y)};
  } else if (tid < 144) {
    *(u16x2*)(row + 272 + 2 * (tid - 136)) = u16x2{0, 0};
  }
}

extern "C" void kernel_launch(void* const* d_in, const int* in_sizes, int n_in,
                              void* d_out, int out_size, void* d_ws, size_t ws_size,
                              hipStream_t stream)
{
  const float* X     = (const float*)d_in[0];
  const float* Y     = (const float*)d_in[1];
  const float* noise = (const float*)d_in[2];
  const void*  adj   = d_in[3];
  const float* W0    = (const float*)d_in[4];
  const float* a0    = (const float*)d_in[5];
  const float* W1    = (const float*)d_in[6];
  const float* a1    = (const float*)d_in[7];
  const float* W2    = (const float*)d_in[8];
  const float* a2    = (const float*)d_in[9];
  const float* fc1w  = (const float*)d_in[10];
  const float* fc1b  = (const float*)d_in[11];
  const float* fc2w  = (const float*)d_in[12];
  const float* fc2b  = (const float*)d_in[13];
  float* out = (float*)d_out;
  char* W = (char*)d_ws;

  // workspace layout (bytes), ~31.7 MB
  u16*   Xb    = (u16*)(W + 0);            // 4096x1024 bf16 (dead after gemm0)
  u16*   zcatb = (u16*)(W + 0);            // 4096x288 bf16
  u16*   zzb   = (u16*)(W + 2359296);      // 4096x512 bf16
  u16*   h0b   = (u16*)(W + 8388608);      // 4096x512 bf16 (dead after agg0)
  float* h12   = (float*)(W + 8388608);    // 4096x512 f32 (reuses h0b region)
  u16*   hb    = (u16*)(W + 16777216);     // 4096x544 bf16
  u16*   W0t   = (u16*)(W + 21233664);     // 512x1024
  u16*   W12t  = (u16*)(W + 22282240);     // 512x544
  u16*   fc1t  = (u16*)(W + 22839296);     // 512x288
  u16*   fc2t  = (u16*)(W + 23134208);     // 4096x512
  int*   nbr   = (int*)(W + 27328512);     // 4096x256 int
  int*   cnt   = (int*)(W + 31522816);     // 4096 int
  float* fs0   = (float*)(W + 31539200);
  float* fd0   = fs0 + 4096;
  float* fs1   = fd0 + 4096;
  float* fd1   = fs1 + 4096;
  float* fs2   = fd1 + 4096;
  float* fd2   = fs2 + 4096;
  int*   flag  = (int*)(fd2 + 4096);

  prep_all<<<7072, dim3(32, 8), 0, stream>>>(W0, W0t, W1, W12t, W2, W12t + 256 * 544,
                                             fc1w, fc1t, fc2w, fc2t, X, Xb, flag);
  detect_adj<<<256, 256, 0, stream>>>((const unsigned int*)adj, 524288, flag);
  build_csr<<<4096, 256, 0, stream>>>((const unsigned*)adj, flag, nbr, cnt);

  // GAT layer 0 (h0 in bf16 for the gather)
  gemm_mfma64<0,true><<<dim3(8, 32), 256, 0, stream>>>(Xb, 1024, W0t, 1024, h0b, 512, 1024, nullptr);
  fsrc_fdst_bf16<<<1024, 256, 0, stream>>>(h0b, a0, fs0, fd0);
  agg_gat0<<<4096, 256, 0, stream>>>(h0b, fs0, fd0, nbr, cnt, Y, hb);

  // GAT layers 1 & 2 merged: h12 = hb @ [W1|W2] (f32)
  gemm_mfma64<0,false><<<dim3(8, 32), 256, 0, stream>>>(hb, 544, W12t, 544, h12, 512, 544, nullptr);
  fsrc_fdst12<<<1024, 256, 0, stream>>>(h12, a1, a2, fs1, fd1, fs2, fd2);
  agg_gat12<<<4096, 256, 0, stream>>>(h12, fs1, fd1, fs2, fd2, nbr, cnt, noise, Y, zcatb);

  // decoder
  gemm_mfma64<1,true><<<dim3(8, 32), 256, 0, stream>>>(zcatb, 288, fc1t, 288, zzb, 512, 288, fc1b);
  gemm_mfma256<2><<<dim3(16, 16), 512, 0, stream>>>(zzb, 512, fc2t, 512, out, 4096, 512, fc2b);
}

// Round 10
// 143.983 us; speedup vs baseline: 3.9038x; 1.0321x over previous
//
#include <hip/hip_runtime.h>

#define LRELU_ALPHA 0.2f
#define NN 4096
#define CAP 256

typedef unsigned short u16;
typedef short bf16x8 __attribute__((ext_vector_type(8)));
typedef float f32x4 __attribute__((ext_vector_type(4)));
typedef u16 u16x4 __attribute__((ext_vector_type(4)));
typedef u16 u16x2 __attribute__((ext_vector_type(2)));
typedef u16 u16x8 __attribute__((ext_vector_type(8)));

__device__ __forceinline__ u16 f2bf(float f) {
  unsigned u = __float_as_uint(f);
  u += 0x7FFFu + ((u >> 16) & 1u);
  return (u16)(u >> 16);
}
__device__ __forceinline__ float bf2f(u16 u) {
  return __uint_as_float(((unsigned)u) << 16);
}

__device__ __forceinline__ float waveSum(float v) {
  #pragma unroll
  for (int o = 32; o > 0; o >>= 1) v += __shfl_down(v, o, 64);
  return v;
}
__device__ __forceinline__ float waveMax(float v) {
  #pragma unroll
  for (int o = 32; o > 0; o >>= 1) v = fmaxf(v, __shfl_down(v, o, 64));
  return v;
}

__device__ __forceinline__ void gload_lds16(const void* g, void* l) {
  __builtin_amdgcn_global_load_lds((const __attribute__((address_space(1))) void*)g,
                                   (__attribute__((address_space(3))) void*)l, 16, 0, 0);
}

// ---- CSR build body: one block per row, single pass, uint4-vectorized
__device__ __forceinline__ void csr_body(const unsigned* __restrict__ adjw,
                                         const int* __restrict__ adjflag,
                                         int* __restrict__ nbr, int* __restrict__ cnt,
                                         int i, int* scn)
{
  const int tid = threadIdx.x;
  const int fmask = *adjflag;
  const bool bytemode = (fmask & 2) && !(fmask & 1);
  unsigned bits = 0;
  if (!bytemode) {
    const unsigned* row = adjw + (size_t)i * 4096 + tid * 16;
    #pragma unroll
    for (int ck = 0; ck < 4; ++ck) {
      uint4 v = *(const uint4*)(row + ck * 4);
      if (v.x) bits |= 1u << (ck * 4 + 0);
      if (v.y) bits |= 1u << (ck * 4 + 1);
      if (v.z) bits |= 1u << (ck * 4 + 2);
      if (v.w) bits |= 1u << (ck * 4 + 3);
    }
  } else {
    const unsigned* row = adjw + (size_t)i * 1024 + tid * 4;
    uint4 v = *(const uint4*)row;
    unsigned w4[4] = {v.x, v.y, v.z, v.w};
    #pragma unroll
    for (int wi = 0; wi < 4; ++wi)
      #pragma unroll
      for (int b = 0; b < 4; ++b)
        if ((w4[wi] >> (b * 8)) & 0xFFu) bits |= 1u << (wi * 4 + b);
  }
  int mycnt = __popc(bits);
  scn[tid] = mycnt;
  __syncthreads();
  for (int off = 1; off < 256; off <<= 1) {
    int v = (tid >= off) ? scn[tid - off] : 0;
    __syncthreads();
    scn[tid] += v;
    __syncthreads();
  }
  const int total = scn[255];
  int pos = scn[tid] - mycnt;
  #pragma unroll
  for (int b = 0; b < 16; ++b) {
    if (bits & (1u << b)) {
      if (pos < CAP) nbr[(size_t)i * CAP + pos] = tid * 16 + b;
      ++pos;
    }
  }
  if (tid == 0) cnt[i] = total;
}

// ---- transpose helper: Wt[n][k] (bf16, ld=Kpad) from W[k][n] (f32)
__device__ __forceinline__ void transpose_body(const float* Wsrc, u16* Wt,
                                               int K, int N, int Kpad,
                                               int bx, int by) {
  __shared__ float t[32][33];
  const int kb = by * 32, nb = bx * 32;
  const int tx = threadIdx.x, ty = threadIdx.y;  // 32 x 8
  for (int i = ty; i < 32; i += 8) {
    int k = kb + i, n = nb + tx;
    t[i][tx] = (k < K && n < N) ? Wsrc[(size_t)k * N + n] : 0.f;
  }
  __syncthreads();
  for (int i = ty; i < 32; i += 8) {
    int n = nb + i, k = kb + tx;
    if (n < N && k < Kpad) Wt[(size_t)n * Kpad + k] = f2bf(t[tx][i]);
  }
}

// ---- ALL weight transposes + X f32->bf16 + adj dtype probe in ONE dispatch
// [0,2048) fc2 | [2048,2560) W0 | [2560,2696) W1 | [2696,2832) W2 | [2832,2976) fc1 |
// [2976,7072) X convert | [7072,7328) detect_adj (flag pre-zeroed via memset)
__global__ __launch_bounds__(256) void prep_all(
    const float* __restrict__ W0, u16* __restrict__ W0t,
    const float* __restrict__ W1, u16* __restrict__ W1t,
    const float* __restrict__ W2, u16* __restrict__ W2t,
    const float* __restrict__ fc1w, u16* __restrict__ fc1t,
    const float* __restrict__ fc2w, u16* __restrict__ fc2t,
    const float* __restrict__ X, u16* __restrict__ Xb,
    const unsigned* __restrict__ adjw, int* __restrict__ flag)
{
  const int i = blockIdx.x;
  if (i < 2048) {
    transpose_body(fc2w, fc2t, 512, 4096, 512, i & 127, i >> 7);
  } else if (i < 2560) {
    int j = i - 2048;
    transpose_body(W0, W0t, 1024, 512, 1024, j & 15, j >> 4);
  } else if (i < 2696) {
    int j = i - 2560;
    transpose_body(W1, W1t, 528, 256, 544, j & 7, j >> 3);
  } else if (i < 2832) {
    int j = i - 2696;
    transpose_body(W2, W2t, 528, 256, 544, j & 7, j >> 3);
  } else if (i < 2976) {
    int j = i - 2832;
    transpose_body(fc1w, fc1t, 272, 512, 288, j & 15, j >> 4);
  } else if (i < 7072) {
    int j = i - 2976;
    int idx = j * 256 + threadIdx.y * 32 + threadIdx.x;
    float4 v = ((const float4*)X)[idx];
    u16x4 o = {f2bf(v.x), f2bf(v.y), f2bf(v.z), f2bf(v.w)};
    ((u16x4*)Xb)[idx] = o;
  } else {
    int j = i - 7072;
    int t = threadIdx.y * 32 + threadIdx.x;
    int f = 0;
    for (int idx = j * 256 + t; idx < 524288; idx += 65536) {
      unsigned v = adjw[idx];
      if (v == 0x3F800000u) f |= 1;
      else if (v > 1u) f |= 2;
    }
    if (f) atomicOr(flag, f);
  }
}

// ---- bf16 MFMA GEMM 128x64-tile body (dbuf + counted vmcnt, staged epilogue, XCD swizzle)
template<int ACT, bool OBF>
__device__ __forceinline__ void gemm64_dev(
    const u16* __restrict__ A, int lda,
    const u16* __restrict__ Bt, int ldb,
    void* __restrict__ Cout, int ldc,
    int K, const float* __restrict__ bias,
    u16 (&As)[2][128 * 32], u16 (&Bs)[2][64 * 32], int bid)
{
  const int tid = threadIdx.x;
  const int lane = tid & 63, wv = tid >> 6;
  const int wm = wv >> 1, wn = wv & 1;
  const int swz = ((bid & 7) << 5) | (bid >> 3);
  const int m0 = (swz >> 3) * 128, n0 = (swz & 7) * 64;
  const int nk = K >> 5;

  f32x4 acc[4][2] = {};

  auto STAGE = [&](int buf, int kt) {
    #pragma unroll
    for (int i = 0; i < 2; ++i) {
      int c = tid + i * 256;
      int r = c >> 2;
      int s = (c & 3) ^ ((r >> 1) & 3);
      gload_lds16(A + (size_t)(m0 + r) * lda + kt * 32 + s * 8, (char*)As[buf] + (c & ~63) * 16);
    }
    {
      int c = tid;
      int r = c >> 2;
      int s = (c & 3) ^ ((r >> 1) & 3);
      gload_lds16(Bt + (size_t)(n0 + r) * ldb + kt * 32 + s * 8, (char*)Bs[buf] + (c & ~63) * 16);
    }
  };

  STAGE(0, 0);
  if (nk > 1) STAGE(1, 1);

  int cur = 0;
  for (int kt = 0; kt < nk; ++kt) {
    if (kt + 1 < nk) { asm volatile("s_waitcnt vmcnt(3)" ::: "memory"); }
    else             { asm volatile("s_waitcnt vmcnt(0)" ::: "memory"); }
    __builtin_amdgcn_s_barrier();

    bf16x8 af[4], bf_[2];
    #pragma unroll
    for (int mi = 0; mi < 4; ++mi) {
      int r = wm * 64 + mi * 16 + (lane & 15);
      int sp = (lane >> 4) ^ ((r >> 1) & 3);
      af[mi] = *(const bf16x8*)((const char*)As[cur] + r * 64 + sp * 16);
    }
    #pragma unroll
    for (int ni = 0; ni < 2; ++ni) {
      int r = wn * 32 + ni * 16 + (lane & 15);
      int sp = (lane >> 4) ^ ((r >> 1) & 3);
      bf_[ni] = *(const bf16x8*)((const char*)Bs[cur] + r * 64 + sp * 16);
    }
    __builtin_amdgcn_s_setprio(1);
    #pragma unroll
    for (int mi = 0; mi < 4; ++mi)
      #pragma unroll
      for (int ni = 0; ni < 2; ++ni)
        acc[mi][ni] = __builtin_amdgcn_mfma_f32_16x16x32_bf16(af[mi], bf_[ni], acc[mi][ni], 0, 0, 0);
    __builtin_amdgcn_s_setprio(0);

    __builtin_amdgcn_s_barrier();
    if (kt + 2 < nk) STAGE(cur, kt + 2);
    cur ^= 1;
  }

  float bv2[2];
  #pragma unroll
  for (int ni = 0; ni < 2; ++ni)
    bv2[ni] = bias ? bias[n0 + wn * 32 + ni * 16 + (lane & 15)] : 0.f;
  float* sc = (float*)As;
  #pragma unroll
  for (int mi = 0; mi < 4; ++mi) {
    __syncthreads();
    const int lr = wm * 16 + (lane >> 4) * 4;
    #pragma unroll
    for (int ni = 0; ni < 2; ++ni) {
      const int lc = wn * 32 + ni * 16 + (lane & 15);
      #pragma unroll
      for (int j = 0; j < 4; ++j) {
        float v = acc[mi][ni][j] + bv2[ni];
        if (ACT == 1) v = fmaxf(v, 0.f);
        if (ACT == 2) v = 1.f / (1.f + __expf(-v));
        sc[(lr + j) * 64 + lc] = v;
      }
    }
    __syncthreads();
    #pragma unroll
    for (int u = 0; u < 2; ++u) {
      int idx = tid + u * 256;
      int r = idx >> 4, c4 = (idx & 15) * 4;
      int grow = m0 + (r >> 4) * 64 + mi * 16 + (r & 15);
      float4 v4 = *(const float4*)(sc + r * 64 + c4);
      if (OBF) {
        u16x4 o = {f2bf(v4.x), f2bf(v4.y), f2bf(v4.z), f2bf(v4.w)};
        *(u16x4*)((u16*)Cout + (size_t)grow * ldc + n0 + c4) = o;
      } else {
        *(float4*)((float*)Cout + (size_t)grow * ldc + n0 + c4) = v4;
      }
    }
  }
}

template<int ACT, bool OBF>
__global__ __launch_bounds__(256) void gemm_mfma64(
    const u16* __restrict__ A, int lda, const u16* __restrict__ Bt, int ldb,
    void* __restrict__ Cout, int ldc, int K, const float* __restrict__ bias)
{
  __shared__ u16 As[2][128 * 32];
  __shared__ u16 Bs[2][64 * 32];
  gemm64_dev<ACT, OBF>(A, lda, Bt, ldb, Cout, ldc, K, bias, As, Bs,
                       blockIdx.y * 8 + blockIdx.x);
}

// ---- merged dispatch: blocks [0,256) = gemm0 (Xb@W0t -> h0b bf16), [256,4352) = build_csr
__global__ __launch_bounds__(256) void csr_gemm0(
    const u16* __restrict__ Xb, const u16* __restrict__ W0t, u16* __restrict__ h0b,
    const unsigned* __restrict__ adjw, const int* __restrict__ adjflag,
    int* __restrict__ nbr, int* __restrict__ cnt)
{
  __shared__ u16 As[2][128 * 32];
  __shared__ u16 Bs[2][64 * 32];
  if (blockIdx.x < 256) {
    gemm64_dev<0, true>(Xb, 1024, W0t, 1024, h0b, 512, 1024, nullptr, As, Bs, blockIdx.x);
  } else {
    csr_body(adjw, adjflag, nbr, cnt, blockIdx.x - 256, (int*)As);
  }
}

// ---- fc2: 256x256 tile, BK=64, 8 waves, 8-PHASE counted-vmcnt schedule (T3+T4+T5),
//      LDS half-buffers [slot][half:128x64], staged NT epilogue, XCD swizzle. K even*64.
__global__ __launch_bounds__(512, 2) void gemm_fc2_8p(
    const u16* __restrict__ A, int lda,
    const u16* __restrict__ Bt, int ldb,
    float* __restrict__ Cout, int ldc,
    int K, const float* __restrict__ bias)
{
  __shared__ u16 As[2][2][128 * 64];   // [slot][half] 16KB each -> 64KB
  __shared__ u16 Bs[2][2][128 * 64];   // 64KB
  const int tid = threadIdx.x;
  const int lane = tid & 63, wv = tid >> 6;
  const int wm = wv >> 2, wn = wv & 3;          // 2 x 4; wave owns 128x64
  const int bid = blockIdx.y * 16 + blockIdx.x;
  const int swz = ((bid & 7) << 5) | (bid >> 3);
  const int m0 = (swz >> 4) * 256, n0 = (swz & 15) * 256;
  const int nk = K >> 6;

  f32x4 acc[8][4] = {};

  auto stA = [&](int slot, int h, int t) {      // 2 loads/thread (one 128x64 half)
    const u16* Ap = A + (size_t)(m0 + h * 128) * lda + t * 64;
    #pragma unroll
    for (int i = 0; i < 2; ++i) {
      int c = tid + i * 512;
      int r = c >> 3, sl = c & 7;
      int sg = sl ^ (r & 7);
      gload_lds16(Ap + (size_t)r * lda + sg * 8, (char*)&As[slot][h][0] + (c & ~63) * 16);
    }
  };
  auto stB = [&](int slot, int h, int t) {
    const u16* Bp = Bt + (size_t)(n0 + h * 128) * ldb + t * 64;
    #pragma unroll
    for (int i = 0; i < 2; ++i) {
      int c = tid + i * 512;
      int r = c >> 3, sl = c & 7;
      int sg = sl ^ (r & 7);
      gload_lds16(Bp + (size_t)r * ldb + sg * 8, (char*)&Bs[slot][h][0] + (c & ~63) * 16);
    }
  };

  bf16x8 afl[4][2], afh[4][2], bfl[2][2], bfh[2][2];
  auto rdAq = [&](int slot, int mi0, bf16x8 (&dst)[4][2]) {
    #pragma unroll
    for (int m = 0; m < 4; ++m)
      #pragma unroll
      for (int ks = 0; ks < 2; ++ks) {
        int r = (mi0 + m) * 16 + (lane & 15);
        int sl = (ks * 4 + (lane >> 4)) ^ (r & 7);
        dst[m][ks] = *(const bf16x8*)((const char*)&As[slot][wm][0] + r * 128 + sl * 16);
      }
  };
  auto rdBq = [&](int slot, int ni0, bf16x8 (&dst)[2][2]) {
    #pragma unroll
    for (int n = 0; n < 2; ++n)
      #pragma unroll
      for (int ks = 0; ks < 2; ++ks) {
        int r = (wn & 1) * 64 + (ni0 + n) * 16 + (lane & 15);
        int sl = (ks * 4 + (lane >> 4)) ^ (r & 7);
        dst[n][ks] = *(const bf16x8*)((const char*)&Bs[slot][wn >> 1][0] + r * 128 + sl * 16);
      }
  };
  auto quad = [&](int mi0, int ni0, bf16x8 (&af)[4][2], bf16x8 (&bf)[2][2]) {
    __builtin_amdgcn_s_setprio(1);
    #pragma unroll
    for (int m = 0; m < 4; ++m)
      #pragma unroll
      for (int n = 0; n < 2; ++n)
        #pragma unroll
        for (int ks = 0; ks < 2; ++ks)
          acc[mi0 + m][ni0 + n] =
              __builtin_amdgcn_mfma_f32_16x16x32_bf16(af[m][ks], bf[n][ks], acc[mi0 + m][ni0 + n], 0, 0, 0);
    __builtin_amdgcn_s_setprio(0);
  };
  #define BARX() __builtin_amdgcn_s_barrier()

  // prologue: tile0 fully + A-halves of tile1 (12 loads/thread)
  stA(0, 0, 0); stA(0, 1, 0); stB(0, 0, 0); stB(0, 1, 0);
  stA(1, 0, 1); stA(1, 1, 1);
  asm volatile("s_waitcnt vmcnt(4)" ::: "memory");   // tile0 landed; Ah(1) in flight
  BARX();

  for (int j = 0; j < nk; j += 2) {
    const bool s2 = (j + 2) < nk;
    // ---- tile j (slot 0), 4 phases ----
    rdAq(0, 0, afl); rdBq(0, 0, bfl);          // P1
    stB(1, 0, j + 1);
    BARX(); quad(0, 0, afl, bfl); BARX();
    rdAq(0, 4, afh);                           // P2
    stB(1, 1, j + 1);
    BARX(); quad(4, 0, afh, bfl); BARX();
    rdBq(0, 2, bfh);                           // P3
    if (s2) stA(0, 0, j + 2);
    BARX(); quad(0, 2, afl, bfh); BARX();
    if (s2) {                                  // P4
      stA(0, 1, j + 2);
      asm volatile("s_waitcnt vmcnt(4)" ::: "memory");
    } else {
      asm volatile("s_waitcnt vmcnt(0)" ::: "memory");
    }
    BARX(); quad(4, 2, afh, bfh); BARX();
    // ---- tile j+1 (slot 1), 4 phases ----
    rdAq(1, 0, afl); rdBq(1, 0, bfl);          // P5
    if (s2) stB(0, 0, j + 2);
    BARX(); quad(0, 0, afl, bfl); BARX();
    rdAq(1, 4, afh);                           // P6
    if (s2) stB(0, 1, j + 2);
    BARX(); quad(4, 0, afh, bfl); BARX();
    rdBq(1, 2, bfh);                           // P7
    if (s2) stA(1, 0, j + 3);
    BARX(); quad(0, 2, afl, bfh); BARX();
    if (s2) {                                  // P8
      stA(1, 1, j + 3);
      asm volatile("s_waitcnt vmcnt(4)" ::: "memory");
    } else {
      asm volatile("s_waitcnt vmcnt(0)" ::: "memory");
    }
    BARX(); quad(4, 2, afh, bfh); BARX();
  }

  // epilogue: per-mi 32-row x 256-col band staged in LDS, coalesced NT writeback (sigmoid+bias)
  float bv4[4];
  #pragma unroll
  for (int ni = 0; ni < 4; ++ni)
    bv4[ni] = bias[n0 + wn * 64 + ni * 16 + (lane & 15)];
  float* sc = (float*)As;   // 32KB of the 64KB A region
  #pragma unroll
  for (int mi = 0; mi < 8; ++mi) {
    __syncthreads();
    const int lr = wm * 16 + (lane >> 4) * 4;
    #pragma unroll
    for (int ni = 0; ni < 4; ++ni) {
      const int lc = wn * 64 + ni * 16 + (lane & 15);
      #pragma unroll
      for (int j = 0; j < 4; ++j) {
        float v = acc[mi][ni][j] + bv4[ni];
        v = 1.f / (1.f + __expf(-v));
        sc[(lr + j) * 256 + lc] = v;
      }
    }
    __syncthreads();
    #pragma unroll
    for (int u = 0; u < 4; ++u) {
      int idx = tid + u * 512;
      int r = idx >> 6, c4 = (idx & 63) * 4;
      int grow = m0 + (r >> 4) * 128 + mi * 16 + (r & 15);
      f32x4 v4 = *(const f32x4*)(sc + r * 256 + c4);
      __builtin_nontemporal_store(v4, (f32x4*)(Cout + (size_t)grow * ldc + n0 + c4));
    }
  }
}

// ---- per-row attention scores, bf16 h (layer 0, F=512)
__global__ __launch_bounds__(256) void fsrc_fdst_bf16(
    const u16* __restrict__ h, const float* __restrict__ a,
    float* __restrict__ fs, float* __restrict__ fd)
{
  const int wid = threadIdx.x >> 6, lane = threadIdx.x & 63;
  const int row = blockIdx.x * 4 + wid;
  u16x8 hv = *(const u16x8*)(h + (size_t)row * 512 + lane * 8);
  float s0 = 0.f, s1 = 0.f;
  #pragma unroll
  for (int j = 0; j < 8; ++j) {
    float x = bf2f(hv[j]);
    s0 = fmaf(x, a[lane * 8 + j], s0);
    s1 = fmaf(x, a[512 + lane * 8 + j], s1);
  }
  s0 = waveSum(s0);
  s1 = waveSum(s1);
  if (lane == 0) { fs[row] = s0; fd[row] = s1; }
}

// ---- merged scores for layers 1&2 over h12 [4096][512] f32
__global__ __launch_bounds__(256) void fsrc_fdst12(
    const float* __restrict__ h12,
    const float* __restrict__ a1, const float* __restrict__ a2,
    float* __restrict__ fs1, float* __restrict__ fd1,
    float* __restrict__ fs2, float* __restrict__ fd2)
{
  const int wid = threadIdx.x >> 6, lane = threadIdx.x & 63;
  const int row = blockIdx.x * 4 + wid;
  const float* hr = h12 + (size_t)row * 512;
  float s0 = 0.f, s1 = 0.f, s2 = 0.f, s3 = 0.f;
  #pragma unroll
  for (int f = lane; f < 256; f += 64) {
    float h1v = hr[f], h2v = hr[256 + f];
    s0 = fmaf(h1v, a1[f], s0);
    s1 = fmaf(h1v, a1[256 + f], s1);
    s2 = fmaf(h2v, a2[f], s2);
    s3 = fmaf(h2v, a2[256 + f], s3);
  }
  s0 = waveSum(s0); s1 = waveSum(s1); s2 = waveSum(s2); s3 = waveSum(s3);
  if (lane == 0) { fs1[row] = s0; fd1[row] = s1; fs2[row] = s2; fd2[row] = s3; }
}

// ---- layer-0 aggregate via CSR (bf16 h): hb[row] = [elu(att@h0) (512) | Y (16) | 0 (16)]
__global__ __launch_bounds__(256) void agg_gat0(
    const u16* __restrict__ h,
    const float* __restrict__ fs, const float* __restrict__ fd,
    const int* __restrict__ nbr, const int* __restrict__ cnt,
    const float* __restrict__ Y, u16* __restrict__ hb)
{
  __shared__ int   nb[CAP];
  __shared__ float pbuf[CAP];
  __shared__ float redm[4], reds[4];
  const int i = blockIdx.x, tid = threadIdx.x;
  const int wid = tid >> 6, lane = tid & 63;
  int c = cnt[i]; if (c > CAP) c = CAP;
  const float fsi = fs[i];
  float2 acc = {0.f, 0.f};

  if (c > 0) {
    float e = -3.0e38f;
    if (tid < c) {
      int j = nbr[(size_t)i * CAP + tid];
      nb[tid] = j;
      float t = fsi + fd[j];
      e = t > 0.f ? t : LRELU_ALPHA * t;
    }
    float wm = waveMax(e);
    if (lane == 0) redm[wid] = wm;
    __syncthreads();
    const float gmax = fmaxf(fmaxf(redm[0], redm[1]), fmaxf(redm[2], redm[3]));
    float p = (tid < c) ? expf(e - gmax) : 0.f;
    float ws = waveSum(p);
    if (lane == 0) reds[wid] = ws;
    __syncthreads();
    const float inv = 1.f / (reds[0] + reds[1] + reds[2] + reds[3]);
    if (tid < c) pbuf[tid] = p * inv;
    __syncthreads();
    const u16* hp = h + 2 * tid;
    #pragma unroll 4
    for (int n = 0; n < c; ++n) {
      u16x2 hv = *(const u16x2*)(hp + (size_t)nb[n] * 512);
      float pn = pbuf[n];
      acc.x = fmaf(pn, bf2f(hv[0]), acc.x);
      acc.y = fmaf(pn, bf2f(hv[1]), acc.y);
    }
  } else {
    const u16* hp = h + 2 * tid;
    for (int j = 0; j < NN; ++j) {
      u16x2 hv = *(const u16x2*)(hp + (size_t)j * 512);
      acc.x += bf2f(hv[0]); acc.y += bf2f(hv[1]);
    }
    acc.x *= (1.f / NN); acc.y *= (1.f / NN);
  }
  float vx = acc.x > 0.f ? acc.x : expm1f(acc.x);
  float vy = acc.y > 0.f ? acc.y : expm1f(acc.y);
  u16* row = hb + (size_t)i * 544;
  *(u16x2*)(row + 2 * tid) = u16x2{f2bf(vx), f2bf(vy)};
  if (tid < 8) {
    float2 yv = *(const float2*)(Y + (size_t)i * 16 + 2 * tid);
    *(u16x2*)(row + 512 + 2 * tid) = u16x2{f2bf(yv.x), f2bf(yv.y)};
  } else if (tid < 16) {
    *(u16x2*)(row + 528 + 2 * (tid - 8)) = u16x2{0, 0};
  }
}

// ---- fused layers 1+2 aggregate + reparam + concat (h12 f32, ld=512)
__global__ __launch_bounds__(256) void agg_gat12(
    const float* __restrict__ h12,
    const float* __restrict__ fs1, const float* __restrict__ fd1,
    const float* __restrict__ fs2, const float* __restrict__ fd2,
    const int* __restrict__ nbr, const int* __restrict__ cnt,
    const float* __restrict__ noise, const float* __restrict__ Y,
    u16* __restrict__ zcat)
{
  __shared__ int   nb[CAP];
  __shared__ float p1[CAP], p2[CAP];
  __shared__ float mn_s[256], lsd_s[256];
  __shared__ float redm1[4], redm2[4], reds1[4], reds2[4];
  const int i = blockIdx.x, tid = threadIdx.x;
  const int wid = tid >> 6, lane = tid & 63;
  int c = cnt[i]; if (c > CAP) c = CAP;
  const int half = tid >> 7, t = tid & 127;

  float2 acc = {0.f, 0.f};
  if (c > 0) {
    float e1 = -3.0e38f, e2 = -3.0e38f;
    if (tid < c) {
      int j = nbr[(size_t)i * CAP + tid];
      nb[tid] = j;
      float a1v = fs1[i] + fd1[j];
      float a2v = fs2[i] + fd2[j];
      e1 = a1v > 0.f ? a1v : LRELU_ALPHA * a1v;
      e2 = a2v > 0.f ? a2v : LRELU_ALPHA * a2v;
    }
    float wm1 = waveMax(e1), wm2 = waveMax(e2);
    if (lane == 0) { redm1[wid] = wm1; redm2[wid] = wm2; }
    __syncthreads();
    const float g1 = fmaxf(fmaxf(redm1[0], redm1[1]), fmaxf(redm1[2], redm1[3]));
    const float g2 = fmaxf(fmaxf(redm2[0], redm2[1]), fmaxf(redm2[2], redm2[3]));
    float pp1 = (tid < c) ? expf(e1 - g1) : 0.f;
    float pp2 = (tid < c) ? expf(e2 - g2) : 0.f;
    float ws1 = waveSum(pp1), ws2 = waveSum(pp2);
    if (lane == 0) { reds1[wid] = ws1; reds2[wid] = ws2; }
    __syncthreads();
    const float inv1 = 1.f / (reds1[0] + reds1[1] + reds1[2] + reds1[3]);
    const float inv2 = 1.f / (reds2[0] + reds2[1] + reds2[2] + reds2[3]);
    if (tid < c) { p1[tid] = pp1 * inv1; p2[tid] = pp2 * inv2; }
    __syncthreads();
    const float* hh = h12 + (half ? 256 : 0) + 2 * t;
    const float* pp = half ? p2 : p1;
    #pragma unroll 4
    for (int n = 0; n < c; ++n) {
      float2 hv = *(const float2*)(hh + (size_t)nb[n] * 512);
      float pn = pp[n];
      acc.x = fmaf(pn, hv.x, acc.x);
      acc.y = fmaf(pn, hv.y, acc.y);
    }
  } else {
    const float* hh = h12 + (half ? 256 : 0) + 2 * t;
    for (int j = 0; j < NN; ++j) {
      float2 hv = *(const float2*)(hh + (size_t)j * 512);
      acc.x += hv.x; acc.y += hv.y;
    }
    acc.x *= (1.f / NN); acc.y *= (1.f / NN);
  }
  float vx = acc.x > 0.f ? acc.x : expm1f(acc.x);
  float vy = acc.y > 0.f ? acc.y : expm1f(acc.y);
  float* dst = half ? lsd_s : mn_s;
  dst[2 * t] = vx; dst[2 * t + 1] = vy;
  __syncthreads();
  u16* row = zcat + (size_t)i * 288;
  if (tid < 128) {
    const int f = 2 * tid;
    float2 nz = *(const float2*)(noise + (size_t)i * 256 + f);
    float zx = fmaf(nz.x, expf(lsd_s[f]), mn_s[f]);
    float zy = fmaf(nz.y, expf(lsd_s[f + 1]), mn_s[f + 1]);
    *(u16x2*)(row + f) = u16x2{f2bf(zx), f2bf(zy)};
  } else if (tid < 136) {
    const int k = tid - 128;
    float2 yv = *(const float2*)(Y + (size_t)i * 16 + 2 * k);
    *(u16x2*)(row + 256 + 2 * k) = u16x2{f2bf(yv.x), f2bf(yv.y)};
  } else if (tid < 144) {
    *(u16x2*)(row + 272 + 2 * (tid - 136)) = u16x2{0, 0};
  }
}

extern "C" void kernel_launch(void* const* d_in, const int* in_sizes, int n_in,
                              void* d_out, int out_size, void* d_ws, size_t ws_size,
                              hipStream_t stream)
{
  const float* X     = (const float*)d_in[0];
  const float* Y     = (const float*)d_in[1];
  const float* noise = (const float*)d_in[2];
  const void*  adj   = d_in[3];
  const float* W0    = (const float*)d_in[4];
  const float* a0    = (const float*)d_in[5];
  const float* W1    = (const float*)d_in[6];
  const float* a1    = (const float*)d_in[7];
  const float* W2    = (const float*)d_in[8];
  const float* a2    = (const float*)d_in[9];
  const float* fc1w  = (const float*)d_in[10];
  const float* fc1b  = (const float*)d_in[11];
  const float* fc2w  = (const float*)d_in[12];
  const float* fc2b  = (const float*)d_in[13];
  float* out = (float*)d_out;
  char* W = (char*)d_ws;

  // workspace layout (bytes), ~31.7 MB
  u16*   Xb    = (u16*)(W + 0);            // 4096x1024 bf16 (dead after gemm0)
  u16*   zcatb = (u16*)(W + 0);            // 4096x288 bf16
  u16*   zzb   = (u16*)(W + 2359296);      // 4096x512 bf16
  u16*   h0b   = (u16*)(W + 8388608);      // 4096x512 bf16 (dead after agg0)
  float* h12   = (float*)(W + 8388608);    // 4096x512 f32 (reuses h0b region)
  u16*   hb    = (u16*)(W + 16777216);     // 4096x544 bf16
  u16*   W0t   = (u16*)(W + 21233664);     // 512x1024
  u16*   W12t  = (u16*)(W + 22282240);     // 512x544
  u16*   fc1t  = (u16*)(W + 22839296);     // 512x288
  u16*   fc2t  = (u16*)(W + 23134208);     // 4096x512
  int*   nbr   = (int*)(W + 27328512);     // 4096x256 int
  int*   cnt   = (int*)(W + 31522816);     // 4096 int
  float* fs0   = (float*)(W + 31539200);
  float* fd0   = fs0 + 4096;
  float* fs1   = fd0 + 4096;
  float* fd1   = fs1 + 4096;
  float* fs2   = fd1 + 4096;
  float* fd2   = fs2 + 4096;
  int*   flag  = (int*)(fd2 + 4096);

  hipMemsetAsync(flag, 0, 4, stream);
  prep_all<<<7328, dim3(32, 8), 0, stream>>>(W0, W0t, W1, W12t, W2, W12t + 256 * 544,
                                             fc1w, fc1t, fc2w, fc2t, X, Xb,
                                             (const unsigned*)adj, flag);

  // gemm0 (256 blocks) overlapped with build_csr (4096 blocks) in one dispatch
  csr_gemm0<<<4352, 256, 0, stream>>>(Xb, W0t, h0b, (const unsigned*)adj, flag, nbr, cnt);

  fsrc_fdst_bf16<<<1024, 256, 0, stream>>>(h0b, a0, fs0, fd0);
  agg_gat0<<<4096, 256, 0, stream>>>(h0b, fs0, fd0, nbr, cnt, Y, hb);

  // GAT layers 1 & 2 merged: h12 = hb @ [W1|W2] (f32)
  gemm_mfma64<0, false><<<dim3(8, 32), 256, 0, stream>>>(hb, 544, W12t, 544, h12, 512, 544, nullptr);
  fsrc_fdst12<<<1024, 256, 0, stream>>>(h12, a1, a2, fs1, fd1, fs2, fd2);
  agg_gat12<<<4096, 256, 0, stream>>>(h12, fs1, fd1, fs2, fd2, nbr, cnt, noise, Y, zcatb);

  // decoder
  gemm_mfma64<1, true><<<dim3(8, 32), 256, 0, stream>>>(zcatb, 288, fc1t, 288, zzb, 512, 288, fc1b);
  gemm_fc2_8p<<<dim3(16, 16), 512, 0, stream>>>(zzb, 512, fc2t, 512, out, 4096, 512, fc2b);
}

// Round 11
// 138.971 us; speedup vs baseline: 4.0446x; 1.0361x over previous
//
#include <hip/hip_runtime.h>

#define LRELU_ALPHA 0.2f
#define NN 4096
#define CAP 256

typedef unsigned short u16;
typedef short bf16x8 __attribute__((ext_vector_type(8)));
typedef float f32x4 __attribute__((ext_vector_type(4)));
typedef u16 u16x4 __attribute__((ext_vector_type(4)));
typedef u16 u16x2 __attribute__((ext_vector_type(2)));
typedef u16 u16x8 __attribute__((ext_vector_type(8)));

__device__ __forceinline__ u16 f2bf(float f) {
  unsigned u = __float_as_uint(f);
  u += 0x7FFFu + ((u >> 16) & 1u);
  return (u16)(u >> 16);
}
__device__ __forceinline__ float bf2f(u16 u) {
  return __uint_as_float(((unsigned)u) << 16);
}

__device__ __forceinline__ float waveSum(float v) {
  #pragma unroll
  for (int o = 32; o > 0; o >>= 1) v += __shfl_down(v, o, 64);
  return v;
}
__device__ __forceinline__ float waveMax(float v) {
  #pragma unroll
  for (int o = 32; o > 0; o >>= 1) v = fmaxf(v, __shfl_down(v, o, 64));
  return v;
}

__device__ __forceinline__ void gload_lds16(const void* g, void* l) {
  __builtin_amdgcn_global_load_lds((const __attribute__((address_space(1))) void*)g,
                                   (__attribute__((address_space(3))) void*)l, 16, 0, 0);
}

// ---- CSR build body: one block per row, single pass, uint4-vectorized
__device__ __forceinline__ void csr_body(const unsigned* __restrict__ adjw,
                                         const int* __restrict__ adjflag,
                                         int* __restrict__ nbr, int* __restrict__ cnt,
                                         int i, int* scn)
{
  const int tid = threadIdx.x;
  const int fmask = *adjflag;
  const bool bytemode = (fmask & 2) && !(fmask & 1);
  unsigned bits = 0;
  if (!bytemode) {
    const unsigned* row = adjw + (size_t)i * 4096 + tid * 16;
    #pragma unroll
    for (int ck = 0; ck < 4; ++ck) {
      uint4 v = *(const uint4*)(row + ck * 4);
      if (v.x) bits |= 1u << (ck * 4 + 0);
      if (v.y) bits |= 1u << (ck * 4 + 1);
      if (v.z) bits |= 1u << (ck * 4 + 2);
      if (v.w) bits |= 1u << (ck * 4 + 3);
    }
  } else {
    const unsigned* row = adjw + (size_t)i * 1024 + tid * 4;
    uint4 v = *(const uint4*)row;
    unsigned w4[4] = {v.x, v.y, v.z, v.w};
    #pragma unroll
    for (int wi = 0; wi < 4; ++wi)
      #pragma unroll
      for (int b = 0; b < 4; ++b)
        if ((w4[wi] >> (b * 8)) & 0xFFu) bits |= 1u << (wi * 4 + b);
  }
  int mycnt = __popc(bits);
  scn[tid] = mycnt;
  __syncthreads();
  for (int off = 1; off < 256; off <<= 1) {
    int v = (tid >= off) ? scn[tid - off] : 0;
    __syncthreads();
    scn[tid] += v;
    __syncthreads();
  }
  const int total = scn[255];
  int pos = scn[tid] - mycnt;
  #pragma unroll
  for (int b = 0; b < 16; ++b) {
    if (bits & (1u << b)) {
      if (pos < CAP) nbr[(size_t)i * CAP + pos] = tid * 16 + b;
      ++pos;
    }
  }
  if (tid == 0) cnt[i] = total;
}

// ---- transpose helper (flat 256 threads): Wt[n][k] (bf16, ld=Kpad) from W[k][n] (f32)
__device__ __forceinline__ void transpose_body(const float* Wsrc, u16* Wt,
                                               int K, int N, int Kpad,
                                               int bx, int by, float (*t)[33]) {
  const int kb = by * 32, nb = bx * 32;
  const int tx = threadIdx.x & 31, ty = threadIdx.x >> 5;  // 32 x 8
  for (int i = ty; i < 32; i += 8) {
    int k = kb + i, n = nb + tx;
    t[i][tx] = (k < K && n < N) ? Wsrc[(size_t)k * N + n] : 0.f;
  }
  __syncthreads();
  for (int i = ty; i < 32; i += 8) {
    int n = nb + i, k = kb + tx;
    if (n < N && k < Kpad) Wt[(size_t)n * Kpad + k] = f2bf(t[tx][i]);
  }
}

// ---- small weight transposes + X f32->bf16 + adj dtype probe (fc2 transpose moved out)
// [0,512) W0 | [512,648) W1 | [648,784) W2 | [784,928) fc1 | [928,5024) X | [5024,5280) detect
__global__ __launch_bounds__(256) void prep_all(
    const float* __restrict__ W0, u16* __restrict__ W0t,
    const float* __restrict__ W1, u16* __restrict__ W1t,
    const float* __restrict__ W2, u16* __restrict__ W2t,
    const float* __restrict__ fc1w, u16* __restrict__ fc1t,
    const float* __restrict__ X, u16* __restrict__ Xb,
    const unsigned* __restrict__ adjw, int* __restrict__ flag)
{
  __shared__ float t[32][33];
  const int i = blockIdx.x, tid = threadIdx.x;
  if (i < 512) {
    transpose_body(W0, W0t, 1024, 512, 1024, i & 15, i >> 4, t);
  } else if (i < 648) {
    int j = i - 512;
    transpose_body(W1, W1t, 528, 256, 544, j & 7, j >> 3, t);
  } else if (i < 784) {
    int j = i - 648;
    transpose_body(W2, W2t, 528, 256, 544, j & 7, j >> 3, t);
  } else if (i < 928) {
    int j = i - 784;
    transpose_body(fc1w, fc1t, 272, 512, 288, j & 15, j >> 4, t);
  } else if (i < 5024) {
    int j = i - 928;
    int idx = j * 256 + tid;
    float4 v = ((const float4*)X)[idx];
    u16x4 o = {f2bf(v.x), f2bf(v.y), f2bf(v.z), f2bf(v.w)};
    ((u16x4*)Xb)[idx] = o;
  } else {
    int j = i - 5024;
    int f = 0;
    for (int idx = j * 256 + tid; idx < 524288; idx += 65536) {
      unsigned v = adjw[idx];
      if (v == 0x3F800000u) f |= 1;
      else if (v > 1u) f |= 2;
    }
    if (f) atomicOr(flag, f);
  }
}

// ---- bf16 MFMA GEMM 128x64-tile body (dbuf + counted vmcnt, staged epilogue, XCD swizzle)
template<int ACT, bool OBF>
__device__ __forceinline__ void gemm64_dev(
    const u16* __restrict__ A, int lda,
    const u16* __restrict__ Bt, int ldb,
    void* __restrict__ Cout, int ldc,
    int K, const float* __restrict__ bias,
    u16 (&As)[2][128 * 32], u16 (&Bs)[2][64 * 32], int bid)
{
  const int tid = threadIdx.x;
  const int lane = tid & 63, wv = tid >> 6;
  const int wm = wv >> 1, wn = wv & 1;
  const int swz = ((bid & 7) << 5) | (bid >> 3);
  const int m0 = (swz >> 3) * 128, n0 = (swz & 7) * 64;
  const int nk = K >> 5;

  f32x4 acc[4][2] = {};

  auto STAGE = [&](int buf, int kt) {
    #pragma unroll
    for (int i = 0; i < 2; ++i) {
      int c = tid + i * 256;
      int r = c >> 2;
      int s = (c & 3) ^ ((r >> 1) & 3);
      gload_lds16(A + (size_t)(m0 + r) * lda + kt * 32 + s * 8, (char*)As[buf] + (c & ~63) * 16);
    }
    {
      int c = tid;
      int r = c >> 2;
      int s = (c & 3) ^ ((r >> 1) & 3);
      gload_lds16(Bt + (size_t)(n0 + r) * ldb + kt * 32 + s * 8, (char*)Bs[buf] + (c & ~63) * 16);
    }
  };

  STAGE(0, 0);
  if (nk > 1) STAGE(1, 1);

  int cur = 0;
  for (int kt = 0; kt < nk; ++kt) {
    if (kt + 1 < nk) { asm volatile("s_waitcnt vmcnt(3)" ::: "memory"); }
    else             { asm volatile("s_waitcnt vmcnt(0)" ::: "memory"); }
    __builtin_amdgcn_s_barrier();

    bf16x8 af[4], bf_[2];
    #pragma unroll
    for (int mi = 0; mi < 4; ++mi) {
      int r = wm * 64 + mi * 16 + (lane & 15);
      int sp = (lane >> 4) ^ ((r >> 1) & 3);
      af[mi] = *(const bf16x8*)((const char*)As[cur] + r * 64 + sp * 16);
    }
    #pragma unroll
    for (int ni = 0; ni < 2; ++ni) {
      int r = wn * 32 + ni * 16 + (lane & 15);
      int sp = (lane >> 4) ^ ((r >> 1) & 3);
      bf_[ni] = *(const bf16x8*)((const char*)Bs[cur] + r * 64 + sp * 16);
    }
    __builtin_amdgcn_s_setprio(1);
    #pragma unroll
    for (int mi = 0; mi < 4; ++mi)
      #pragma unroll
      for (int ni = 0; ni < 2; ++ni)
        acc[mi][ni] = __builtin_amdgcn_mfma_f32_16x16x32_bf16(af[mi], bf_[ni], acc[mi][ni], 0, 0, 0);
    __builtin_amdgcn_s_setprio(0);

    __builtin_amdgcn_s_barrier();
    if (kt + 2 < nk) STAGE(cur, kt + 2);
    cur ^= 1;
  }

  float bv2[2];
  #pragma unroll
  for (int ni = 0; ni < 2; ++ni)
    bv2[ni] = bias ? bias[n0 + wn * 32 + ni * 16 + (lane & 15)] : 0.f;
  float* sc = (float*)As;
  #pragma unroll
  for (int mi = 0; mi < 4; ++mi) {
    __syncthreads();
    const int lr = wm * 16 + (lane >> 4) * 4;
    #pragma unroll
    for (int ni = 0; ni < 2; ++ni) {
      const int lc = wn * 32 + ni * 16 + (lane & 15);
      #pragma unroll
      for (int j = 0; j < 4; ++j) {
        float v = acc[mi][ni][j] + bv2[ni];
        if (ACT == 1) v = fmaxf(v, 0.f);
        if (ACT == 2) v = 1.f / (1.f + __expf(-v));
        sc[(lr + j) * 64 + lc] = v;
      }
    }
    __syncthreads();
    #pragma unroll
    for (int u = 0; u < 2; ++u) {
      int idx = tid + u * 256;
      int r = idx >> 4, c4 = (idx & 15) * 4;
      int grow = m0 + (r >> 4) * 64 + mi * 16 + (r & 15);
      float4 v4 = *(const float4*)(sc + r * 64 + c4);
      if (OBF) {
        u16x4 o = {f2bf(v4.x), f2bf(v4.y), f2bf(v4.z), f2bf(v4.w)};
        *(u16x4*)((u16*)Cout + (size_t)grow * ldc + n0 + c4) = o;
      } else {
        *(float4*)((float*)Cout + (size_t)grow * ldc + n0 + c4) = v4;
      }
    }
  }
}

template<int ACT, bool OBF>
__global__ __launch_bounds__(256) void gemm_mfma64(
    const u16* __restrict__ A, int lda, const u16* __restrict__ Bt, int ldb,
    void* __restrict__ Cout, int ldc, int K, const float* __restrict__ bias)
{
  __shared__ u16 As[2][128 * 32];
  __shared__ u16 Bs[2][64 * 32];
  gemm64_dev<ACT, OBF>(A, lda, Bt, ldb, Cout, ldc, K, bias, As, Bs,
                       blockIdx.y * 8 + blockIdx.x);
}

// ---- merged dispatch: [0,256) gemm0 | [256,4352) build_csr | [4352,6400) fc2 transpose
__global__ __launch_bounds__(256) void csr_gemm0(
    const u16* __restrict__ Xb, const u16* __restrict__ W0t, u16* __restrict__ h0b,
    const unsigned* __restrict__ adjw, const int* __restrict__ adjflag,
    int* __restrict__ nbr, int* __restrict__ cnt,
    const float* __restrict__ fc2w, u16* __restrict__ fc2t)
{
  __shared__ u16 As[2][128 * 32];
  __shared__ u16 Bs[2][64 * 32];
  if (blockIdx.x < 256) {
    gemm64_dev<0, true>(Xb, 1024, W0t, 1024, h0b, 512, 1024, nullptr, As, Bs, blockIdx.x);
  } else if (blockIdx.x < 4352) {
    csr_body(adjw, adjflag, nbr, cnt, blockIdx.x - 256, (int*)As);
  } else {
    int j = blockIdx.x - 4352;   // fc2: K=512 (16 k-tiles) x N=4096 (128 n-tiles)
    transpose_body(fc2w, fc2t, 512, 4096, 512, j & 127, j >> 7, (float(*)[33])As);
  }
}

// ---- fc2: 256x256 tile, BK=64, 8 waves, 8-PHASE counted-vmcnt schedule (T3+T4+T5),
//      LDS half-buffers [slot][half:128x64], staged NT epilogue, XCD swizzle. K even*64.
__global__ __launch_bounds__(512, 2) void gemm_fc2_8p(
    const u16* __restrict__ A, int lda,
    const u16* __restrict__ Bt, int ldb,
    float* __restrict__ Cout, int ldc,
    int K, const float* __restrict__ bias)
{
  __shared__ u16 As[2][2][128 * 64];   // [slot][half] 16KB each -> 64KB
  __shared__ u16 Bs[2][2][128 * 64];   // 64KB
  const int tid = threadIdx.x;
  const int lane = tid & 63, wv = tid >> 6;
  const int wm = wv >> 2, wn = wv & 3;          // 2 x 4; wave owns 128x64
  const int bid = blockIdx.y * 16 + blockIdx.x;
  const int swz = ((bid & 7) << 5) | (bid >> 3);
  const int m0 = (swz >> 4) * 256, n0 = (swz & 15) * 256;
  const int nk = K >> 6;

  f32x4 acc[8][4] = {};

  auto stA = [&](int slot, int h, int t) {      // 2 loads/thread (one 128x64 half)
    const u16* Ap = A + (size_t)(m0 + h * 128) * lda + t * 64;
    #pragma unroll
    for (int i = 0; i < 2; ++i) {
      int c = tid + i * 512;
      int r = c >> 3, sl = c & 7;
      int sg = sl ^ (r & 7);
      gload_lds16(Ap + (size_t)r * lda + sg * 8, (char*)&As[slot][h][0] + (c & ~63) * 16);
    }
  };
  auto stB = [&](int slot, int h, int t) {
    const u16* Bp = Bt + (size_t)(n0 + h * 128) * ldb + t * 64;
    #pragma unroll
    for (int i = 0; i < 2; ++i) {
      int c = tid + i * 512;
      int r = c >> 3, sl = c & 7;
      int sg = sl ^ (r & 7);
      gload_lds16(Bp + (size_t)r * ldb + sg * 8, (char*)&Bs[slot][h][0] + (c & ~63) * 16);
    }
  };

  bf16x8 afl[4][2], afh[4][2], bfl[2][2], bfh[2][2];
  auto rdAq = [&](int slot, int mi0, bf16x8 (&dst)[4][2]) {
    #pragma unroll
    for (int m = 0; m < 4; ++m)
      #pragma unroll
      for (int ks = 0; ks < 2; ++ks) {
        int r = (mi0 + m) * 16 + (lane & 15);
        int sl = (ks * 4 + (lane >> 4)) ^ (r & 7);
        dst[m][ks] = *(const bf16x8*)((const char*)&As[slot][wm][0] + r * 128 + sl * 16);
      }
  };
  auto rdBq = [&](int slot, int ni0, bf16x8 (&dst)[2][2]) {
    #pragma unroll
    for (int n = 0; n < 2; ++n)
      #pragma unroll
      for (int ks = 0; ks < 2; ++ks) {
        int r = (wn & 1) * 64 + (ni0 + n) * 16 + (lane & 15);
        int sl = (ks * 4 + (lane >> 4)) ^ (r & 7);
        dst[n][ks] = *(const bf16x8*)((const char*)&Bs[slot][wn >> 1][0] + r * 128 + sl * 16);
      }
  };
  auto quad = [&](int mi0, int ni0, bf16x8 (&af)[4][2], bf16x8 (&bf)[2][2]) {
    __builtin_amdgcn_s_setprio(1);
    #pragma unroll
    for (int m = 0; m < 4; ++m)
      #pragma unroll
      for (int n = 0; n < 2; ++n)
        #pragma unroll
        for (int ks = 0; ks < 2; ++ks)
          acc[mi0 + m][ni0 + n] =
              __builtin_amdgcn_mfma_f32_16x16x32_bf16(af[m][ks], bf[n][ks], acc[mi0 + m][ni0 + n], 0, 0, 0);
    __builtin_amdgcn_s_setprio(0);
  };
  #define BARX() __builtin_amdgcn_s_barrier()

  // prologue: tile0 fully + A-halves of tile1 (12 loads/thread)
  stA(0, 0, 0); stA(0, 1, 0); stB(0, 0, 0); stB(0, 1, 0);
  stA(1, 0, 1); stA(1, 1, 1);
  asm volatile("s_waitcnt vmcnt(4)" ::: "memory");   // tile0 landed; Ah(1) in flight
  BARX();

  for (int j = 0; j < nk; j += 2) {
    const bool s2 = (j + 2) < nk;
    // ---- tile j (slot 0), 4 phases ----
    rdAq(0, 0, afl); rdBq(0, 0, bfl);          // P1
    stB(1, 0, j + 1);
    BARX(); quad(0, 0, afl, bfl); BARX();
    rdAq(0, 4, afh);                           // P2
    stB(1, 1, j + 1);
    BARX(); quad(4, 0, afh, bfl); BARX();
    rdBq(0, 2, bfh);                           // P3
    if (s2) stA(0, 0, j + 2);
    BARX(); quad(0, 2, afl, bfh); BARX();
    if (s2) {                                  // P4
      stA(0, 1, j + 2);
      asm volatile("s_waitcnt vmcnt(4)" ::: "memory");
    } else {
      asm volatile("s_waitcnt vmcnt(0)" ::: "memory");
    }
    BARX(); quad(4, 2, afh, bfh); BARX();
    // ---- tile j+1 (slot 1), 4 phases ----
    rdAq(1, 0, afl); rdBq(1, 0, bfl);          // P5
    if (s2) stB(0, 0, j + 2);
    BARX(); quad(0, 0, afl, bfl); BARX();
    rdAq(1, 4, afh);                           // P6
    if (s2) stB(0, 1, j + 2);
    BARX(); quad(4, 0, afh, bfl); BARX();
    rdBq(1, 2, bfh);                           // P7
    if (s2) stA(1, 0, j + 3);
    BARX(); quad(0, 2, afl, bfh); BARX();
    if (s2) {                                  // P8
      stA(1, 1, j + 3);
      asm volatile("s_waitcnt vmcnt(4)" ::: "memory");
    } else {
      asm volatile("s_waitcnt vmcnt(0)" ::: "memory");
    }
    BARX(); quad(4, 2, afh, bfh); BARX();
  }

  // epilogue: per-mi 32-row x 256-col band staged in LDS, coalesced NT writeback (sigmoid+bias)
  float bv4[4];
  #pragma unroll
  for (int ni = 0; ni < 4; ++ni)
    bv4[ni] = bias[n0 + wn * 64 + ni * 16 + (lane & 15)];
  float* sc = (float*)As;   // 32KB of the 64KB A region
  #pragma unroll
  for (int mi = 0; mi < 8; ++mi) {
    __syncthreads();
    const int lr = wm * 16 + (lane >> 4) * 4;
    #pragma unroll
    for (int ni = 0; ni < 4; ++ni) {
      const int lc = wn * 64 + ni * 16 + (lane & 15);
      #pragma unroll
      for (int j = 0; j < 4; ++j) {
        float v = acc[mi][ni][j] + bv4[ni];
        v = 1.f / (1.f + __expf(-v));
        sc[(lr + j) * 256 + lc] = v;
      }
    }
    __syncthreads();
    #pragma unroll
    for (int u = 0; u < 4; ++u) {
      int idx = tid + u * 512;
      int r = idx >> 6, c4 = (idx & 63) * 4;
      int grow = m0 + (r >> 4) * 128 + mi * 16 + (r & 15);
      f32x4 v4 = *(const f32x4*)(sc + r * 256 + c4);
      __builtin_nontemporal_store(v4, (f32x4*)(Cout + (size_t)grow * ldc + n0 + c4));
    }
  }
}

// ---- per-row attention scores, bf16 h (layer 0, F=512)
__global__ __launch_bounds__(256) void fsrc_fdst_bf16(
    const u16* __restrict__ h, const float* __restrict__ a,
    float* __restrict__ fs, float* __restrict__ fd)
{
  const int wid = threadIdx.x >> 6, lane = threadIdx.x & 63;
  const int row = blockIdx.x * 4 + wid;
  u16x8 hv = *(const u16x8*)(h + (size_t)row * 512 + lane * 8);
  float s0 = 0.f, s1 = 0.f;
  #pragma unroll
  for (int j = 0; j < 8; ++j) {
    float x = bf2f(hv[j]);
    s0 = fmaf(x, a[lane * 8 + j], s0);
    s1 = fmaf(x, a[512 + lane * 8 + j], s1);
  }
  s0 = waveSum(s0);
  s1 = waveSum(s1);
  if (lane == 0) { fs[row] = s0; fd[row] = s1; }
}

// ---- merged scores for layers 1&2 over h12 [4096][512] f32
__global__ __launch_bounds__(256) void fsrc_fdst12(
    const float* __restrict__ h12,
    const float* __restrict__ a1, const float* __restrict__ a2,
    float* __restrict__ fs1, float* __restrict__ fd1,
    float* __restrict__ fs2, float* __restrict__ fd2)
{
  const int wid = threadIdx.x >> 6, lane = threadIdx.x & 63;
  const int row = blockIdx.x * 4 + wid;
  const float* hr = h12 + (size_t)row * 512;
  float s0 = 0.f, s1 = 0.f, s2 = 0.f, s3 = 0.f;
  #pragma unroll
  for (int f = lane; f < 256; f += 64) {
    float h1v = hr[f], h2v = hr[256 + f];
    s0 = fmaf(h1v, a1[f], s0);
    s1 = fmaf(h1v, a1[256 + f], s1);
    s2 = fmaf(h2v, a2[f], s2);
    s3 = fmaf(h2v, a2[256 + f], s3);
  }
  s0 = waveSum(s0); s1 = waveSum(s1); s2 = waveSum(s2); s3 = waveSum(s3);
  if (lane == 0) { fs1[row] = s0; fd1[row] = s1; fs2[row] = s2; fd2[row] = s3; }
}

// ---- layer-0 aggregate via CSR (bf16 h): TWO rows per block, 8B/lane gather
// hb[row] = [elu(att@h0) (512) | Y (16) | 0 (16)]
__global__ __launch_bounds__(256) void agg_gat0(
    const u16* __restrict__ h,
    const float* __restrict__ fs, const float* __restrict__ fd,
    const int* __restrict__ nbr, const int* __restrict__ cnt,
    const float* __restrict__ Y, u16* __restrict__ hb)
{
  __shared__ int   nb[2][CAP];
  __shared__ float pbuf[2][CAP];
  __shared__ float redm[4], reds[4];
  const int tid = threadIdx.x;
  const int hh = tid >> 7, t = tid & 127;       // half selects row
  const int wid = tid >> 6, lane = tid & 63;
  const int r = blockIdx.x * 2 + hh;
  int c = cnt[r]; if (c > CAP) c = CAP;
  const float fsi = fs[r];
  float4 acc = {0.f, 0.f, 0.f, 0.f};

  if (c > 0) {
    float e0 = -3.0e38f, e1 = -3.0e38f;
    if (t < c) {
      int j = nbr[(size_t)r * CAP + t];
      nb[hh][t] = j;
      float v = fsi + fd[j];
      e0 = v > 0.f ? v : LRELU_ALPHA * v;
    }
    if (t + 128 < c) {
      int j = nbr[(size_t)r * CAP + t + 128];
      nb[hh][t + 128] = j;
      float v = fsi + fd[j];
      e1 = v > 0.f ? v : LRELU_ALPHA * v;
    }
    float wm = waveMax(fmaxf(e0, e1));
    if (lane == 0) redm[wid] = wm;
    __syncthreads();
    const float gmax = fmaxf(redm[2 * hh], redm[2 * hh + 1]);
    float p0 = (t < c) ? __expf(e0 - gmax) : 0.f;
    float p1 = (t + 128 < c) ? __expf(e1 - gmax) : 0.f;
    float ws = waveSum(p0 + p1);
    if (lane == 0) reds[wid] = ws;
    __syncthreads();
    const float inv = 1.f / (reds[2 * hh] + reds[2 * hh + 1]);
    if (t < c) pbuf[hh][t] = p0 * inv;
    if (t + 128 < c) pbuf[hh][t + 128] = p1 * inv;
    __syncthreads();
    const u16* hp = h + 4 * t;
    #pragma unroll 4
    for (int n = 0; n < c; ++n) {
      u16x4 hv = *(const u16x4*)(hp + (size_t)nb[hh][n] * 512);
      float pn = pbuf[hh][n];
      acc.x = fmaf(pn, bf2f(hv[0]), acc.x);
      acc.y = fmaf(pn, bf2f(hv[1]), acc.y);
      acc.z = fmaf(pn, bf2f(hv[2]), acc.z);
      acc.w = fmaf(pn, bf2f(hv[3]), acc.w);
    }
  } else {
    const u16* hp = h + 4 * t;
    for (int j = 0; j < NN; ++j) {
      u16x4 hv = *(const u16x4*)(hp + (size_t)j * 512);
      acc.x += bf2f(hv[0]); acc.y += bf2f(hv[1]);
      acc.z += bf2f(hv[2]); acc.w += bf2f(hv[3]);
    }
    acc.x *= (1.f / NN); acc.y *= (1.f / NN);
    acc.z *= (1.f / NN); acc.w *= (1.f / NN);
  }
  float vx = acc.x > 0.f ? acc.x : expm1f(acc.x);
  float vy = acc.y > 0.f ? acc.y : expm1f(acc.y);
  float vz = acc.z > 0.f ? acc.z : expm1f(acc.z);
  float vw = acc.w > 0.f ? acc.w : expm1f(acc.w);
  u16* row = hb + (size_t)r * 544;
  *(u16x4*)(row + 4 * t) = u16x4{f2bf(vx), f2bf(vy), f2bf(vz), f2bf(vw)};
  if (t < 8) {
    float2 yv = *(const float2*)(Y + (size_t)r * 16 + 2 * t);
    *(u16x2*)(row + 512 + 2 * t) = u16x2{f2bf(yv.x), f2bf(yv.y)};
  } else if (t < 16) {
    *(u16x2*)(row + 528 + 2 * (t - 8)) = u16x2{0, 0};
  }
}

// ---- fused layers 1+2 aggregate + reparam + concat (h12 f32, ld=512)
__global__ __launch_bounds__(256) void agg_gat12(
    const float* __restrict__ h12,
    const float* __restrict__ fs1, const float* __restrict__ fd1,
    const float* __restrict__ fs2, const float* __restrict__ fd2,
    const int* __restrict__ nbr, const int* __restrict__ cnt,
    const float* __restrict__ noise, const float* __restrict__ Y,
    u16* __restrict__ zcat)
{
  __shared__ int   nb[CAP];
  __shared__ float p1[CAP], p2[CAP];
  __shared__ float mn_s[256], lsd_s[256];
  __shared__ float redm1[4], redm2[4], reds1[4], reds2[4];
  const int i = blockIdx.x, tid = threadIdx.x;
  const int wid = tid >> 6, lane = tid & 63;
  int c = cnt[i]; if (c > CAP) c = CAP;
  const int half = tid >> 7, t = tid & 127;

  float2 acc = {0.f, 0.f};
  if (c > 0) {
    float e1 = -3.0e38f, e2 = -3.0e38f;
    if (tid < c) {
      int j = nbr[(size_t)i * CAP + tid];
      nb[tid] = j;
      float a1v = fs1[i] + fd1[j];
      float a2v = fs2[i] + fd2[j];
      e1 = a1v > 0.f ? a1v : LRELU_ALPHA * a1v;
      e2 = a2v > 0.f ? a2v : LRELU_ALPHA * a2v;
    }
    float wm1 = waveMax(e1), wm2 = waveMax(e2);
    if (lane == 0) { redm1[wid] = wm1; redm2[wid] = wm2; }
    __syncthreads();
    const float g1 = fmaxf(fmaxf(redm1[0], redm1[1]), fmaxf(redm1[2], redm1[3]));
    const float g2 = fmaxf(fmaxf(redm2[0], redm2[1]), fmaxf(redm2[2], redm2[3]));
    float pp1 = (tid < c) ? __expf(e1 - g1) : 0.f;
    float pp2 = (tid < c) ? __expf(e2 - g2) : 0.f;
    float ws1 = waveSum(pp1), ws2 = waveSum(pp2);
    if (lane == 0) { reds1[wid] = ws1; reds2[wid] = ws2; }
    __syncthreads();
    const float inv1 = 1.f / (reds1[0] + reds1[1] + reds1[2] + reds1[3]);
    const float inv2 = 1.f / (reds2[0] + reds2[1] + reds2[2] + reds2[3]);
    if (tid < c) { p1[tid] = pp1 * inv1; p2[tid] = pp2 * inv2; }
    __syncthreads();
    const float* hh = h12 + (half ? 256 : 0) + 2 * t;
    const float* pp = half ? p2 : p1;
    #pragma unroll 4
    for (int n = 0; n < c; ++n) {
      float2 hv = *(const float2*)(hh + (size_t)nb[n] * 512);
      float pn = pp[n];
      acc.x = fmaf(pn, hv.x, acc.x);
      acc.y = fmaf(pn, hv.y, acc.y);
    }
  } else {
    const float* hh = h12 + (half ? 256 : 0) + 2 * t;
    for (int j = 0; j < NN; ++j) {
      float2 hv = *(const float2*)(hh + (size_t)j * 512);
      acc.x += hv.x; acc.y += hv.y;
    }
    acc.x *= (1.f / NN); acc.y *= (1.f / NN);
  }
  float vx = acc.x > 0.f ? acc.x : expm1f(acc.x);
  float vy = acc.y > 0.f ? acc.y : expm1f(acc.y);
  float* dst = half ? lsd_s : mn_s;
  dst[2 * t] = vx; dst[2 * t + 1] = vy;
  __syncthreads();
  u16* row = zcat + (size_t)i * 288;
  if (tid < 128) {
    const int f = 2 * tid;
    float2 nz = *(const float2*)(noise + (size_t)i * 256 + f);
    float zx = fmaf(nz.x, expf(lsd_s[f]), mn_s[f]);
    float zy = fmaf(nz.y, expf(lsd_s[f + 1]), mn_s[f + 1]);
    *(u16x2*)(row + f) = u16x2{f2bf(zx), f2bf(zy)};
  } else if (tid < 136) {
    const int k = tid - 128;
    float2 yv = *(const float2*)(Y + (size_t)i * 16 + 2 * k);
    *(u16x2*)(row + 256 + 2 * k) = u16x2{f2bf(yv.x), f2bf(yv.y)};
  } else if (tid < 144) {
    *(u16x2*)(row + 272 + 2 * (tid - 136)) = u16x2{0, 0};
  }
}

extern "C" void kernel_launch(void* const* d_in, const int* in_sizes, int n_in,
                              void* d_out, int out_size, void* d_ws, size_t ws_size,
                              hipStream_t stream)
{
  const float* X     = (const float*)d_in[0];
  const float* Y     = (const float*)d_in[1];
  const float* noise = (const float*)d_in[2];
  const void*  adj   = d_in[3];
  const float* W0    = (const float*)d_in[4];
  const float* a0    = (const float*)d_in[5];
  const float* W1    = (const float*)d_in[6];
  const float* a1    = (const float*)d_in[7];
  const float* W2    = (const float*)d_in[8];
  const float* a2    = (const float*)d_in[9];
  const float* fc1w  = (const float*)d_in[10];
  const float* fc1b  = (const float*)d_in[11];
  const float* fc2w  = (const float*)d_in[12];
  const float* fc2b  = (const float*)d_in[13];
  float* out = (float*)d_out;
  char* W = (char*)d_ws;

  // workspace layout (bytes), ~31.7 MB
  u16*   Xb    = (u16*)(W + 0);            // 4096x1024 bf16 (dead after gemm0)
  u16*   zcatb = (u16*)(W + 0);            // 4096x288 bf16
  u16*   zzb   = (u16*)(W + 2359296);      // 4096x512 bf16
  u16*   h0b   = (u16*)(W + 8388608);      // 4096x512 bf16 (dead after agg0)
  float* h12   = (float*)(W + 8388608);    // 4096x512 f32 (reuses h0b region)
  u16*   hb    = (u16*)(W + 16777216);     // 4096x544 bf16
  u16*   W0t   = (u16*)(W + 21233664);     // 512x1024
  u16*   W12t  = (u16*)(W + 22282240);     // 512x544
  u16*   fc1t  = (u16*)(W + 22839296);     // 512x288
  u16*   fc2t  = (u16*)(W + 23134208);     // 4096x512
  int*   nbr   = (int*)(W + 27328512);     // 4096x256 int
  int*   cnt   = (int*)(W + 31522816);     // 4096 int
  float* fs0   = (float*)(W + 31539200);
  float* fd0   = fs0 + 4096;
  float* fs1   = fd0 + 4096;
  float* fd1   = fs1 + 4096;
  float* fs2   = fd1 + 4096;
  float* fd2   = fs2 + 4096;
  int*   flag  = (int*)(fd2 + 4096);

  hipMemsetAsync(flag, 0, 4, stream);
  prep_all<<<5280, 256, 0, stream>>>(W0, W0t, W1, W12t, W2, W12t + 256 * 544,
                                     fc1w, fc1t, X, Xb, (const unsigned*)adj, flag);

  // gemm0 (256) + build_csr (4096, HBM-bound) + fc2 transpose (2048) in one dispatch
  csr_gemm0<<<6400, 256, 0, stream>>>(Xb, W0t, h0b, (const unsigned*)adj, flag, nbr, cnt,
                                      fc2w, fc2t);

  fsrc_fdst_bf16<<<1024, 256, 0, stream>>>(h0b, a0, fs0, fd0);
  agg_gat0<<<2048, 256, 0, stream>>>(h0b, fs0, fd0, nbr, cnt, Y, hb);

  // GAT layers 1 & 2 merged: h12 = hb @ [W1|W2] (f32)
  gemm_mfma64<0, false><<<dim3(8, 32), 256, 0, stream>>>(hb, 544, W12t, 544, h12, 512, 544, nullptr);
  fsrc_fdst12<<<1024, 256, 0, stream>>>(h12, a1, a2, fs1, fd1, fs2, fd2);
  agg_gat12<<<4096, 256, 0, stream>>>(h12, fs1, fd1, fs2, fd2, nbr, cnt, noise, Y, zcatb);

  // decoder
  gemm_mfma64<1, true><<<dim3(8, 32), 256, 0, stream>>>(zcatb, 288, fc1t, 288, zzb, 512, 288, fc1b);
  gemm_fc2_8p<<<dim3(16, 16), 512, 0, stream>>>(zzb, 512, fc2t, 512, out, 4096, 512, fc2b);
}

// Round 12
// 126.725 us; speedup vs baseline: 4.4355x; 1.0966x over previous
//
#include <hip/hip_runtime.h>

#define LRELU_ALPHA 0.2f
#define NN 4096
#define CAP 256

typedef unsigned short u16;
typedef short bf16x8 __attribute__((ext_vector_type(8)));
typedef float f32x4 __attribute__((ext_vector_type(4)));
typedef u16 u16x4 __attribute__((ext_vector_type(4)));
typedef u16 u16x2 __attribute__((ext_vector_type(2)));
typedef u16 u16x8 __attribute__((ext_vector_type(8)));

__device__ __forceinline__ u16 f2bf(float f) {
  unsigned u = __float_as_uint(f);
  u += 0x7FFFu + ((u >> 16) & 1u);
  return (u16)(u >> 16);
}
__device__ __forceinline__ float bf2f(u16 u) {
  return __uint_as_float(((unsigned)u) << 16);
}

__device__ __forceinline__ float waveSum(float v) {
  #pragma unroll
  for (int o = 32; o > 0; o >>= 1) v += __shfl_down(v, o, 64);
  return v;
}
__device__ __forceinline__ float waveMax(float v) {
  #pragma unroll
  for (int o = 32; o > 0; o >>= 1) v = fmaxf(v, __shfl_down(v, o, 64));
  return v;
}

__device__ __forceinline__ void gload_lds16(const void* g, void* l) {
  __builtin_amdgcn_global_load_lds((const __attribute__((address_space(1))) void*)g,
                                   (__attribute__((address_space(3))) void*)l, 16, 0, 0);
}

// ---- CSR build body: one block per row, single pass, uint4-vectorized
__device__ __forceinline__ void csr_body(const unsigned* __restrict__ adjw,
                                         const int* __restrict__ adjflag,
                                         int* __restrict__ nbr, int* __restrict__ cnt,
                                         int i, int* scn)
{
  const int tid = threadIdx.x;
  const int fmask = *adjflag;
  const bool bytemode = (fmask & 2) && !(fmask & 1);
  unsigned bits = 0;
  if (!bytemode) {
    const unsigned* row = adjw + (size_t)i * 4096 + tid * 16;
    #pragma unroll
    for (int ck = 0; ck < 4; ++ck) {
      uint4 v = *(const uint4*)(row + ck * 4);
      if (v.x) bits |= 1u << (ck * 4 + 0);
      if (v.y) bits |= 1u << (ck * 4 + 1);
      if (v.z) bits |= 1u << (ck * 4 + 2);
      if (v.w) bits |= 1u << (ck * 4 + 3);
    }
  } else {
    const unsigned* row = adjw + (size_t)i * 1024 + tid * 4;
    uint4 v = *(const uint4*)row;
    unsigned w4[4] = {v.x, v.y, v.z, v.w};
    #pragma unroll
    for (int wi = 0; wi < 4; ++wi)
      #pragma unroll
      for (int b = 0; b < 4; ++b)
        if ((w4[wi] >> (b * 8)) & 0xFFu) bits |= 1u << (wi * 4 + b);
  }
  int mycnt = __popc(bits);
  scn[tid] = mycnt;
  __syncthreads();
  for (int off = 1; off < 256; off <<= 1) {
    int v = (tid >= off) ? scn[tid - off] : 0;
    __syncthreads();
    scn[tid] += v;
    __syncthreads();
  }
  const int total = scn[255];
  int pos = scn[tid] - mycnt;
  #pragma unroll
  for (int b = 0; b < 16; ++b) {
    if (bits & (1u << b)) {
      if (pos < CAP) nbr[(size_t)i * CAP + pos] = tid * 16 + b;
      ++pos;
    }
  }
  if (tid == 0) cnt[i] = total;
}

// ---- transpose helper (flat 256 threads): Wt[n][k] (bf16, ld=Kpad) from W[k][n] (f32)
__device__ __forceinline__ void transpose_body(const float* Wsrc, u16* Wt,
                                               int K, int N, int Kpad,
                                               int bx, int by, float (*t)[33]) {
  const int kb = by * 32, nb = bx * 32;
  const int tx = threadIdx.x & 31, ty = threadIdx.x >> 5;  // 32 x 8
  for (int i = ty; i < 32; i += 8) {
    int k = kb + i, n = nb + tx;
    t[i][tx] = (k < K && n < N) ? Wsrc[(size_t)k * N + n] : 0.f;
  }
  __syncthreads();
  for (int i = ty; i < 32; i += 8) {
    int n = nb + i, k = kb + tx;
    if (n < N && k < Kpad) Wt[(size_t)n * Kpad + k] = f2bf(t[tx][i]);
  }
}

// ---- small weight transposes + X f32->bf16 + adj dtype probe
// [0,512) W0 | [512,648) W1 | [648,784) W2 | [784,928) fc1 | [928,5024) X | [5024,5280) detect
__global__ __launch_bounds__(256) void prep_all(
    const float* __restrict__ W0, u16* __restrict__ W0t,
    const float* __restrict__ W1, u16* __restrict__ W1t,
    const float* __restrict__ W2, u16* __restrict__ W2t,
    const float* __restrict__ fc1w, u16* __restrict__ fc1t,
    const float* __restrict__ X, u16* __restrict__ Xb,
    const unsigned* __restrict__ adjw, int* __restrict__ flag)
{
  __shared__ float t[32][33];
  const int i = blockIdx.x, tid = threadIdx.x;
  if (i < 512) {
    transpose_body(W0, W0t, 1024, 512, 1024, i & 15, i >> 4, t);
  } else if (i < 648) {
    int j = i - 512;
    transpose_body(W1, W1t, 528, 256, 544, j & 7, j >> 3, t);
  } else if (i < 784) {
    int j = i - 648;
    transpose_body(W2, W2t, 528, 256, 544, j & 7, j >> 3, t);
  } else if (i < 928) {
    int j = i - 784;
    transpose_body(fc1w, fc1t, 272, 512, 288, j & 15, j >> 4, t);
  } else if (i < 5024) {
    int j = i - 928;
    int idx = j * 256 + tid;
    float4 v = ((const float4*)X)[idx];
    u16x4 o = {f2bf(v.x), f2bf(v.y), f2bf(v.z), f2bf(v.w)};
    ((u16x4*)Xb)[idx] = o;
  } else {
    int j = i - 5024;
    int f = 0;
    for (int idx = j * 256 + tid; idx < 524288; idx += 65536) {
      unsigned v = adjw[idx];
      if (v == 0x3F800000u) f |= 1;
      else if (v > 1u) f |= 2;
    }
    if (f) atomicOr(flag, f);
  }
}

// ---- bf16 MFMA GEMM 128x64-tile body (dbuf + counted vmcnt, staged epilogue, XCD swizzle)
template<int ACT, bool OBF>
__device__ __forceinline__ void gemm64_dev(
    const u16* __restrict__ A, int lda,
    const u16* __restrict__ Bt, int ldb,
    void* __restrict__ Cout, int ldc,
    int K, const float* __restrict__ bias,
    u16 (&As)[2][128 * 32], u16 (&Bs)[2][64 * 32], int bid)
{
  const int tid = threadIdx.x;
  const int lane = tid & 63, wv = tid >> 6;
  const int wm = wv >> 1, wn = wv & 1;
  const int swz = ((bid & 7) << 5) | (bid >> 3);
  const int m0 = (swz >> 3) * 128, n0 = (swz & 7) * 64;
  const int nk = K >> 5;

  f32x4 acc[4][2] = {};

  auto STAGE = [&](int buf, int kt) {
    #pragma unroll
    for (int i = 0; i < 2; ++i) {
      int c = tid + i * 256;
      int r = c >> 2;
      int s = (c & 3) ^ ((r >> 1) & 3);
      gload_lds16(A + (size_t)(m0 + r) * lda + kt * 32 + s * 8, (char*)As[buf] + (c & ~63) * 16);
    }
    {
      int c = tid;
      int r = c >> 2;
      int s = (c & 3) ^ ((r >> 1) & 3);
      gload_lds16(Bt + (size_t)(n0 + r) * ldb + kt * 32 + s * 8, (char*)Bs[buf] + (c & ~63) * 16);
    }
  };

  STAGE(0, 0);
  if (nk > 1) STAGE(1, 1);

  int cur = 0;
  for (int kt = 0; kt < nk; ++kt) {
    if (kt + 1 < nk) { asm volatile("s_waitcnt vmcnt(3)" ::: "memory"); }
    else             { asm volatile("s_waitcnt vmcnt(0)" ::: "memory"); }
    __builtin_amdgcn_s_barrier();

    bf16x8 af[4], bf_[2];
    #pragma unroll
    for (int mi = 0; mi < 4; ++mi) {
      int r = wm * 64 + mi * 16 + (lane & 15);
      int sp = (lane >> 4) ^ ((r >> 1) & 3);
      af[mi] = *(const bf16x8*)((const char*)As[cur] + r * 64 + sp * 16);
    }
    #pragma unroll
    for (int ni = 0; ni < 2; ++ni) {
      int r = wn * 32 + ni * 16 + (lane & 15);
      int sp = (lane >> 4) ^ ((r >> 1) & 3);
      bf_[ni] = *(const bf16x8*)((const char*)Bs[cur] + r * 64 + sp * 16);
    }
    __builtin_amdgcn_s_setprio(1);
    #pragma unroll
    for (int mi = 0; mi < 4; ++mi)
      #pragma unroll
      for (int ni = 0; ni < 2; ++ni)
        acc[mi][ni] = __builtin_amdgcn_mfma_f32_16x16x32_bf16(af[mi], bf_[ni], acc[mi][ni], 0, 0, 0);
    __builtin_amdgcn_s_setprio(0);

    __builtin_amdgcn_s_barrier();
    if (kt + 2 < nk) STAGE(cur, kt + 2);
    cur ^= 1;
  }

  float bv2[2];
  #pragma unroll
  for (int ni = 0; ni < 2; ++ni)
    bv2[ni] = bias ? bias[n0 + wn * 32 + ni * 16 + (lane & 15)] : 0.f;
  float* sc = (float*)As;
  #pragma unroll
  for (int mi = 0; mi < 4; ++mi) {
    __syncthreads();
    const int lr = wm * 16 + (lane >> 4) * 4;
    #pragma unroll
    for (int ni = 0; ni < 2; ++ni) {
      const int lc = wn * 32 + ni * 16 + (lane & 15);
      #pragma unroll
      for (int j = 0; j < 4; ++j) {
        float v = acc[mi][ni][j] + bv2[ni];
        if (ACT == 1) v = fmaxf(v, 0.f);
        if (ACT == 2) v = 1.f / (1.f + __expf(-v));
        sc[(lr + j) * 64 + lc] = v;
      }
    }
    __syncthreads();
    #pragma unroll
    for (int u = 0; u < 2; ++u) {
      int idx = tid + u * 256;
      int r = idx >> 4, c4 = (idx & 15) * 4;
      int grow = m0 + (r >> 4) * 64 + mi * 16 + (r & 15);
      float4 v4 = *(const float4*)(sc + r * 64 + c4);
      if (OBF) {
        u16x4 o = {f2bf(v4.x), f2bf(v4.y), f2bf(v4.z), f2bf(v4.w)};
        *(u16x4*)((u16*)Cout + (size_t)grow * ldc + n0 + c4) = o;
      } else {
        *(float4*)((float*)Cout + (size_t)grow * ldc + n0 + c4) = v4;
      }
    }
  }
}

template<int ACT, bool OBF>
__global__ __launch_bounds__(256) void gemm_mfma64(
    const u16* __restrict__ A, int lda, const u16* __restrict__ Bt, int ldb,
    void* __restrict__ Cout, int ldc, int K, const float* __restrict__ bias)
{
  __shared__ u16 As[2][128 * 32];
  __shared__ u16 Bs[2][64 * 32];
  gemm64_dev<ACT, OBF>(A, lda, Bt, ldb, Cout, ldc, K, bias, As, Bs,
                       blockIdx.y * 8 + blockIdx.x);
}

// ---- merged dispatch: [0,256) gemm0 | [256,4352) build_csr | [4352,6400) fc2 transpose
__global__ __launch_bounds__(256) void csr_gemm0(
    const u16* __restrict__ Xb, const u16* __restrict__ W0t, u16* __restrict__ h0b,
    const unsigned* __restrict__ adjw, const int* __restrict__ adjflag,
    int* __restrict__ nbr, int* __restrict__ cnt,
    const float* __restrict__ fc2w, u16* __restrict__ fc2t)
{
  __shared__ u16 As[2][128 * 32];
  __shared__ u16 Bs[2][64 * 32];
  if (blockIdx.x < 256) {
    gemm64_dev<0, true>(Xb, 1024, W0t, 1024, h0b, 512, 1024, nullptr, As, Bs, blockIdx.x);
  } else if (blockIdx.x < 4352) {
    csr_body(adjw, adjflag, nbr, cnt, blockIdx.x - 256, (int*)As);
  } else {
    int j = blockIdx.x - 4352;   // fc2: K=512 (16 k-tiles) x N=4096 (128 n-tiles)
    transpose_body(fc2w, fc2t, 512, 4096, 512, j & 127, j >> 7, (float(*)[33])As);
  }
}

// ---- fc2: 256x256 tile, BK=64, 8 waves, 8-PHASE counted-vmcnt schedule (T3+T4+T5),
//      LDS half-buffers [slot][half:128x64], staged NT epilogue, XCD swizzle. K even*64.
__global__ __launch_bounds__(512, 2) void gemm_fc2_8p(
    const u16* __restrict__ A, int lda,
    const u16* __restrict__ Bt, int ldb,
    float* __restrict__ Cout, int ldc,
    int K, const float* __restrict__ bias)
{
  __shared__ u16 As[2][2][128 * 64];   // [slot][half] 16KB each -> 64KB
  __shared__ u16 Bs[2][2][128 * 64];   // 64KB
  const int tid = threadIdx.x;
  const int lane = tid & 63, wv = tid >> 6;
  const int wm = wv >> 2, wn = wv & 3;          // 2 x 4; wave owns 128x64
  const int bid = blockIdx.y * 16 + blockIdx.x;
  const int swz = ((bid & 7) << 5) | (bid >> 3);
  const int m0 = (swz >> 4) * 256, n0 = (swz & 15) * 256;
  const int nk = K >> 6;

  f32x4 acc[8][4] = {};

  auto stA = [&](int slot, int h, int t) {      // 2 loads/thread (one 128x64 half)
    const u16* Ap = A + (size_t)(m0 + h * 128) * lda + t * 64;
    #pragma unroll
    for (int i = 0; i < 2; ++i) {
      int c = tid + i * 512;
      int r = c >> 3, sl = c & 7;
      int sg = sl ^ (r & 7);
      gload_lds16(Ap + (size_t)r * lda + sg * 8, (char*)&As[slot][h][0] + (c & ~63) * 16);
    }
  };
  auto stB = [&](int slot, int h, int t) {
    const u16* Bp = Bt + (size_t)(n0 + h * 128) * ldb + t * 64;
    #pragma unroll
    for (int i = 0; i < 2; ++i) {
      int c = tid + i * 512;
      int r = c >> 3, sl = c & 7;
      int sg = sl ^ (r & 7);
      gload_lds16(Bp + (size_t)r * ldb + sg * 8, (char*)&Bs[slot][h][0] + (c & ~63) * 16);
    }
  };

  bf16x8 afl[4][2], afh[4][2], bfl[2][2], bfh[2][2];
  auto rdAq = [&](int slot, int mi0, bf16x8 (&dst)[4][2]) {
    #pragma unroll
    for (int m = 0; m < 4; ++m)
      #pragma unroll
      for (int ks = 0; ks < 2; ++ks) {
        int r = (mi0 + m) * 16 + (lane & 15);
        int sl = (ks * 4 + (lane >> 4)) ^ (r & 7);
        dst[m][ks] = *(const bf16x8*)((const char*)&As[slot][wm][0] + r * 128 + sl * 16);
      }
  };
  auto rdBq = [&](int slot, int ni0, bf16x8 (&dst)[2][2]) {
    #pragma unroll
    for (int n = 0; n < 2; ++n)
      #pragma unroll
      for (int ks = 0; ks < 2; ++ks) {
        int r = (wn & 1) * 64 + (ni0 + n) * 16 + (lane & 15);
        int sl = (ks * 4 + (lane >> 4)) ^ (r & 7);
        dst[n][ks] = *(const bf16x8*)((const char*)&Bs[slot][wn >> 1][0] + r * 128 + sl * 16);
      }
  };
  auto quad = [&](int mi0, int ni0, bf16x8 (&af)[4][2], bf16x8 (&bf)[2][2]) {
    __builtin_amdgcn_s_setprio(1);
    #pragma unroll
    for (int m = 0; m < 4; ++m)
      #pragma unroll
      for (int n = 0; n < 2; ++n)
        #pragma unroll
        for (int ks = 0; ks < 2; ++ks)
          acc[mi0 + m][ni0 + n] =
              __builtin_amdgcn_mfma_f32_16x16x32_bf16(af[m][ks], bf[n][ks], acc[mi0 + m][ni0 + n], 0, 0, 0);
    __builtin_amdgcn_s_setprio(0);
  };
  #define BARX() __builtin_amdgcn_s_barrier()

  // prologue: tile0 fully + A-halves of tile1 (12 loads/thread)
  stA(0, 0, 0); stA(0, 1, 0); stB(0, 0, 0); stB(0, 1, 0);
  stA(1, 0, 1); stA(1, 1, 1);
  asm volatile("s_waitcnt vmcnt(4)" ::: "memory");   // tile0 landed; Ah(1) in flight
  BARX();

  for (int j = 0; j < nk; j += 2) {
    const bool s2 = (j + 2) < nk;
    // ---- tile j (slot 0), 4 phases ----
    rdAq(0, 0, afl); rdBq(0, 0, bfl);          // P1
    stB(1, 0, j + 1);
    BARX(); quad(0, 0, afl, bfl); BARX();
    rdAq(0, 4, afh);                           // P2
    stB(1, 1, j + 1);
    BARX(); quad(4, 0, afh, bfl); BARX();
    rdBq(0, 2, bfh);                           // P3
    if (s2) stA(0, 0, j + 2);
    BARX(); quad(0, 2, afl, bfh); BARX();
    if (s2) {                                  // P4
      stA(0, 1, j + 2);
      asm volatile("s_waitcnt vmcnt(4)" ::: "memory");
    } else {
      asm volatile("s_waitcnt vmcnt(0)" ::: "memory");
    }
    BARX(); quad(4, 2, afh, bfh); BARX();
    // ---- tile j+1 (slot 1), 4 phases ----
    rdAq(1, 0, afl); rdBq(1, 0, bfl);          // P5
    if (s2) stB(0, 0, j + 2);
    BARX(); quad(0, 0, afl, bfl); BARX();
    rdAq(1, 4, afh);                           // P6
    if (s2) stB(0, 1, j + 2);
    BARX(); quad(4, 0, afh, bfl); BARX();
    rdBq(1, 2, bfh);                           // P7
    if (s2) stA(1, 0, j + 3);
    BARX(); quad(0, 2, afl, bfh); BARX();
    if (s2) {                                  // P8
      stA(1, 1, j + 3);
      asm volatile("s_waitcnt vmcnt(4)" ::: "memory");
    } else {
      asm volatile("s_waitcnt vmcnt(0)" ::: "memory");
    }
    BARX(); quad(4, 2, afh, bfh); BARX();
  }

  // epilogue: per-mi 32-row x 256-col band staged in LDS, coalesced NT writeback (sigmoid+bias)
  float bv4[4];
  #pragma unroll
  for (int ni = 0; ni < 4; ++ni)
    bv4[ni] = bias[n0 + wn * 64 + ni * 16 + (lane & 15)];
  float* sc = (float*)As;   // 32KB of the 64KB A region
  #pragma unroll
  for (int mi = 0; mi < 8; ++mi) {
    __syncthreads();
    const int lr = wm * 16 + (lane >> 4) * 4;
    #pragma unroll
    for (int ni = 0; ni < 4; ++ni) {
      const int lc = wn * 64 + ni * 16 + (lane & 15);
      #pragma unroll
      for (int j = 0; j < 4; ++j) {
        float v = acc[mi][ni][j] + bv4[ni];
        v = 1.f / (1.f + __expf(-v));
        sc[(lr + j) * 256 + lc] = v;
      }
    }
    __syncthreads();
    #pragma unroll
    for (int u = 0; u < 4; ++u) {
      int idx = tid + u * 512;
      int r = idx >> 6, c4 = (idx & 63) * 4;
      int grow = m0 + (r >> 4) * 128 + mi * 16 + (r & 15);
      f32x4 v4 = *(const f32x4*)(sc + r * 256 + c4);
      __builtin_nontemporal_store(v4, (f32x4*)(Cout + (size_t)grow * ldc + n0 + c4));
    }
  }
}

// ---- per-row attention scores, bf16 h (layer 0, F=512)
__global__ __launch_bounds__(256) void fsrc_fdst_bf16(
    const u16* __restrict__ h, const float* __restrict__ a,
    float* __restrict__ fs, float* __restrict__ fd)
{
  const int wid = threadIdx.x >> 6, lane = threadIdx.x & 63;
  const int row = blockIdx.x * 4 + wid;
  u16x8 hv = *(const u16x8*)(h + (size_t)row * 512 + lane * 8);
  float s0 = 0.f, s1 = 0.f;
  #pragma unroll
  for (int j = 0; j < 8; ++j) {
    float x = bf2f(hv[j]);
    s0 = fmaf(x, a[lane * 8 + j], s0);
    s1 = fmaf(x, a[512 + lane * 8 + j], s1);
  }
  s0 = waveSum(s0);
  s1 = waveSum(s1);
  if (lane == 0) { fs[row] = s0; fd[row] = s1; }
}

// ---- merged scores for layers 1&2 over h12b [4096][512] bf16 (cols 0-255 h1, 256-511 h2)
// lane j covers cols 8j..8j+7; lanes 0-31 -> (fs1,fd1), lanes 32-63 -> (fs2,fd2)
__global__ __launch_bounds__(256) void fsrc_fdst12_bf16(
    const u16* __restrict__ h12,
    const float* __restrict__ a1, const float* __restrict__ a2,
    float* __restrict__ fs1, float* __restrict__ fd1,
    float* __restrict__ fs2, float* __restrict__ fd2)
{
  const int wid = threadIdx.x >> 6, lane = threadIdx.x & 63;
  const int row = blockIdx.x * 4 + wid;
  u16x8 hv = *(const u16x8*)(h12 + (size_t)row * 512 + lane * 8);
  float s0 = 0.f, s1 = 0.f;
  const bool lo = lane < 32;
  const float* av = lo ? a1 : a2;
  const int base = lo ? lane * 8 : lane * 8 - 256;
  #pragma unroll
  for (int j = 0; j < 8; ++j) {
    float x = bf2f(hv[j]);
    s0 = fmaf(x, av[base + j], s0);
    s1 = fmaf(x, av[256 + base + j], s1);
  }
  #pragma unroll
  for (int o = 16; o > 0; o >>= 1) {
    s0 += __shfl_down(s0, o, 64);
    s1 += __shfl_down(s1, o, 64);
  }
  if (lane == 0)  { fs1[row] = s0; fd1[row] = s1; }
  if (lane == 32) { fs2[row] = s0; fd2[row] = s1; }
}

// ---- layer-0 aggregate via CSR (bf16 h): TWO rows per block, 8B/lane gather
__global__ __launch_bounds__(256) void agg_gat0(
    const u16* __restrict__ h,
    const float* __restrict__ fs, const float* __restrict__ fd,
    const int* __restrict__ nbr, const int* __restrict__ cnt,
    const float* __restrict__ Y, u16* __restrict__ hb)
{
  __shared__ int   nb[2][CAP];
  __shared__ float pbuf[2][CAP];
  __shared__ float redm[4], reds[4];
  const int tid = threadIdx.x;
  const int hh = tid >> 7, t = tid & 127;       // half selects row
  const int wid = tid >> 6, lane = tid & 63;
  const int r = blockIdx.x * 2 + hh;
  int c = cnt[r]; if (c > CAP) c = CAP;
  const float fsi = fs[r];
  float4 acc = {0.f, 0.f, 0.f, 0.f};

  if (c > 0) {
    float e0 = -3.0e38f, e1 = -3.0e38f;
    if (t < c) {
      int j = nbr[(size_t)r * CAP + t];
      nb[hh][t] = j;
      float v = fsi + fd[j];
      e0 = v > 0.f ? v : LRELU_ALPHA * v;
    }
    if (t + 128 < c) {
      int j = nbr[(size_t)r * CAP + t + 128];
      nb[hh][t + 128] = j;
      float v = fsi + fd[j];
      e1 = v > 0.f ? v : LRELU_ALPHA * v;
    }
    float wm = waveMax(fmaxf(e0, e1));
    if (lane == 0) redm[wid] = wm;
    __syncthreads();
    const float gmax = fmaxf(redm[2 * hh], redm[2 * hh + 1]);
    float p0 = (t < c) ? __expf(e0 - gmax) : 0.f;
    float p1 = (t + 128 < c) ? __expf(e1 - gmax) : 0.f;
    float ws = waveSum(p0 + p1);
    if (lane == 0) reds[wid] = ws;
    __syncthreads();
    const float inv = 1.f / (reds[2 * hh] + reds[2 * hh + 1]);
    if (t < c) pbuf[hh][t] = p0 * inv;
    if (t + 128 < c) pbuf[hh][t + 128] = p1 * inv;
    __syncthreads();
    const u16* hp = h + 4 * t;
    #pragma unroll 4
    for (int n = 0; n < c; ++n) {
      u16x4 hv = *(const u16x4*)(hp + (size_t)nb[hh][n] * 512);
      float pn = pbuf[hh][n];
      acc.x = fmaf(pn, bf2f(hv[0]), acc.x);
      acc.y = fmaf(pn, bf2f(hv[1]), acc.y);
      acc.z = fmaf(pn, bf2f(hv[2]), acc.z);
      acc.w = fmaf(pn, bf2f(hv[3]), acc.w);
    }
  } else {
    const u16* hp = h + 4 * t;
    for (int j = 0; j < NN; ++j) {
      u16x4 hv = *(const u16x4*)(hp + (size_t)j * 512);
      acc.x += bf2f(hv[0]); acc.y += bf2f(hv[1]);
      acc.z += bf2f(hv[2]); acc.w += bf2f(hv[3]);
    }
    acc.x *= (1.f / NN); acc.y *= (1.f / NN);
    acc.z *= (1.f / NN); acc.w *= (1.f / NN);
  }
  float vx = acc.x > 0.f ? acc.x : expm1f(acc.x);
  float vy = acc.y > 0.f ? acc.y : expm1f(acc.y);
  float vz = acc.z > 0.f ? acc.z : expm1f(acc.z);
  float vw = acc.w > 0.f ? acc.w : expm1f(acc.w);
  u16* row = hb + (size_t)r * 544;
  *(u16x4*)(row + 4 * t) = u16x4{f2bf(vx), f2bf(vy), f2bf(vz), f2bf(vw)};
  if (t < 8) {
    float2 yv = *(const float2*)(Y + (size_t)r * 16 + 2 * t);
    *(u16x2*)(row + 512 + 2 * t) = u16x2{f2bf(yv.x), f2bf(yv.y)};
  } else if (t < 16) {
    *(u16x2*)(row + 528 + 2 * (t - 8)) = u16x2{0, 0};
  }
}

// ---- fused layers 1+2 aggregate + reparam + concat, bf16 h12, TWO rows per block,
//      8B/lane gather. thread t covers concatenated cols 4t..4t+3 (0-255 mn | 256-511 lsd)
__global__ __launch_bounds__(256) void agg_gat12(
    const u16* __restrict__ h12,
    const float* __restrict__ fs1, const float* __restrict__ fd1,
    const float* __restrict__ fs2, const float* __restrict__ fd2,
    const int* __restrict__ nbr, const int* __restrict__ cnt,
    const float* __restrict__ noise, const float* __restrict__ Y,
    u16* __restrict__ zcat)
{
  __shared__ int   nb[2][CAP];
  __shared__ float p1[2][CAP], p2[2][CAP];
  __shared__ float sm[2][512];
  __shared__ float redm1[4], redm2[4], reds1[4], reds2[4];
  const int tid = threadIdx.x;
  const int hh = tid >> 7, t = tid & 127;
  const int wid = tid >> 6, lane = tid & 63;
  const int r = blockIdx.x * 2 + hh;
  int c = cnt[r]; if (c > CAP) c = CAP;
  float4 acc = {0.f, 0.f, 0.f, 0.f};

  if (c > 0) {
    float e1a = -3.0e38f, e1b = -3.0e38f, e2a = -3.0e38f, e2b = -3.0e38f;
    if (t < c) {
      int j = nbr[(size_t)r * CAP + t];
      nb[hh][t] = j;
      float v1 = fs1[r] + fd1[j], v2 = fs2[r] + fd2[j];
      e1a = v1 > 0.f ? v1 : LRELU_ALPHA * v1;
      e2a = v2 > 0.f ? v2 : LRELU_ALPHA * v2;
    }
    if (t + 128 < c) {
      int j = nbr[(size_t)r * CAP + t + 128];
      nb[hh][t + 128] = j;
      float v1 = fs1[r] + fd1[j], v2 = fs2[r] + fd2[j];
      e1b = v1 > 0.f ? v1 : LRELU_ALPHA * v1;
      e2b = v2 > 0.f ? v2 : LRELU_ALPHA * v2;
    }
    float wm1 = waveMax(fmaxf(e1a, e1b)), wm2 = waveMax(fmaxf(e2a, e2b));
    if (lane == 0) { redm1[wid] = wm1; redm2[wid] = wm2; }
    __syncthreads();
    const float g1 = fmaxf(redm1[2 * hh], redm1[2 * hh + 1]);
    const float g2 = fmaxf(redm2[2 * hh], redm2[2 * hh + 1]);
    float p1a = (t < c) ? __expf(e1a - g1) : 0.f;
    float p1b = (t + 128 < c) ? __expf(e1b - g1) : 0.f;
    float p2a = (t < c) ? __expf(e2a - g2) : 0.f;
    float p2b = (t + 128 < c) ? __expf(e2b - g2) : 0.f;
    float ws1 = waveSum(p1a + p1b), ws2 = waveSum(p2a + p2b);
    if (lane == 0) { reds1[wid] = ws1; reds2[wid] = ws2; }
    __syncthreads();
    const float i1 = 1.f / (reds1[2 * hh] + reds1[2 * hh + 1]);
    const float i2 = 1.f / (reds2[2 * hh] + reds2[2 * hh + 1]);
    if (t < c) { p1[hh][t] = p1a * i1; p2[hh][t] = p2a * i2; }
    if (t + 128 < c) { p1[hh][t + 128] = p1b * i1; p2[hh][t + 128] = p2b * i2; }
    __syncthreads();
    const u16* hp = h12 + 4 * t;
    const float* pp = (t < 64) ? p1[hh] : p2[hh];
    #pragma unroll 4
    for (int n = 0; n < c; ++n) {
      u16x4 hv = *(const u16x4*)(hp + (size_t)nb[hh][n] * 512);
      float pn = pp[n];
      acc.x = fmaf(pn, bf2f(hv[0]), acc.x);
      acc.y = fmaf(pn, bf2f(hv[1]), acc.y);
      acc.z = fmaf(pn, bf2f(hv[2]), acc.z);
      acc.w = fmaf(pn, bf2f(hv[3]), acc.w);
    }
  } else {
    const u16* hp = h12 + 4 * t;
    for (int j = 0; j < NN; ++j) {
      u16x4 hv = *(const u16x4*)(hp + (size_t)j * 512);
      acc.x += bf2f(hv[0]); acc.y += bf2f(hv[1]);
      acc.z += bf2f(hv[2]); acc.w += bf2f(hv[3]);
    }
    acc.x *= (1.f / NN); acc.y *= (1.f / NN);
    acc.z *= (1.f / NN); acc.w *= (1.f / NN);
  }
  sm[hh][4 * t + 0] = acc.x > 0.f ? acc.x : expm1f(acc.x);
  sm[hh][4 * t + 1] = acc.y > 0.f ? acc.y : expm1f(acc.y);
  sm[hh][4 * t + 2] = acc.z > 0.f ? acc.z : expm1f(acc.z);
  sm[hh][4 * t + 3] = acc.w > 0.f ? acc.w : expm1f(acc.w);
  __syncthreads();
  u16* row = zcat + (size_t)r * 288;
  if (t < 64) {
    const int f = 4 * t;
    float4 nz = *(const float4*)(noise + (size_t)r * 256 + f);
    float z0 = fmaf(nz.x, expf(sm[hh][256 + f + 0]), sm[hh][f + 0]);
    float z1 = fmaf(nz.y, expf(sm[hh][256 + f + 1]), sm[hh][f + 1]);
    float z2 = fmaf(nz.z, expf(sm[hh][256 + f + 2]), sm[hh][f + 2]);
    float z3 = fmaf(nz.w, expf(sm[hh][256 + f + 3]), sm[hh][f + 3]);
    *(u16x4*)(row + f) = u16x4{f2bf(z0), f2bf(z1), f2bf(z2), f2bf(z3)};
  } else if (t < 72) {
    const int k = t - 64;
    float2 yv = *(const float2*)(Y + (size_t)r * 16 + 2 * k);
    *(u16x2*)(row + 256 + 2 * k) = u16x2{f2bf(yv.x), f2bf(yv.y)};
  } else if (t < 80) {
    *(u16x2*)(row + 272 + 2 * (t - 72)) = u16x2{0, 0};
  }
}

extern "C" void kernel_launch(void* const* d_in, const int* in_sizes, int n_in,
                              void* d_out, int out_size, void* d_ws, size_t ws_size,
                              hipStream_t stream)
{
  const float* X     = (const float*)d_in[0];
  const float* Y     = (const float*)d_in[1];
  const float* noise = (const float*)d_in[2];
  const void*  adj   = d_in[3];
  const float* W0    = (const float*)d_in[4];
  const float* a0    = (const float*)d_in[5];
  const float* W1    = (const float*)d_in[6];
  const float* a1    = (const float*)d_in[7];
  const float* W2    = (const float*)d_in[8];
  const float* a2    = (const float*)d_in[9];
  const float* fc1w  = (const float*)d_in[10];
  const float* fc1b  = (const float*)d_in[11];
  const float* fc2w  = (const float*)d_in[12];
  const float* fc2b  = (const float*)d_in[13];
  float* out = (float*)d_out;
  char* W = (char*)d_ws;

  // workspace layout (bytes), ~31.7 MB
  u16*   Xb    = (u16*)(W + 0);            // 4096x1024 bf16 (dead after gemm0)
  u16*   zcatb = (u16*)(W + 0);            // 4096x288 bf16
  u16*   zzb   = (u16*)(W + 2359296);      // 4096x512 bf16
  u16*   h0b   = (u16*)(W + 8388608);      // 4096x512 bf16 (dead after agg0)
  u16*   h12b  = (u16*)(W + 8388608);      // 4096x512 bf16 (reuses h0b region)
  u16*   hb    = (u16*)(W + 16777216);     // 4096x544 bf16
  u16*   W0t   = (u16*)(W + 21233664);     // 512x1024
  u16*   W12t  = (u16*)(W + 22282240);     // 512x544
  u16*   fc1t  = (u16*)(W + 22839296);     // 512x288
  u16*   fc2t  = (u16*)(W + 23134208);     // 4096x512
  int*   nbr   = (int*)(W + 27328512);     // 4096x256 int
  int*   cnt   = (int*)(W + 31522816);     // 4096 int
  float* fs0   = (float*)(W + 31539200);
  float* fd0   = fs0 + 4096;
  float* fs1   = fd0 + 4096;
  float* fd1   = fs1 + 4096;
  float* fs2   = fd1 + 4096;
  float* fd2   = fs2 + 4096;
  int*   flag  = (int*)(fd2 + 4096);

  hipMemsetAsync(flag, 0, 4, stream);
  prep_all<<<5280, 256, 0, stream>>>(W0, W0t, W1, W12t, W2, W12t + 256 * 544,
                                     fc1w, fc1t, X, Xb, (const unsigned*)adj, flag);

  // gemm0 (256) + build_csr (4096, HBM-bound) + fc2 transpose (2048) in one dispatch
  csr_gemm0<<<6400, 256, 0, stream>>>(Xb, W0t, h0b, (const unsigned*)adj, flag, nbr, cnt,
                                      fc2w, fc2t);

  fsrc_fdst_bf16<<<1024, 256, 0, stream>>>(h0b, a0, fs0, fd0);
  agg_gat0<<<2048, 256, 0, stream>>>(h0b, fs0, fd0, nbr, cnt, Y, hb);

  // GAT layers 1 & 2 merged: h12 = hb @ [W1|W2] (bf16 for the gather)
  gemm_mfma64<0, true><<<dim3(8, 32), 256, 0, stream>>>(hb, 544, W12t, 544, h12b, 512, 544, nullptr);
  fsrc_fdst12_bf16<<<1024, 256, 0, stream>>>(h12b, a1, a2, fs1, fd1, fs2, fd2);
  agg_gat12<<<2048, 256, 0, stream>>>(h12b, fs1, fd1, fs2, fd2, nbr, cnt, noise, Y, zcatb);

  // decoder
  gemm_mfma64<1, true><<<dim3(8, 32), 256, 0, stream>>>(zcatb, 288, fc1t, 288, zzb, 512, 288, fc1b);
  gemm_fc2_8p<<<dim3(16, 16), 512, 0, stream>>>(zzb, 512, fc2t, 512, out, 4096, 512, fc2b);
}

// Round 14
// 115.309 us; speedup vs baseline: 4.8746x; 1.0990x over previous
//
#include <hip/hip_runtime.h>

#define LRELU_ALPHA 0.2f
#define NN 4096
#define CAP 256

typedef unsigned short u16;
typedef short bf16x8 __attribute__((ext_vector_type(8)));
typedef float f32x4 __attribute__((ext_vector_type(4)));
typedef u16 u16x4 __attribute__((ext_vector_type(4)));
typedef u16 u16x2 __attribute__((ext_vector_type(2)));
typedef u16 u16x8 __attribute__((ext_vector_type(8)));

__device__ __forceinline__ u16 f2bf(float f) {
  unsigned u = __float_as_uint(f);
  u += 0x7FFFu + ((u >> 16) & 1u);
  return (u16)(u >> 16);
}
__device__ __forceinline__ float bf2f(u16 u) {
  return __uint_as_float(((unsigned)u) << 16);
}

// butterfly reductions: result valid in ALL 64 lanes
__device__ __forceinline__ float waveSum(float v) {
  #pragma unroll
  for (int o = 32; o > 0; o >>= 1) v += __shfl_xor(v, o, 64);
  return v;
}
__device__ __forceinline__ float waveMax(float v) {
  #pragma unroll
  for (int o = 32; o > 0; o >>= 1) v = fmaxf(v, __shfl_xor(v, o, 64));
  return v;
}

__device__ __forceinline__ void gload_lds16(const void* g, void* l) {
  __builtin_amdgcn_global_load_lds((const __attribute__((address_space(1))) void*)g,
                                   (__attribute__((address_space(3))) void*)l, 16, 0, 0);
}

// ---- CSR build body: one block per row, single pass, uint4-vectorized.
// adj is a 4-byte dtype (int32/f32 — confirmed by FETCH arithmetic); nonzero word == edge.
__device__ __forceinline__ void csr_body(const unsigned* __restrict__ adjw,
                                         int* __restrict__ nbr, int* __restrict__ cnt,
                                         int i, int* scn)
{
  const int tid = threadIdx.x;
  unsigned bits = 0;
  const unsigned* row = adjw + (size_t)i * 4096 + tid * 16;
  #pragma unroll
  for (int ck = 0; ck < 4; ++ck) {
    uint4 v = *(const uint4*)(row + ck * 4);
    if (v.x) bits |= 1u << (ck * 4 + 0);
    if (v.y) bits |= 1u << (ck * 4 + 1);
    if (v.z) bits |= 1u << (ck * 4 + 2);
    if (v.w) bits |= 1u << (ck * 4 + 3);
  }
  int mycnt = __popc(bits);
  scn[tid] = mycnt;
  __syncthreads();
  for (int off = 1; off < 256; off <<= 1) {
    int v = (tid >= off) ? scn[tid - off] : 0;
    __syncthreads();
    scn[tid] += v;
    __syncthreads();
  }
  const int total = scn[255];
  int pos = scn[tid] - mycnt;
  #pragma unroll
  for (int b = 0; b < 16; ++b) {
    if (bits & (1u << b)) {
      if (pos < CAP) nbr[(size_t)i * CAP + pos] = tid * 16 + b;
      ++pos;
    }
  }
  if (tid == 0) cnt[i] = total;
}

// ---- transpose helper (flat 256 threads): Wt[n][k] (bf16, ld=Kpad) from W[k][n] (f32)
__device__ __forceinline__ void transpose_body(const float* Wsrc, u16* Wt,
                                               int K, int N, int Kpad,
                                               int bx, int by, float (*t)[33]) {
  const int kb = by * 32, nb = bx * 32;
  const int tx = threadIdx.x & 31, ty = threadIdx.x >> 5;  // 32 x 8
  for (int i = ty; i < 32; i += 8) {
    int k = kb + i, n = nb + tx;
    t[i][tx] = (k < K && n < N) ? Wsrc[(size_t)k * N + n] : 0.f;
  }
  __syncthreads();
  for (int i = ty; i < 32; i += 8) {
    int n = nb + i, k = kb + tx;
    if (n < N && k < Kpad) Wt[(size_t)n * Kpad + k] = f2bf(t[tx][i]);
  }
}

// ---- small weight transposes + X f32->bf16
// [0,512) W0 | [512,648) W1 | [648,784) W2 | [784,928) fc1 | [928,5024) X
__global__ __launch_bounds__(256) void prep_all(
    const float* __restrict__ W0, u16* __restrict__ W0t,
    const float* __restrict__ W1, u16* __restrict__ W1t,
    const float* __restrict__ W2, u16* __restrict__ W2t,
    const float* __restrict__ fc1w, u16* __restrict__ fc1t,
    const float* __restrict__ X, u16* __restrict__ Xb)
{
  __shared__ float t[32][33];
  const int i = blockIdx.x, tid = threadIdx.x;
  if (i < 512) {
    transpose_body(W0, W0t, 1024, 512, 1024, i & 15, i >> 4, t);
  } else if (i < 648) {
    int j = i - 512;
    transpose_body(W1, W1t, 528, 256, 544, j & 7, j >> 3, t);
  } else if (i < 784) {
    int j = i - 648;
    transpose_body(W2, W2t, 528, 256, 544, j & 7, j >> 3, t);
  } else if (i < 928) {
    int j = i - 784;
    transpose_body(fc1w, fc1t, 272, 512, 288, j & 15, j >> 4, t);
  } else {
    int j = i - 928;
    int idx = j * 256 + tid;
    float4 v = ((const float4*)X)[idx];
    u16x4 o = {f2bf(v.x), f2bf(v.y), f2bf(v.z), f2bf(v.w)};
    ((u16x4*)Xb)[idx] = o;
  }
}

// ---- bf16 MFMA GEMM 128x64-tile body (dbuf + counted vmcnt, staged epilogue, XCD swizzle)
template<int ACT, bool OBF>
__device__ __forceinline__ void gemm64_dev(
    const u16* __restrict__ A, int lda,
    const u16* __restrict__ Bt, int ldb,
    void* __restrict__ Cout, int ldc,
    int K, const float* __restrict__ bias,
    u16 (&As)[2][128 * 32], u16 (&Bs)[2][64 * 32], int bid)
{
  const int tid = threadIdx.x;
  const int lane = tid & 63, wv = tid >> 6;
  const int wm = wv >> 1, wn = wv & 1;
  const int swz = ((bid & 7) << 5) | (bid >> 3);
  const int m0 = (swz >> 3) * 128, n0 = (swz & 7) * 64;
  const int nk = K >> 5;

  f32x4 acc[4][2] = {};

  auto STAGE = [&](int buf, int kt) {
    #pragma unroll
    for (int i = 0; i < 2; ++i) {
      int c = tid + i * 256;
      int r = c >> 2;
      int s = (c & 3) ^ ((r >> 1) & 3);
      gload_lds16(A + (size_t)(m0 + r) * lda + kt * 32 + s * 8, (char*)As[buf] + (c & ~63) * 16);
    }
    {
      int c = tid;
      int r = c >> 2;
      int s = (c & 3) ^ ((r >> 1) & 3);
      gload_lds16(Bt + (size_t)(n0 + r) * ldb + kt * 32 + s * 8, (char*)Bs[buf] + (c & ~63) * 16);
    }
  };

  STAGE(0, 0);
  if (nk > 1) STAGE(1, 1);

  int cur = 0;
  for (int kt = 0; kt < nk; ++kt) {
    if (kt + 1 < nk) { asm volatile("s_waitcnt vmcnt(3)" ::: "memory"); }
    else             { asm volatile("s_waitcnt vmcnt(0)" ::: "memory"); }
    __builtin_amdgcn_s_barrier();

    bf16x8 af[4], bf_[2];
    #pragma unroll
    for (int mi = 0; mi < 4; ++mi) {
      int r = wm * 64 + mi * 16 + (lane & 15);
      int sp = (lane >> 4) ^ ((r >> 1) & 3);
      af[mi] = *(const bf16x8*)((const char*)As[cur] + r * 64 + sp * 16);
    }
    #pragma unroll
    for (int ni = 0; ni < 2; ++ni) {
      int r = wn * 32 + ni * 16 + (lane & 15);
      int sp = (lane >> 4) ^ ((r >> 1) & 3);
      bf_[ni] = *(const bf16x8*)((const char*)Bs[cur] + r * 64 + sp * 16);
    }
    __builtin_amdgcn_s_setprio(1);
    #pragma unroll
    for (int mi = 0; mi < 4; ++mi)
      #pragma unroll
      for (int ni = 0; ni < 2; ++ni)
        acc[mi][ni] = __builtin_amdgcn_mfma_f32_16x16x32_bf16(af[mi], bf_[ni], acc[mi][ni], 0, 0, 0);
    __builtin_amdgcn_s_setprio(0);

    __builtin_amdgcn_s_barrier();
    if (kt + 2 < nk) STAGE(cur, kt + 2);
    cur ^= 1;
  }

  float bv2[2];
  #pragma unroll
  for (int ni = 0; ni < 2; ++ni)
    bv2[ni] = bias ? bias[n0 + wn * 32 + ni * 16 + (lane & 15)] : 0.f;
  float* sc = (float*)As;
  #pragma unroll
  for (int mi = 0; mi < 4; ++mi) {
    __syncthreads();
    const int lr = wm * 16 + (lane >> 4) * 4;
    #pragma unroll
    for (int ni = 0; ni < 2; ++ni) {
      const int lc = wn * 32 + ni * 16 + (lane & 15);
      #pragma unroll
      for (int j = 0; j < 4; ++j) {
        float v = acc[mi][ni][j] + bv2[ni];
        if (ACT == 1) v = fmaxf(v, 0.f);
        if (ACT == 2) v = 1.f / (1.f + __expf(-v));
        sc[(lr + j) * 64 + lc] = v;
      }
    }
    __syncthreads();
    #pragma unroll
    for (int u = 0; u < 2; ++u) {
      int idx = tid + u * 256;
      int r = idx >> 4, c4 = (idx & 15) * 4;
      int grow = m0 + (r >> 4) * 64 + mi * 16 + (r & 15);
      float4 v4 = *(const float4*)(sc + r * 64 + c4);
      if (OBF) {
        u16x4 o = {f2bf(v4.x), f2bf(v4.y), f2bf(v4.z), f2bf(v4.w)};
        *(u16x4*)((u16*)Cout + (size_t)grow * ldc + n0 + c4) = o;
      } else {
        *(float4*)((float*)Cout + (size_t)grow * ldc + n0 + c4) = v4;
      }
    }
  }
}

template<int ACT, bool OBF>
__global__ __launch_bounds__(256) void gemm_mfma64(
    const u16* __restrict__ A, int lda, const u16* __restrict__ Bt, int ldb,
    void* __restrict__ Cout, int ldc, int K, const float* __restrict__ bias)
{
  __shared__ u16 As[2][128 * 32];
  __shared__ u16 Bs[2][64 * 32];
  gemm64_dev<ACT, OBF>(A, lda, Bt, ldb, Cout, ldc, K, bias, As, Bs,
                       blockIdx.y * 8 + blockIdx.x);
}

// ---- merged dispatch: [0,256) gemm0 | [256,4352) build_csr | [4352,6400) fc2 transpose
__global__ __launch_bounds__(256) void csr_gemm0(
    const u16* __restrict__ Xb, const u16* __restrict__ W0t, u16* __restrict__ h0b,
    const unsigned* __restrict__ adjw,
    int* __restrict__ nbr, int* __restrict__ cnt,
    const float* __restrict__ fc2w, u16* __restrict__ fc2t)
{
  __shared__ u16 As[2][128 * 32];
  __shared__ u16 Bs[2][64 * 32];
  if (blockIdx.x < 256) {
    gemm64_dev<0, true>(Xb, 1024, W0t, 1024, h0b, 512, 1024, nullptr, As, Bs, blockIdx.x);
  } else if (blockIdx.x < 4352) {
    csr_body(adjw, nbr, cnt, blockIdx.x - 256, (int*)As);
  } else {
    int j = blockIdx.x - 4352;   // fc2: K=512 (16 k-tiles) x N=4096 (128 n-tiles)
    transpose_body(fc2w, fc2t, 512, 4096, 512, j & 127, j >> 7, (float(*)[33])As);
  }
}

// ---- fc2: 256x256 tile, BK=64, 8 waves, 8-PHASE counted-vmcnt schedule (T3+T4+T5),
//      LDS half-buffers [slot][half:128x64], staged NT epilogue, XCD swizzle. K even*64.
__global__ __launch_bounds__(512, 2) void gemm_fc2_8p(
    const u16* __restrict__ A, int lda,
    const u16* __restrict__ Bt, int ldb,
    float* __restrict__ Cout, int ldc,
    int K, const float* __restrict__ bias)
{
  __shared__ u16 As[2][2][128 * 64];   // [slot][half] 16KB each -> 64KB
  __shared__ u16 Bs[2][2][128 * 64];   // 64KB
  const int tid = threadIdx.x;
  const int lane = tid & 63, wv = tid >> 6;
  const int wm = wv >> 2, wn = wv & 3;          // 2 x 4; wave owns 128x64
  const int bid = blockIdx.y * 16 + blockIdx.x;
  const int swz = ((bid & 7) << 5) | (bid >> 3);
  const int m0 = (swz >> 4) * 256, n0 = (swz & 15) * 256;
  const int nk = K >> 6;

  f32x4 acc[8][4] = {};

  auto stA = [&](int slot, int h, int t) {      // 2 loads/thread (one 128x64 half)
    const u16* Ap = A + (size_t)(m0 + h * 128) * lda + t * 64;
    #pragma unroll
    for (int i = 0; i < 2; ++i) {
      int c = tid + i * 512;
      int r = c >> 3, sl = c & 7;
      int sg = sl ^ (r & 7);
      gload_lds16(Ap + (size_t)r * lda + sg * 8, (char*)&As[slot][h][0] + (c & ~63) * 16);
    }
  };
  auto stB = [&](int slot, int h, int t) {
    const u16* Bp = Bt + (size_t)(n0 + h * 128) * ldb + t * 64;
    #pragma unroll
    for (int i = 0; i < 2; ++i) {
      int c = tid + i * 512;
      int r = c >> 3, sl = c & 7;
      int sg = sl ^ (r & 7);
      gload_lds16(Bp + (size_t)r * ldb + sg * 8, (char*)&Bs[slot][h][0] + (c & ~63) * 16);
    }
  };

  bf16x8 afl[4][2], afh[4][2], bfl[2][2], bfh[2][2];
  auto rdAq = [&](int slot, int mi0, bf16x8 (&dst)[4][2]) {
    #pragma unroll
    for (int m = 0; m < 4; ++m)
      #pragma unroll
      for (int ks = 0; ks < 2; ++ks) {
        int r = (mi0 + m) * 16 + (lane & 15);
        int sl = (ks * 4 + (lane >> 4)) ^ (r & 7);
        dst[m][ks] = *(const bf16x8*)((const char*)&As[slot][wm][0] + r * 128 + sl * 16);
      }
  };
  auto rdBq = [&](int slot, int ni0, bf16x8 (&dst)[2][2]) {
    #pragma unroll
    for (int n = 0; n < 2; ++n)
      #pragma unroll
      for (int ks = 0; ks < 2; ++ks) {
        int r = (wn & 1) * 64 + (ni0 + n) * 16 + (lane & 15);
        int sl = (ks * 4 + (lane >> 4)) ^ (r & 7);
        dst[n][ks] = *(const bf16x8*)((const char*)&Bs[slot][wn >> 1][0] + r * 128 + sl * 16);
      }
  };
  auto quad = [&](int mi0, int ni0, bf16x8 (&af)[4][2], bf16x8 (&bf)[2][2]) {
    __builtin_amdgcn_s_setprio(1);
    #pragma unroll
    for (int m = 0; m < 4; ++m)
      #pragma unroll
      for (int n = 0; n < 2; ++n)
        #pragma unroll
        for (int ks = 0; ks < 2; ++ks)
          acc[mi0 + m][ni0 + n] =
              __builtin_amdgcn_mfma_f32_16x16x32_bf16(af[m][ks], bf[n][ks], acc[mi0 + m][ni0 + n], 0, 0, 0);
    __builtin_amdgcn_s_setprio(0);
  };
  #define BARX() __builtin_amdgcn_s_barrier()

  // prologue: tile0 fully + A-halves of tile1 (12 loads/thread)
  stA(0, 0, 0); stA(0, 1, 0); stB(0, 0, 0); stB(0, 1, 0);
  stA(1, 0, 1); stA(1, 1, 1);
  asm volatile("s_waitcnt vmcnt(4)" ::: "memory");   // tile0 landed; Ah(1) in flight
  BARX();

  for (int j = 0; j < nk; j += 2) {
    const bool s2 = (j + 2) < nk;
    // ---- tile j (slot 0), 4 phases ----
    rdAq(0, 0, afl); rdBq(0, 0, bfl);          // P1
    stB(1, 0, j + 1);
    BARX(); quad(0, 0, afl, bfl); BARX();
    rdAq(0, 4, afh);                           // P2
    stB(1, 1, j + 1);
    BARX(); quad(4, 0, afh, bfl); BARX();
    rdBq(0, 2, bfh);                           // P3
    if (s2) stA(0, 0, j + 2);
    BARX(); quad(0, 2, afl, bfh); BARX();
    if (s2) {                                  // P4
      stA(0, 1, j + 2);
      asm volatile("s_waitcnt vmcnt(4)" ::: "memory");
    } else {
      asm volatile("s_waitcnt vmcnt(0)" ::: "memory");
    }
    BARX(); quad(4, 2, afh, bfh); BARX();
    // ---- tile j+1 (slot 1), 4 phases ----
    rdAq(1, 0, afl); rdBq(1, 0, bfl);          // P5
    if (s2) stB(0, 0, j + 2);
    BARX(); quad(0, 0, afl, bfl); BARX();
    rdAq(1, 4, afh);                           // P6
    if (s2) stB(0, 1, j + 2);
    BARX(); quad(4, 0, afh, bfl); BARX();
    rdBq(1, 2, bfh);                           // P7
    if (s2) stA(1, 0, j + 3);
    BARX(); quad(0, 2, afl, bfh); BARX();
    if (s2) {                                  // P8
      stA(1, 1, j + 3);
      asm volatile("s_waitcnt vmcnt(4)" ::: "memory");
    } else {
      asm volatile("s_waitcnt vmcnt(0)" ::: "memory");
    }
    BARX(); quad(4, 2, afh, bfh); BARX();
  }

  // epilogue: per-mi 32-row x 256-col band staged in LDS, coalesced NT writeback (sigmoid+bias)
  float bv4[4];
  #pragma unroll
  for (int ni = 0; ni < 4; ++ni)
    bv4[ni] = bias[n0 + wn * 64 + ni * 16 + (lane & 15)];
  float* sc = (float*)As;   // 32KB of the 64KB A region
  #pragma unroll
  for (int mi = 0; mi < 8; ++mi) {
    __syncthreads();
    const int lr = wm * 16 + (lane >> 4) * 4;
    #pragma unroll
    for (int ni = 0; ni < 4; ++ni) {
      const int lc = wn * 64 + ni * 16 + (lane & 15);
      #pragma unroll
      for (int j = 0; j < 4; ++j) {
        float v = acc[mi][ni][j] + bv4[ni];
        v = 1.f / (1.f + __expf(-v));
        sc[(lr + j) * 256 + lc] = v;
      }
    }
    __syncthreads();
    #pragma unroll
    for (int u = 0; u < 4; ++u) {
      int idx = tid + u * 512;
      int r = idx >> 6, c4 = (idx & 63) * 4;
      int grow = m0 + (r >> 4) * 128 + mi * 16 + (r & 15);
      f32x4 v4 = *(const f32x4*)(sc + r * 256 + c4);
      __builtin_nontemporal_store(v4, (f32x4*)(Cout + (size_t)grow * ldc + n0 + c4));
    }
  }
}

// ---- per-row attention scores, bf16 h (layer 0, F=512)
__global__ __launch_bounds__(256) void fsrc_fdst_bf16(
    const u16* __restrict__ h, const float* __restrict__ a,
    float* __restrict__ fs, float* __restrict__ fd)
{
  const int wid = threadIdx.x >> 6, lane = threadIdx.x & 63;
  const int row = blockIdx.x * 4 + wid;
  u16x8 hv = *(const u16x8*)(h + (size_t)row * 512 + lane * 8);
  float s0 = 0.f, s1 = 0.f;
  #pragma unroll
  for (int j = 0; j < 8; ++j) {
    float x = bf2f(hv[j]);
    s0 = fmaf(x, a[lane * 8 + j], s0);
    s1 = fmaf(x, a[512 + lane * 8 + j], s1);
  }
  s0 = waveSum(s0);
  s1 = waveSum(s1);
  if (lane == 0) { fs[row] = s0; fd[row] = s1; }
}

// ---- merged scores for layers 1&2 over h12b [4096][512] bf16
__global__ __launch_bounds__(256) void fsrc_fdst12_bf16(
    const u16* __restrict__ h12,
    const float* __restrict__ a1, const float* __restrict__ a2,
    float* __restrict__ fs1, float* __restrict__ fd1,
    float* __restrict__ fs2, float* __restrict__ fd2)
{
  const int wid = threadIdx.x >> 6, lane = threadIdx.x & 63;
  const int row = blockIdx.x * 4 + wid;
  u16x8 hv = *(const u16x8*)(h12 + (size_t)row * 512 + lane * 8);
  float s0 = 0.f, s1 = 0.f;
  const bool lo = lane < 32;
  const float* av = lo ? a1 : a2;
  const int base = lo ? lane * 8 : lane * 8 - 256;
  #pragma unroll
  for (int j = 0; j < 8; ++j) {
    float x = bf2f(hv[j]);
    s0 = fmaf(x, av[base + j], s0);
    s1 = fmaf(x, av[256 + base + j], s1);
  }
  #pragma unroll
  for (int o = 16; o > 0; o >>= 1) {
    s0 += __shfl_down(s0, o, 64);
    s1 += __shfl_down(s1, o, 64);
  }
  if (lane == 0)  { fs1[row] = s0; fd1[row] = s1; }
  if (lane == 32) { fs2[row] = s0; fd2[row] = s1; }
}

// ---- layer-0 aggregate via CSR (bf16 h): wave-per-row, 16B/lane, no barriers
__global__ __launch_bounds__(256) void agg_gat0(
    const u16* __restrict__ h,
    const float* __restrict__ fs, const float* __restrict__ fd,
    const int* __restrict__ nbr, const int* __restrict__ cnt,
    const float* __restrict__ Y, u16* __restrict__ hb)
{
  __shared__ int   nb[4][CAP];
  __shared__ float pbuf[4][CAP];
  const int tid = threadIdx.x;
  const int w = tid >> 6, lane = tid & 63;
  const int r = blockIdx.x * 4 + w;
  int c = cnt[r]; if (c > CAP) c = CAP;
  float acc[8] = {};
  const u16* hp = h + lane * 8;

  if (c > 0) {
    const float fsi = fs[r];
    float e[4];
    #pragma unroll
    for (int k = 0; k < 4; ++k) {
      int n = lane + k * 64;
      e[k] = -3.0e38f;
      if (n < c) {
        int j = nbr[(size_t)r * CAP + n];
        nb[w][n] = j;
        float v = fsi + fd[j];
        e[k] = v > 0.f ? v : LRELU_ALPHA * v;
      }
    }
    float m = waveMax(fmaxf(fmaxf(e[0], e[1]), fmaxf(e[2], e[3])));
    float p[4], ps = 0.f;
    #pragma unroll
    for (int k = 0; k < 4; ++k) {
      int n = lane + k * 64;
      p[k] = (n < c) ? __expf(e[k] - m) : 0.f;
      ps += p[k];
    }
    const float inv = 1.f / waveSum(ps);
    #pragma unroll
    for (int k = 0; k < 4; ++k) {
      int n = lane + k * 64;
      if (n < c) pbuf[w][n] = p[k] * inv;
    }
    for (int n = 0; n < c; ++n) {
      int j = nb[w][n];
      float pn = pbuf[w][n];
      u16x8 hv = *(const u16x8*)(hp + (size_t)j * 512);
      #pragma unroll
      for (int q = 0; q < 8; ++q) acc[q] = fmaf(pn, bf2f(hv[q]), acc[q]);
    }
  } else {
    for (int j = 0; j < NN; ++j) {
      u16x8 hv = *(const u16x8*)(hp + (size_t)j * 512);
      #pragma unroll
      for (int q = 0; q < 8; ++q) acc[q] += bf2f(hv[q]);
    }
    #pragma unroll
    for (int q = 0; q < 8; ++q) acc[q] *= (1.f / NN);
  }
  u16x8 o;
  #pragma unroll
  for (int q = 0; q < 8; ++q) {
    float v = acc[q] > 0.f ? acc[q] : expm1f(acc[q]);
    o[q] = f2bf(v);
  }
  u16* row = hb + (size_t)r * 544;
  *(u16x8*)(row + lane * 8) = o;
  if (lane < 4) {
    float4 yv = *(const float4*)(Y + (size_t)r * 16 + 4 * lane);
    *(u16x4*)(row + 512 + 4 * lane) = u16x4{f2bf(yv.x), f2bf(yv.y), f2bf(yv.z), f2bf(yv.w)};
  } else if (lane < 8) {
    *(u16x4*)(row + 528 + 4 * (lane - 4)) = u16x4{0, 0, 0, 0};
  }
}

// ---- fused layers 1+2 aggregate + reparam + concat: wave-per-row, 16B/lane, no barriers.
// lane<32 covers mn cols (p1 weights), lane>=32 covers lsd cols (p2); reparam via shfl.
__global__ __launch_bounds__(256) void agg_gat12(
    const u16* __restrict__ h12,
    const float* __restrict__ fs1, const float* __restrict__ fd1,
    const float* __restrict__ fs2, const float* __restrict__ fd2,
    const int* __restrict__ nbr, const int* __restrict__ cnt,
    const float* __restrict__ noise, const float* __restrict__ Y,
    u16* __restrict__ zcat)
{
  __shared__ int   nb[4][CAP];
  __shared__ float p1[4][CAP], p2[4][CAP];
  const int tid = threadIdx.x;
  const int w = tid >> 6, lane = tid & 63;
  const int r = blockIdx.x * 4 + w;
  int c = cnt[r]; if (c > CAP) c = CAP;
  float acc[8] = {};
  const u16* hp = h12 + lane * 8;

  if (c > 0) {
    const float f1 = fs1[r], f2 = fs2[r];
    float e1[4], e2[4];
    #pragma unroll
    for (int k = 0; k < 4; ++k) {
      int n = lane + k * 64;
      e1[k] = -3.0e38f; e2[k] = -3.0e38f;
      if (n < c) {
        int j = nbr[(size_t)r * CAP + n];
        nb[w][n] = j;
        float v1 = f1 + fd1[j], v2 = f2 + fd2[j];
        e1[k] = v1 > 0.f ? v1 : LRELU_ALPHA * v1;
        e2[k] = v2 > 0.f ? v2 : LRELU_ALPHA * v2;
      }
    }
    float g1 = waveMax(fmaxf(fmaxf(e1[0], e1[1]), fmaxf(e1[2], e1[3])));
    float g2 = waveMax(fmaxf(fmaxf(e2[0], e2[1]), fmaxf(e2[2], e2[3])));
    float q1[4], q2[4], s1p = 0.f, s2p = 0.f;
    #pragma unroll
    for (int k = 0; k < 4; ++k) {
      int n = lane + k * 64;
      q1[k] = (n < c) ? __expf(e1[k] - g1) : 0.f;
      q2[k] = (n < c) ? __expf(e2[k] - g2) : 0.f;
      s1p += q1[k]; s2p += q2[k];
    }
    const float i1 = 1.f / waveSum(s1p);
    const float i2 = 1.f / waveSum(s2p);
    #pragma unroll
    for (int k = 0; k < 4; ++k) {
      int n = lane + k * 64;
      if (n < c) { p1[w][n] = q1[k] * i1; p2[w][n] = q2[k] * i2; }
    }
    const float* pp = (lane < 32) ? p1[w] : p2[w];
    for (int n = 0; n < c; ++n) {
      int j = nb[w][n];
      float pn = pp[n];
      u16x8 hv = *(const u16x8*)(hp + (size_t)j * 512);
      #pragma unroll
      for (int q = 0; q < 8; ++q) acc[q] = fmaf(pn, bf2f(hv[q]), acc[q]);
    }
  } else {
    for (int j = 0; j < NN; ++j) {
      u16x8 hv = *(const u16x8*)(hp + (size_t)j * 512);
      #pragma unroll
      for (int q = 0; q < 8; ++q) acc[q] += bf2f(hv[q]);
    }
    #pragma unroll
    for (int q = 0; q < 8; ++q) acc[q] *= (1.f / NN);
  }
  // ELU
  float v[8];
  #pragma unroll
  for (int q = 0; q < 8; ++q) v[q] = acc[q] > 0.f ? acc[q] : expm1f(acc[q]);
  // lsd values live in lane+32; pull them down for the reparam (xor keeps index in-range)
  float lsd[8];
  #pragma unroll
  for (int q = 0; q < 8; ++q) lsd[q] = __shfl_xor(v[q], 32, 64);
  u16* row = zcat + (size_t)r * 288;
  if (lane < 32) {
    const float* nz = noise + (size_t)r * 256 + lane * 8;
    float4 na = *(const float4*)nz, nbv = *(const float4*)(nz + 4);
    float nzv[8] = {na.x, na.y, na.z, na.w, nbv.x, nbv.y, nbv.z, nbv.w};
    u16x8 o;
    #pragma unroll
    for (int q = 0; q < 8; ++q)
      o[q] = f2bf(fmaf(nzv[q], __expf(lsd[q]), v[q]));
    *(u16x8*)(row + lane * 8) = o;
  } else if (lane < 36) {
    float4 yv = *(const float4*)(Y + (size_t)r * 16 + 4 * (lane - 32));
    *(u16x4*)(row + 256 + 4 * (lane - 32)) = u16x4{f2bf(yv.x), f2bf(yv.y), f2bf(yv.z), f2bf(yv.w)};
  } else if (lane < 40) {
    *(u16x4*)(row + 272 + 4 * (lane - 36)) = u16x4{0, 0, 0, 0};
  }
}

extern "C" void kernel_launch(void* const* d_in, const int* in_sizes, int n_in,
                              void* d_out, int out_size, void* d_ws, size_t ws_size,
                              hipStream_t stream)
{
  const float* X     = (const float*)d_in[0];
  const float* Y     = (const float*)d_in[1];
  const float* noise = (const float*)d_in[2];
  const void*  adj   = d_in[3];
  const float* W0    = (const float*)d_in[4];
  const float* a0    = (const float*)d_in[5];
  const float* W1    = (const float*)d_in[6];
  const float* a1    = (const float*)d_in[7];
  const float* W2    = (const float*)d_in[8];
  const float* a2    = (const float*)d_in[9];
  const float* fc1w  = (const float*)d_in[10];
  const float* fc1b  = (const float*)d_in[11];
  const float* fc2w  = (const float*)d_in[12];
  const float* fc2b  = (const float*)d_in[13];
  float* out = (float*)d_out;
  char* W = (char*)d_ws;

  // workspace layout (bytes), ~31.7 MB
  u16*   Xb    = (u16*)(W + 0);            // 4096x1024 bf16 (dead after gemm0)
  u16*   zcatb = (u16*)(W + 0);            // 4096x288 bf16
  u16*   zzb   = (u16*)(W + 2359296);      // 4096x512 bf16
  u16*   h0b   = (u16*)(W + 8388608);      // 4096x512 bf16 (dead after agg0)
  u16*   h12b  = (u16*)(W + 8388608);      // 4096x512 bf16 (reuses h0b region)
  u16*   hb    = (u16*)(W + 16777216);     // 4096x544 bf16
  u16*   W0t   = (u16*)(W + 21233664);     // 512x1024
  u16*   W12t  = (u16*)(W + 22282240);     // 512x544
  u16*   fc1t  = (u16*)(W + 22839296);     // 512x288
  u16*   fc2t  = (u16*)(W + 23134208);     // 4096x512
  int*   nbr   = (int*)(W + 27328512);     // 4096x256 int
  int*   cnt   = (int*)(W + 31522816);     // 4096 int
  float* fs0   = (float*)(W + 31539200);
  float* fd0   = fs0 + 4096;
  float* fs1   = fd0 + 4096;
  float* fd1   = fs1 + 4096;
  float* fs2   = fd1 + 4096;
  float* fd2   = fs2 + 4096;

  prep_all<<<5024, 256, 0, stream>>>(W0, W0t, W1, W12t, W2, W12t + 256 * 544,
                                     fc1w, fc1t, X, Xb);

  // gemm0 (256) + build_csr (4096, HBM-bound) + fc2 transpose (2048) in one dispatch
  csr_gemm0<<<6400, 256, 0, stream>>>(Xb, W0t, h0b, (const unsigned*)adj, nbr, cnt,
                                      fc2w, fc2t);

  fsrc_fdst_bf16<<<1024, 256, 0, stream>>>(h0b, a0, fs0, fd0);
  agg_gat0<<<1024, 256, 0, stream>>>(h0b, fs0, fd0, nbr, cnt, Y, hb);

  // GAT layers 1 & 2 merged: h12 = hb @ [W1|W2] (bf16 for the gather)
  gemm_mfma64<0, true><<<dim3(8, 32), 256, 0, stream>>>(hb, 544, W12t, 544, h12b, 512, 544, nullptr);
  fsrc_fdst12_bf16<<<1024, 256, 0, stream>>>(h12b, a1, a2, fs1, fd1, fs2, fd2);
  agg_gat12<<<1024, 256, 0, stream>>>(h12b, fs1, fd1, fs2, fd2, nbr, cnt, noise, Y, zcatb);

  // decoder
  gemm_mfma64<1, true><<<dim3(8, 32), 256, 0, stream>>>(zcatb, 288, fc1t, 288, zzb, 512, 288, fc1b);
  gemm_fc2_8p<<<dim3(16, 16), 512, 0, stream>>>(zzb, 512, fc2t, 512, out, 4096, 512, fc2b);
}